// Round 9
// baseline (129.368 us; speedup 1.0000x reference)
//
#include <hip/hip_runtime.h>
#include <hip/hip_bf16.h>
#include <stdint.h>

#define BATCH 2
#define CH 256
#define NSP 4096          // 64*64 spatial
#define HEADS 8
#define HD 32
#define GROUPS 32
#define EPS_GN 1e-5f
#define NSPLIT 4          // flash KV-sequence splits

// hd^-0.5 * log2(e): folds softmax scale AND exp->exp2 conversion into k
#define ATT_SCALE (0.17677669529663687f * 1.4426950408889634f)

typedef __attribute__((ext_vector_type(8))) short short8;    // 8 bf16 (MFMA A/B frag)
typedef __attribute__((ext_vector_type(4))) float f32x4;     // 16x16 C/D frag
typedef __attribute__((ext_vector_type(16))) float f32x16;   // 32x32 C/D frag
typedef __attribute__((ext_vector_type(2))) float f32x2;     // v_pk_add_f32 operand

#define ZERO16 ((f32x16){0.f,0.f,0.f,0.f,0.f,0.f,0.f,0.f,0.f,0.f,0.f,0.f,0.f,0.f,0.f,0.f})

static __device__ __forceinline__ unsigned short f2bf(float f) {
    union { float f; unsigned u; } v; v.f = f;
    unsigned r = v.u + 0x7fffu + ((v.u >> 16) & 1u);  // RNE
    return (unsigned short)(r >> 16);
}
static __device__ __forceinline__ unsigned pkbf(float x, float y) {
    __hip_bfloat162 h = __float22bfloat162_rn(make_float2(x, y));  // -> v_cvt_pk_bf16_f32
    return *(unsigned*)&h;
}

// ---------------- K1: GroupNorm stats: one block per (b,group) ----------------
__global__ void k_gnstats(const float* __restrict__ x, float* __restrict__ stats) {
    int bg = blockIdx.x;
    int t = threadIdx.x;
    const float4* b4 = (const float4*)(x + (size_t)bg * (8 * NSP));
    float s = 0.f, sq = 0.f;
    #pragma unroll
    for (int i = 0; i < 32; i++) {
        float4 v = b4[t + i * 256];
        s  += v.x + v.y + v.z + v.w;
        sq += v.x * v.x + v.y * v.y + v.z * v.z + v.w * v.w;
    }
    #pragma unroll
    for (int off = 32; off > 0; off >>= 1) {
        s  += __shfl_down(s, off);
        sq += __shfl_down(sq, off);
    }
    __shared__ float rs[4], rq[4];
    int w = t >> 6;
    if ((t & 63) == 0) { rs[w] = s; rq[w] = sq; }
    __syncthreads();
    if (t == 0) {
        float S = rs[0] + rs[1] + rs[2] + rs[3];
        float Q = rq[0] + rq[1] + rq[2] + rq[3];
        float mu  = S * (1.0f / 32768.0f);
        float var = Q * (1.0f / 32768.0f) - mu * mu;
        stats[bg * 2]     = mu;
        stats[bg * 2 + 1] = rsqrtf(var + EPS_GN);
    }
}

// ------ K2: apply GN, write xn^T (b,p,c) bf16, per-channel partial sums ------
__global__ void k_gnapply(const float* __restrict__ x, const float* __restrict__ gn_w,
                          const float* __restrict__ gn_b, const float* __restrict__ stats,
                          unsigned short* __restrict__ xnt, float* __restrict__ gpart) {
    int p0 = blockIdx.x * 64, c0 = blockIdx.y * 64, b = blockIdx.z;
    int t = threadIdx.x;
    __shared__ float tile[64][65];
    int ci0 = t >> 4, pq = t & 15;
    #pragma unroll
    for (int k = 0; k < 4; k++) {
        int ci = ci0 + k * 16;
        int c = c0 + ci;
        float mu   = stats[(b * GROUPS + (c >> 3)) * 2];
        float rstd = stats[(b * GROUPS + (c >> 3)) * 2 + 1];
        float w  = gn_w[c] * rstd;
        float bb = gn_b[c] - mu * w;
        float4 v = *(const float4*)(x + ((size_t)(b * CH + c)) * NSP + p0 + pq * 4);
        tile[ci][pq * 4 + 0] = v.x * w + bb;
        tile[ci][pq * 4 + 1] = v.y * w + bb;
        tile[ci][pq * 4 + 2] = v.z * w + bb;
        tile[ci][pq * 4 + 3] = v.w * w + bb;
    }
    __syncthreads();
    int pi = t >> 2, cb = (t & 3) * 16;
    unsigned pack[8];
    #pragma unroll
    for (int e = 0; e < 8; e++) {
        float a  = tile[cb + 2 * e][pi];
        float bv = tile[cb + 2 * e + 1][pi];
        pack[e] = (unsigned)f2bf(a) | ((unsigned)f2bf(bv) << 16);
    }
    uint4* dst = (uint4*)(xnt + ((size_t)(b * NSP + p0 + pi)) * CH + c0 + cb);
    dst[0] = make_uint4(pack[0], pack[1], pack[2], pack[3]);
    dst[1] = make_uint4(pack[4], pack[5], pack[6], pack[7]);
    if (t < 64) {
        float s = 0.f;
        #pragma unroll
        for (int j = 0; j < 64; j++) s += tile[t][j];
        gpart[((size_t)(b * CH + c0 + t)) * 64 + blockIdx.x] = s;
    }
}

// -------- K3: gfeat = mean(xn) @ gproj_w^T + gproj_b --------
__global__ void k_gproj(const float* __restrict__ gpart, const float* __restrict__ gproj_w,
                        const float* __restrict__ gproj_b, float* __restrict__ gfeat) {
    int b = blockIdx.x, t = threadIdx.x;
    __shared__ float graw[256];
    const float* p = gpart + ((size_t)(b * CH + t)) * 64;
    float s = 0.f;
    #pragma unroll
    for (int i = 0; i < 64; i++) s += p[i];
    graw[t] = s * (1.0f / 4096.0f);
    __syncthreads();
    float acc = gproj_b[t];
    const float* wr = gproj_w + (size_t)t * CH;
    #pragma unroll 8
    for (int c = 0; c < 256; c++) acc += graw[c] * wr[c];
    gfeat[b * CH + t] = acc;
}

// ---------------- K4: convert qkv_w + proj_w to bf16 ----------------
__global__ void k_convert(const float* __restrict__ qkv_w, const float* __restrict__ proj_w,
                          unsigned short* __restrict__ wbf) {
    int i4 = blockIdx.x * 256 + threadIdx.x;
    const float* src = (i4 < 49152) ? (qkv_w + (size_t)i4 * 4)
                                    : (proj_w + (size_t)(i4 - 49152) * 4);
    float4 v = *(const float4*)src;
    ushort4 o;
    o.x = f2bf(v.x); o.y = f2bf(v.y); o.z = f2bf(v.z); o.w = f2bf(v.w);
    *(ushort4*)(wbf + (size_t)i4 * 4) = o;
}

// ---------------- K5a: QKV GEMM -> bf16 q/k/v in attention layouts ----------------
__global__ void k_gemm_qkv(const unsigned short* __restrict__ Ag,
                           const unsigned short* __restrict__ Btg,
                           const float* __restrict__ bias,
                           const float* __restrict__ gfeat,
                           unsigned short* __restrict__ qt,
                           unsigned short* __restrict__ kt,
                           unsigned short* __restrict__ vt) {
    int n0 = blockIdx.x * 128, m0 = blockIdx.y * 64, b = blockIdx.z;
    int t = threadIdx.x, lane = t & 63, w = t >> 6;
    int wm = w >> 1, wn = w & 1;
    __shared__ short A_lds[64][40];
    __shared__ short B_lds[128][40];
    const unsigned short* Bb = Btg + (size_t)b * NSP * CH;
    f32x4 acc[2][4];
    #pragma unroll
    for (int m = 0; m < 2; m++)
        #pragma unroll
        for (int n = 0; n < 4; n++) acc[m][n] = (f32x4){0.f, 0.f, 0.f, 0.f};
    int arow = t >> 2, akk = (t & 3) * 8;
    for (int k0 = 0; k0 < 256; k0 += 32) {
        __syncthreads();
        *(uint4*)&A_lds[arow][akk] = *(const uint4*)(Ag + (size_t)(m0 + arow) * CH + k0 + akk);
        #pragma unroll
        for (int hh = 0; hh < 2; hh++) {
            int f = t + hh * 256;
            int j = f >> 2, kk = (f & 3) * 8;
            *(uint4*)&B_lds[j][kk] = *(const uint4*)(Bb + (size_t)(n0 + j) * CH + k0 + kk);
        }
        __syncthreads();
        short8 a[2], bf[4];
        #pragma unroll
        for (int m = 0; m < 2; m++)
            a[m] = *(const short8*)&A_lds[wm * 32 + m * 16 + (lane & 15)][(lane >> 4) * 8];
        #pragma unroll
        for (int n = 0; n < 4; n++)
            bf[n] = *(const short8*)&B_lds[wn * 64 + n * 16 + (lane & 15)][(lane >> 4) * 8];
        #pragma unroll
        for (int m = 0; m < 2; m++)
            #pragma unroll
            for (int n = 0; n < 4; n++)
                acc[m][n] = __builtin_amdgcn_mfma_f32_16x16x32_bf16(a[m], bf[n], acc[m][n], 0, 0, 0);
    }
    int rbase = m0 + wm * 32 + ((lane >> 4) << 2);
    int cbase = n0 + wn * 64 + (lane & 15);
    #pragma unroll
    for (int m = 0; m < 2; m++) {
        int row0 = rbase + m * 16;
        int sec = row0 >> 8;
        int ch  = row0 & 255;
        int h = ch >> 5, d0 = ch & 31;
        #pragma unroll
        for (int n = 0; n < 4; n++) {
            int col = cbase + n * 16;
            if (sec == 0) {
                ushort4 pk;
                pk.x = f2bf(acc[m][n][0] + bias[row0 + 0]);
                pk.y = f2bf(acc[m][n][1] + bias[row0 + 1]);
                pk.z = f2bf(acc[m][n][2] + bias[row0 + 2]);
                pk.w = f2bf(acc[m][n][3] + bias[row0 + 3]);
                *(ushort4*)(qt + ((size_t)((b * 8 + h) * NSP + col)) * HD + d0) = pk;
            } else if (sec == 1) {
                ushort4 pk;
                #pragma unroll
                for (int i = 0; i < 4; i++) {
                    float v = (acc[m][n][i] + bias[row0 + i]
                               + 0.1f * gfeat[b * CH + ch + i]) * ATT_SCALE;
                    ((unsigned short*)&pk)[i] = f2bf(v);
                }
                *(ushort4*)(kt + ((size_t)((b * 8 + h) * NSP + col)) * HD + d0) = pk;
            } else {
                #pragma unroll
                for (int i = 0; i < 4; i++) {
                    float v = acc[m][n][i] + bias[row0 + i];
                    vt[((size_t)((b * 8 + h) * HD + d0 + i)) * NSP + col] = f2bf(v);
                }
            }
        }
    }
}

// ---------------- K5b: proj GEMM (reads att bf16, adds residuals) ----------------
__global__ void k_gemm_proj(const unsigned short* __restrict__ Ag,
                            const unsigned short* __restrict__ Btg,
                            const float* __restrict__ bias,
                            const float* __restrict__ gfeat,
                            const float* __restrict__ xres,
                            float* __restrict__ out) {
    int n0 = blockIdx.x * 128, m0 = blockIdx.y * 64, b = blockIdx.z;
    int t = threadIdx.x, lane = t & 63, w = t >> 6;
    int wm = w >> 1, wn = w & 1;
    __shared__ short A_lds[64][40];
    __shared__ short B_lds[128][40];
    const unsigned short* Bb = Btg + (size_t)b * NSP * CH;
    f32x4 acc[2][4];
    #pragma unroll
    for (int m = 0; m < 2; m++)
        #pragma unroll
        for (int n = 0; n < 4; n++) acc[m][n] = (f32x4){0.f, 0.f, 0.f, 0.f};
    int arow = t >> 2, akk = (t & 3) * 8;
    for (int k0 = 0; k0 < 256; k0 += 32) {
        __syncthreads();
        *(uint4*)&A_lds[arow][akk] = *(const uint4*)(Ag + (size_t)(m0 + arow) * CH + k0 + akk);
        #pragma unroll
        for (int hh = 0; hh < 2; hh++) {
            int f = t + hh * 256;
            int j = f >> 2, kk = (f & 3) * 8;
            *(uint4*)&B_lds[j][kk] = *(const uint4*)(Bb + (size_t)(n0 + j) * CH + k0 + kk);
        }
        __syncthreads();
        short8 a[2], bf[4];
        #pragma unroll
        for (int m = 0; m < 2; m++)
            a[m] = *(const short8*)&A_lds[wm * 32 + m * 16 + (lane & 15)][(lane >> 4) * 8];
        #pragma unroll
        for (int n = 0; n < 4; n++)
            bf[n] = *(const short8*)&B_lds[wn * 64 + n * 16 + (lane & 15)][(lane >> 4) * 8];
        #pragma unroll
        for (int m = 0; m < 2; m++)
            #pragma unroll
            for (int n = 0; n < 4; n++)
                acc[m][n] = __builtin_amdgcn_mfma_f32_16x16x32_bf16(a[m], bf[n], acc[m][n], 0, 0, 0);
    }
    int rbase = m0 + wm * 32 + ((lane >> 4) << 2);
    int cbase = n0 + wn * 64 + (lane & 15);
    #pragma unroll
    for (int m = 0; m < 2; m++) {
        #pragma unroll
        for (int n = 0; n < 4; n++) {
            int col = cbase + n * 16;
            #pragma unroll
            for (int i = 0; i < 4; i++) {
                int row = rbase + m * 16 + i;
                float add = bias[row] + 0.1f * gfeat[b * CH + row]
                          + xres[((size_t)(b * CH + row)) * NSP + col];
                out[((size_t)(b * CH + row)) * NSP + col] = acc[m][n][i] + add;
            }
        }
    }
}

// ------------- K6: 32x32 MFMA flash attention, dbuf LDS, in-register P -------------
// S^T = mfma(K,Q): lane holds S[j][q=lane&31], j = jt*32 + (r&3) + 8*(r>>2) + 4*hi.
// P stays in registers: cvt_pk pairs + shfl_xor(32) build PV B-frags (T12).
// O^T = mfma(V,P): lane holds O[d=(r&3)+8*(r>>2)+4*hi][q=lane&31].
// K_lds rows padded to 80B (20 banks): conflict-free. Double-buffered K/V:
// ONE barrier per tile; ds-writes of tile i+1 overlap compute of tile i (T3-lite).
__global__ __launch_bounds__(256)
void k_flash32(const unsigned short* __restrict__ qt,
               const unsigned short* __restrict__ kt,
               const unsigned short* __restrict__ vt,
               unsigned short* __restrict__ opart, float* __restrict__ lmpart) {
    const int h = blockIdx.y, b = blockIdx.z;
    const int s = blockIdx.x >> 5;
    const int t = threadIdx.x, lane = t & 63, w = t >> 6;
    const int lo32 = lane & 31, hi = lane >> 5;
    const int q0 = (blockIdx.x & 31) * 128 + w * 32;
    const int j0base = s * (NSP / NSPLIT);
    const unsigned short* qp = qt + ((size_t)(b * 8 + h) * NSP) * HD;
    const unsigned short* kp = kt + ((size_t)(b * 8 + h) * NSP) * HD;
    const unsigned short* vp = vt + ((size_t)(b * 8 + h) * HD) * NSP;
    __shared__ __align__(16) unsigned short K_lds[2][64 * 40];  // 80B rows, conflict-free
    __shared__ __align__(16) unsigned short V_lds[2][32 * 64];  // 128B rows, XOR slot swizzle

    short8 qf0 = *(const short8*)(qp + (size_t)(q0 + lo32) * HD + hi * 8);
    short8 qf1 = *(const short8*)(qp + (size_t)(q0 + lo32) * HD + 16 + hi * 8);
    f32x16 oacc;
    #pragma unroll
    for (int i = 0; i < 16; i++) oacc[i] = 0.f;
    float m = -1e30f, l = 0.f;

    // staging: K remapped so 8-lane phases hit rows 0-7 (bank-tiling); 1KB-coalesced/wave
    const int krow = (t & 7) + 8 * (t >> 5);
    const int kslot = (t >> 3) & 3;
    const int vd = t >> 3, vslot = t & 7;
    const unsigned short* kga = kp + (size_t)(j0base + krow) * HD + kslot * 8;
    const unsigned short* vga = vp + (size_t)vd * NSP + j0base + vslot * 8;
    const int kws = krow * 40 + kslot * 8;
    const int vws = vd * 64 + ((vslot ^ (vd & 7)) * 8);

    const int NT = NSP / NSPLIT / 64;
    // prologue: tile0 -> buf0; prefetch tile1 into regs
    uint4 kreg = *(const uint4*)kga;
    uint4 vreg = *(const uint4*)vga;
    *(uint4*)&K_lds[0][kws] = kreg;
    *(uint4*)&V_lds[0][vws] = vreg;
    kreg = *(const uint4*)(kga + (size_t)64 * HD);
    vreg = *(const uint4*)(vga + 64);

    for (int it = 0; it < NT; ++it) {
        const int cur = it & 1;
        __syncthreads();   // buf[cur] ready; everyone done reading buf[cur^1]
        if (it + 1 < NT) { // write next tile to the other buffer (overlaps compute)
            *(uint4*)&K_lds[cur ^ 1][kws] = kreg;
            *(uint4*)&V_lds[cur ^ 1][vws] = vreg;
        }
        if (it + 2 < NT) { // prefetch tile it+2 into regs (lands under compute)
            kreg = *(const uint4*)(kga + (size_t)(it + 2) * 64 * HD);
            vreg = *(const uint4*)(vga + (it + 2) * 64);
        }
        const unsigned short* Kb = &K_lds[cur][0];
        const unsigned short* Vb = &V_lds[cur][0];
        // ---- S^T = K Q^T : two 32x32 tiles, K=32 chained as 2x k16 ----
        const int jA = lo32, jB = 32 + lo32;
        short8 k00 = *(const short8*)&Kb[jA * 40 + hi * 8];
        short8 k01 = *(const short8*)&Kb[jA * 40 + (2 + hi) * 8];
        short8 k10 = *(const short8*)&Kb[jB * 40 + hi * 8];
        short8 k11 = *(const short8*)&Kb[jB * 40 + (2 + hi) * 8];
        f32x16 sv0, sv1;
        __builtin_amdgcn_s_setprio(1);
        sv0 = __builtin_amdgcn_mfma_f32_32x32x16_bf16(k00, qf0, ZERO16, 0, 0, 0);
        sv0 = __builtin_amdgcn_mfma_f32_32x32x16_bf16(k01, qf1, sv0, 0, 0, 0);
        sv1 = __builtin_amdgcn_mfma_f32_32x32x16_bf16(k10, qf0, ZERO16, 0, 0, 0);
        sv1 = __builtin_amdgcn_mfma_f32_32x32x16_bf16(k11, qf1, sv1, 0, 0, 0);
        __builtin_amdgcn_s_setprio(0);
        // ---- row max: v_max3 triples + shfl partner exchange ----
        float h0 = fmaxf(fmaxf(sv0[0],  sv0[1]),  sv0[2]);
        float h1 = fmaxf(fmaxf(sv0[3],  sv0[4]),  sv0[5]);
        float h2 = fmaxf(fmaxf(sv0[6],  sv0[7]),  sv0[8]);
        float h3 = fmaxf(fmaxf(sv0[9],  sv0[10]), sv0[11]);
        float h4 = fmaxf(fmaxf(sv0[12], sv0[13]), sv0[14]);
        float h5 = fmaxf(fmaxf(sv1[0],  sv1[1]),  sv1[2]);
        float h6 = fmaxf(fmaxf(sv1[3],  sv1[4]),  sv1[5]);
        float h7 = fmaxf(fmaxf(sv1[6],  sv1[7]),  sv1[8]);
        float h8 = fmaxf(fmaxf(sv1[9],  sv1[10]), sv1[11]);
        float h9 = fmaxf(fmaxf(sv1[12], sv1[13]), sv1[14]);
        float r0 = fmaxf(fmaxf(h0, h1), h2);
        float r1 = fmaxf(fmaxf(h3, h4), h5);
        float r2 = fmaxf(fmaxf(h6, h7), h8);
        float r3 = fmaxf(fmaxf(h9, sv0[15]), sv1[15]);
        float vmx = fmaxf(fmaxf(r0, r1), fmaxf(r2, r3));
        vmx = fmaxf(vmx, __shfl_xor(vmx, 32));
        // ---- T13 defer-max: rescale only when max grew by > 8 (log2 units) ----
        if (__any(vmx > m + 8.f)) {
            float nm = fmaxf(m, vmx);
            float corr = __builtin_amdgcn_exp2f(m - nm);
            m = nm;
            l *= corr;
            oacc *= corr;   // vector op -> v_pk_mul_f32
        }
        sv0 -= m;           // vector op -> v_pk_add_f32 x8
        sv1 -= m;
        #pragma unroll
        for (int i = 0; i < 16; i++) {
            sv0[i] = __builtin_amdgcn_exp2f(sv0[i]);
            sv1[i] = __builtin_amdgcn_exp2f(sv1[i]);
        }
        // ---- row sum: v_pk_add_f32 tree + shfl partner exchange ----
        {
            #define SH2(V, I) __builtin_shufflevector(V, V, 2*(I), 2*(I)+1)
            f32x2 t0 = (SH2(sv0,0) + SH2(sv0,1)) + (SH2(sv0,2) + SH2(sv0,3));
            f32x2 t1 = (SH2(sv0,4) + SH2(sv0,5)) + (SH2(sv0,6) + SH2(sv0,7));
            f32x2 t2 = (SH2(sv1,0) + SH2(sv1,1)) + (SH2(sv1,2) + SH2(sv1,3));
            f32x2 t3 = (SH2(sv1,4) + SH2(sv1,5)) + (SH2(sv1,6) + SH2(sv1,7));
            f32x2 tt = (t0 + t1) + (t2 + t3);
            float sm = tt[0] + tt[1];
            #undef SH2
            sm += __shfl_xor(sm, 32);
            l += sm;
        }
        // ---- P->bf16 + shfl_xor(32) exchange (r5-proven form); O^T += V P ----
        #define PVSTEP(SV, BB, C) { \
            unsigned p0 = pkbf(SV[BB + 0], SV[BB + 1]); \
            unsigned p1 = pkbf(SV[BB + 2], SV[BB + 3]); \
            unsigned p2 = pkbf(SV[BB + 4], SV[BB + 5]); \
            unsigned p3 = pkbf(SV[BB + 6], SV[BB + 7]); \
            unsigned s0 = hi ? p0 : p2, s1 = hi ? p1 : p3; \
            unsigned r0 = __shfl_xor(s0, 32), r1 = __shfl_xor(s1, 32); \
            uint4 fu = hi ? make_uint4(r0, r1, p2, p3) : make_uint4(p0, p1, r0, r1); \
            short8 pa = *(short8*)&fu; \
            short8 vf = *(const short8*)&Vb[lo32 * 64 + ((((C) * 2 + hi) ^ (lo32 & 7)) * 8)]; \
            oacc = __builtin_amdgcn_mfma_f32_32x32x16_bf16(vf, pa, oacc, 0, 0, 0); \
        }
        __builtin_amdgcn_s_setprio(1);
        PVSTEP(sv0, 0, 0)
        PVSTEP(sv0, 8, 1)
        PVSTEP(sv1, 0, 2)
        PVSTEP(sv1, 8, 3)
        __builtin_amdgcn_s_setprio(0);
        #undef PVSTEP
    }
    // bf16 unnormalized partials: lane q = q0+lo32, d = 8*rr + 4*hi + 0..3
    unsigned short* op = opart + ((((size_t)s * BATCH + b) * HEADS + h) * NSP + q0 + lo32) * HD;
    #pragma unroll
    for (int rr = 0; rr < 4; rr++) {
        ushort4 pk4;
        pk4.x = f2bf(oacc[rr * 4 + 0]);
        pk4.y = f2bf(oacc[rr * 4 + 1]);
        pk4.z = f2bf(oacc[rr * 4 + 2]);
        pk4.w = f2bf(oacc[rr * 4 + 3]);
        *(ushort4*)(op + rr * 8 + hi * 4) = pk4;
    }
    if (hi == 0)
        *(float2*)(lmpart + ((((size_t)s * BATCH + b) * HEADS + h) * NSP + q0 + lo32) * 2)
            = make_float2(m, l);
}

// ------------- K7: combine NSPLIT partials -> att bf16 (b,p,c) -------------
__global__ __launch_bounds__(256)
void k_combine(const unsigned short* __restrict__ opart, const float* __restrict__ lmpart,
               unsigned short* __restrict__ att) {
    int flat = blockIdx.x * 256 + threadIdx.x;   // 2*8*4096*4 = 262144
    int dchunk = flat & 3;
    int q = (flat >> 2) & (NSP - 1);
    int bh = flat >> 14;
    const size_t sO = (size_t)BATCH * HEADS * NSP * HD;
    const size_t sL = (size_t)BATCH * HEADS * NSP * 2;
    size_t rowq = (size_t)bh * NSP + q;
    float2 lm[NSPLIT];
    float M = -1e30f;
    #pragma unroll
    for (int s2 = 0; s2 < NSPLIT; s2++) {
        lm[s2] = *(const float2*)(lmpart + s2 * sL + rowq * 2);
        M = fmaxf(M, lm[s2].x);
    }
    float den = 0.f, cw[NSPLIT];
    #pragma unroll
    for (int s2 = 0; s2 < NSPLIT; s2++) {
        cw[s2] = __builtin_amdgcn_exp2f(lm[s2].x - M);
        den += lm[s2].y * cw[s2];
    }
    float inv = 1.0f / den;
    float acc[8];
    #pragma unroll
    for (int e = 0; e < 8; e++) acc[e] = 0.f;
    #pragma unroll
    for (int s2 = 0; s2 < NSPLIT; s2++) {
        uint4 v = *(const uint4*)(opart + s2 * sO + rowq * HD + dchunk * 8);
        float wgt = cw[s2] * inv;
        const unsigned short* pv = (const unsigned short*)&v;
        #pragma unroll
        for (int e = 0; e < 8; e++) {
            unsigned u = (unsigned)pv[e] << 16;
            acc[e] += wgt * *(float*)&u;
        }
    }
    uint4 o;
    o.x = (unsigned)f2bf(acc[0]) | ((unsigned)f2bf(acc[1]) << 16);
    o.y = (unsigned)f2bf(acc[2]) | ((unsigned)f2bf(acc[3]) << 16);
    o.z = (unsigned)f2bf(acc[4]) | ((unsigned)f2bf(acc[5]) << 16);
    o.w = (unsigned)f2bf(acc[6]) | ((unsigned)f2bf(acc[7]) << 16);
    *(uint4*)(att + ((size_t)((bh >> 3) * NSP + q)) * CH + (bh & 7) * HD + dchunk * 8) = o;
}

extern "C" void kernel_launch(void* const* d_in, const int* in_sizes, int n_in,
                              void* d_out, int out_size, void* d_ws, size_t ws_size,
                              hipStream_t stream) {
    const float* x       = (const float*)d_in[0];
    const float* gn_w    = (const float*)d_in[1];
    const float* gn_b    = (const float*)d_in[2];
    const float* qkv_w   = (const float*)d_in[3];
    const float* qkv_b   = (const float*)d_in[4];
    const float* proj_w  = (const float*)d_in[5];
    const float* proj_b  = (const float*)d_in[6];
    const float* gproj_w = (const float*)d_in[7];
    const float* gproj_b = (const float*)d_in[8];
    char* ws = (char*)d_ws;
    float*          stats  = (float*)(ws);                      // 512 B
    float*          gpart  = (float*)(ws + 1024);               // 128 KB
    float*          gfeat  = (float*)(ws + 132096);             // 2 KB
    unsigned short* wbf    = (unsigned short*)(ws + 134144);    // 512 KB bf16 weights
    unsigned short* xnt    = (unsigned short*)(ws + 658432);    // (b,p,c) bf16, 4 MB (dead after qkv GEMM)
    float*          lmpart = (float*)(ws + 658432);             // overlays xnt: 2 MB {m,l}
    unsigned short* qt     = (unsigned short*)(ws + 4852736);   // (b,h,n,hd) bf16, 4 MB
    unsigned short* kt     = (unsigned short*)(ws + 9047040);   // (b,h,n,hd) bf16, 4 MB
    unsigned short* vt     = (unsigned short*)(ws + 13241344);  // (b,h,hd,n) bf16, 4 MB
    unsigned short* att    = (unsigned short*)(ws + 17435648);  // (b,p,c) bf16, 4 MB
    unsigned short* opart  = (unsigned short*)(ws + 21629952);  // 4 splits bf16 O, 16.8 MB
    float* out = (float*)d_out;

    hipLaunchKernelGGL(k_gnstats, dim3(64), dim3(256), 0, stream, x, stats);
    hipLaunchKernelGGL(k_gnapply, dim3(64, 4, 2), dim3(256), 0, stream,
                       x, gn_w, gn_b, stats, xnt, gpart);
    hipLaunchKernelGGL(k_gproj, dim3(2), dim3(256), 0, stream,
                       gpart, gproj_w, gproj_b, gfeat);
    hipLaunchKernelGGL(k_convert, dim3(256), dim3(256), 0, stream, qkv_w, proj_w, wbf);
    hipLaunchKernelGGL(k_gemm_qkv, dim3(32, 12, 2), dim3(256), 0, stream,
                       wbf, xnt, qkv_b, gfeat, qt, kt, vt);
    hipLaunchKernelGGL(k_flash32, dim3(32 * NSPLIT, 8, 2), dim3(256), 0, stream,
                       qt, kt, vt, opart, lmpart);
    hipLaunchKernelGGL(k_combine, dim3(1024), dim3(256), 0, stream,
                       opart, lmpart, att);
    hipLaunchKernelGGL(k_gemm_proj, dim3(32, 4, 2), dim3(256), 0, stream,
                       wbf + 196608, att, proj_b, gfeat, x, out);
}

// Round 10
// 122.201 us; speedup vs baseline: 1.0586x; 1.0586x over previous
//
#include <hip/hip_runtime.h>
#include <hip/hip_bf16.h>
#include <stdint.h>

#define BATCH 2
#define CH 256
#define NSP 4096          // 64*64 spatial
#define HEADS 8
#define HD 32
#define GROUPS 32
#define EPS_GN 1e-5f
#define NSPLIT 4          // flash KV-sequence splits

// hd^-0.5 * log2(e): folds softmax scale AND exp->exp2 conversion into k
#define ATT_SCALE (0.17677669529663687f * 1.4426950408889634f)

typedef __attribute__((ext_vector_type(8))) short short8;    // 8 bf16 (MFMA A/B frag)
typedef __attribute__((ext_vector_type(4))) float f32x4;     // 16x16 C/D frag
typedef __attribute__((ext_vector_type(16))) float f32x16;   // 32x32 C/D frag
typedef __attribute__((ext_vector_type(2))) float f32x2;     // v_pk_add_f32 operand

#define ZERO16 ((f32x16){0.f,0.f,0.f,0.f,0.f,0.f,0.f,0.f,0.f,0.f,0.f,0.f,0.f,0.f,0.f,0.f})

static __device__ __forceinline__ unsigned short f2bf(float f) {
    union { float f; unsigned u; } v; v.f = f;
    unsigned r = v.u + 0x7fffu + ((v.u >> 16) & 1u);  // RNE
    return (unsigned short)(r >> 16);
}
static __device__ __forceinline__ unsigned pkbf(float x, float y) {
    __hip_bfloat162 h = __float22bfloat162_rn(make_float2(x, y));  // -> v_cvt_pk_bf16_f32
    return *(unsigned*)&h;
}

// ---------------- K1: GroupNorm stats: one block per (b,group) ----------------
__global__ void k_gnstats(const float* __restrict__ x, float* __restrict__ stats) {
    int bg = blockIdx.x;
    int t = threadIdx.x;
    const float4* b4 = (const float4*)(x + (size_t)bg * (8 * NSP));
    float s = 0.f, sq = 0.f;
    #pragma unroll
    for (int i = 0; i < 32; i++) {
        float4 v = b4[t + i * 256];
        s  += v.x + v.y + v.z + v.w;
        sq += v.x * v.x + v.y * v.y + v.z * v.z + v.w * v.w;
    }
    #pragma unroll
    for (int off = 32; off > 0; off >>= 1) {
        s  += __shfl_down(s, off);
        sq += __shfl_down(sq, off);
    }
    __shared__ float rs[4], rq[4];
    int w = t >> 6;
    if ((t & 63) == 0) { rs[w] = s; rq[w] = sq; }
    __syncthreads();
    if (t == 0) {
        float S = rs[0] + rs[1] + rs[2] + rs[3];
        float Q = rq[0] + rq[1] + rq[2] + rq[3];
        float mu  = S * (1.0f / 32768.0f);
        float var = Q * (1.0f / 32768.0f) - mu * mu;
        stats[bg * 2]     = mu;
        stats[bg * 2 + 1] = rsqrtf(var + EPS_GN);
    }
}

// ------ K2: apply GN, write xn^T (b,p,c) bf16, per-channel partial sums ------
__global__ void k_gnapply(const float* __restrict__ x, const float* __restrict__ gn_w,
                          const float* __restrict__ gn_b, const float* __restrict__ stats,
                          unsigned short* __restrict__ xnt, float* __restrict__ gpart) {
    int p0 = blockIdx.x * 64, c0 = blockIdx.y * 64, b = blockIdx.z;
    int t = threadIdx.x;
    __shared__ float tile[64][65];
    int ci0 = t >> 4, pq = t & 15;
    #pragma unroll
    for (int k = 0; k < 4; k++) {
        int ci = ci0 + k * 16;
        int c = c0 + ci;
        float mu   = stats[(b * GROUPS + (c >> 3)) * 2];
        float rstd = stats[(b * GROUPS + (c >> 3)) * 2 + 1];
        float w  = gn_w[c] * rstd;
        float bb = gn_b[c] - mu * w;
        float4 v = *(const float4*)(x + ((size_t)(b * CH + c)) * NSP + p0 + pq * 4);
        tile[ci][pq * 4 + 0] = v.x * w + bb;
        tile[ci][pq * 4 + 1] = v.y * w + bb;
        tile[ci][pq * 4 + 2] = v.z * w + bb;
        tile[ci][pq * 4 + 3] = v.w * w + bb;
    }
    __syncthreads();
    int pi = t >> 2, cb = (t & 3) * 16;
    unsigned pack[8];
    #pragma unroll
    for (int e = 0; e < 8; e++) {
        float a  = tile[cb + 2 * e][pi];
        float bv = tile[cb + 2 * e + 1][pi];
        pack[e] = (unsigned)f2bf(a) | ((unsigned)f2bf(bv) << 16);
    }
    uint4* dst = (uint4*)(xnt + ((size_t)(b * NSP + p0 + pi)) * CH + c0 + cb);
    dst[0] = make_uint4(pack[0], pack[1], pack[2], pack[3]);
    dst[1] = make_uint4(pack[4], pack[5], pack[6], pack[7]);
    if (t < 64) {
        float s = 0.f;
        #pragma unroll
        for (int j = 0; j < 64; j++) s += tile[t][j];
        gpart[((size_t)(b * CH + c0 + t)) * 64 + blockIdx.x] = s;
    }
}

// -------- K3: gfeat = mean(xn) @ gproj_w^T + gproj_b --------
__global__ void k_gproj(const float* __restrict__ gpart, const float* __restrict__ gproj_w,
                        const float* __restrict__ gproj_b, float* __restrict__ gfeat) {
    int b = blockIdx.x, t = threadIdx.x;
    __shared__ float graw[256];
    const float* p = gpart + ((size_t)(b * CH + t)) * 64;
    float s = 0.f;
    #pragma unroll
    for (int i = 0; i < 64; i++) s += p[i];
    graw[t] = s * (1.0f / 4096.0f);
    __syncthreads();
    float acc = gproj_b[t];
    const float* wr = gproj_w + (size_t)t * CH;
    #pragma unroll 8
    for (int c = 0; c < 256; c++) acc += graw[c] * wr[c];
    gfeat[b * CH + t] = acc;
}

// ---------------- K4: convert qkv_w + proj_w to bf16 ----------------
__global__ void k_convert(const float* __restrict__ qkv_w, const float* __restrict__ proj_w,
                          unsigned short* __restrict__ wbf) {
    int i4 = blockIdx.x * 256 + threadIdx.x;
    const float* src = (i4 < 49152) ? (qkv_w + (size_t)i4 * 4)
                                    : (proj_w + (size_t)(i4 - 49152) * 4);
    float4 v = *(const float4*)src;
    ushort4 o;
    o.x = f2bf(v.x); o.y = f2bf(v.y); o.z = f2bf(v.z); o.w = f2bf(v.w);
    *(ushort4*)(wbf + (size_t)i4 * 4) = o;
}

// ---------------- K5a: QKV GEMM -> bf16 q/k/v in attention layouts ----------------
__global__ void k_gemm_qkv(const unsigned short* __restrict__ Ag,
                           const unsigned short* __restrict__ Btg,
                           const float* __restrict__ bias,
                           const float* __restrict__ gfeat,
                           unsigned short* __restrict__ qt,
                           unsigned short* __restrict__ kt,
                           unsigned short* __restrict__ vt) {
    int n0 = blockIdx.x * 128, m0 = blockIdx.y * 64, b = blockIdx.z;
    int t = threadIdx.x, lane = t & 63, w = t >> 6;
    int wm = w >> 1, wn = w & 1;
    __shared__ short A_lds[64][40];
    __shared__ short B_lds[128][40];
    const unsigned short* Bb = Btg + (size_t)b * NSP * CH;
    f32x4 acc[2][4];
    #pragma unroll
    for (int m = 0; m < 2; m++)
        #pragma unroll
        for (int n = 0; n < 4; n++) acc[m][n] = (f32x4){0.f, 0.f, 0.f, 0.f};
    int arow = t >> 2, akk = (t & 3) * 8;
    for (int k0 = 0; k0 < 256; k0 += 32) {
        __syncthreads();
        *(uint4*)&A_lds[arow][akk] = *(const uint4*)(Ag + (size_t)(m0 + arow) * CH + k0 + akk);
        #pragma unroll
        for (int hh = 0; hh < 2; hh++) {
            int f = t + hh * 256;
            int j = f >> 2, kk = (f & 3) * 8;
            *(uint4*)&B_lds[j][kk] = *(const uint4*)(Bb + (size_t)(n0 + j) * CH + k0 + kk);
        }
        __syncthreads();
        short8 a[2], bf[4];
        #pragma unroll
        for (int m = 0; m < 2; m++)
            a[m] = *(const short8*)&A_lds[wm * 32 + m * 16 + (lane & 15)][(lane >> 4) * 8];
        #pragma unroll
        for (int n = 0; n < 4; n++)
            bf[n] = *(const short8*)&B_lds[wn * 64 + n * 16 + (lane & 15)][(lane >> 4) * 8];
        #pragma unroll
        for (int m = 0; m < 2; m++)
            #pragma unroll
            for (int n = 0; n < 4; n++)
                acc[m][n] = __builtin_amdgcn_mfma_f32_16x16x32_bf16(a[m], bf[n], acc[m][n], 0, 0, 0);
    }
    int rbase = m0 + wm * 32 + ((lane >> 4) << 2);
    int cbase = n0 + wn * 64 + (lane & 15);
    #pragma unroll
    for (int m = 0; m < 2; m++) {
        int row0 = rbase + m * 16;
        int sec = row0 >> 8;
        int ch  = row0 & 255;
        int h = ch >> 5, d0 = ch & 31;
        #pragma unroll
        for (int n = 0; n < 4; n++) {
            int col = cbase + n * 16;
            if (sec == 0) {
                ushort4 pk;
                pk.x = f2bf(acc[m][n][0] + bias[row0 + 0]);
                pk.y = f2bf(acc[m][n][1] + bias[row0 + 1]);
                pk.z = f2bf(acc[m][n][2] + bias[row0 + 2]);
                pk.w = f2bf(acc[m][n][3] + bias[row0 + 3]);
                *(ushort4*)(qt + ((size_t)((b * 8 + h) * NSP + col)) * HD + d0) = pk;
            } else if (sec == 1) {
                ushort4 pk;
                #pragma unroll
                for (int i = 0; i < 4; i++) {
                    float v = (acc[m][n][i] + bias[row0 + i]
                               + 0.1f * gfeat[b * CH + ch + i]) * ATT_SCALE;
                    ((unsigned short*)&pk)[i] = f2bf(v);
                }
                *(ushort4*)(kt + ((size_t)((b * 8 + h) * NSP + col)) * HD + d0) = pk;
            } else {
                #pragma unroll
                for (int i = 0; i < 4; i++) {
                    float v = acc[m][n][i] + bias[row0 + i];
                    vt[((size_t)((b * 8 + h) * HD + d0 + i)) * NSP + col] = f2bf(v);
                }
            }
        }
    }
}

// ---------------- K5b: proj GEMM (reads att bf16, adds residuals) ----------------
__global__ void k_gemm_proj(const unsigned short* __restrict__ Ag,
                            const unsigned short* __restrict__ Btg,
                            const float* __restrict__ bias,
                            const float* __restrict__ gfeat,
                            const float* __restrict__ xres,
                            float* __restrict__ out) {
    int n0 = blockIdx.x * 128, m0 = blockIdx.y * 64, b = blockIdx.z;
    int t = threadIdx.x, lane = t & 63, w = t >> 6;
    int wm = w >> 1, wn = w & 1;
    __shared__ short A_lds[64][40];
    __shared__ short B_lds[128][40];
    const unsigned short* Bb = Btg + (size_t)b * NSP * CH;
    f32x4 acc[2][4];
    #pragma unroll
    for (int m = 0; m < 2; m++)
        #pragma unroll
        for (int n = 0; n < 4; n++) acc[m][n] = (f32x4){0.f, 0.f, 0.f, 0.f};
    int arow = t >> 2, akk = (t & 3) * 8;
    for (int k0 = 0; k0 < 256; k0 += 32) {
        __syncthreads();
        *(uint4*)&A_lds[arow][akk] = *(const uint4*)(Ag + (size_t)(m0 + arow) * CH + k0 + akk);
        #pragma unroll
        for (int hh = 0; hh < 2; hh++) {
            int f = t + hh * 256;
            int j = f >> 2, kk = (f & 3) * 8;
            *(uint4*)&B_lds[j][kk] = *(const uint4*)(Bb + (size_t)(n0 + j) * CH + k0 + kk);
        }
        __syncthreads();
        short8 a[2], bf[4];
        #pragma unroll
        for (int m = 0; m < 2; m++)
            a[m] = *(const short8*)&A_lds[wm * 32 + m * 16 + (lane & 15)][(lane >> 4) * 8];
        #pragma unroll
        for (int n = 0; n < 4; n++)
            bf[n] = *(const short8*)&B_lds[wn * 64 + n * 16 + (lane & 15)][(lane >> 4) * 8];
        #pragma unroll
        for (int m = 0; m < 2; m++)
            #pragma unroll
            for (int n = 0; n < 4; n++)
                acc[m][n] = __builtin_amdgcn_mfma_f32_16x16x32_bf16(a[m], bf[n], acc[m][n], 0, 0, 0);
    }
    int rbase = m0 + wm * 32 + ((lane >> 4) << 2);
    int cbase = n0 + wn * 64 + (lane & 15);
    #pragma unroll
    for (int m = 0; m < 2; m++) {
        #pragma unroll
        for (int n = 0; n < 4; n++) {
            int col = cbase + n * 16;
            #pragma unroll
            for (int i = 0; i < 4; i++) {
                int row = rbase + m * 16 + i;
                float add = bias[row] + 0.1f * gfeat[b * CH + row]
                          + xres[((size_t)(b * CH + row)) * NSP + col];
                out[((size_t)(b * CH + row)) * NSP + col] = acc[m][n][i] + add;
            }
        }
    }
}

// ------------- K6: 32x32 MFMA flash attention, NO-MAX unnormalized softmax -------------
// S^T = mfma(K,Q): lane holds S[j][q=lane&31], j = jt*32 + (r&3) + 8*(r>>2) + 4*hi.
// P' = exp2(S) UNNORMALIZED (valid: |S| <~ 20 << 127, fp32/bf16 scale-invariant;
// the softmax max cancels in O = sum(O'_s)/sum(l'_s) across splits).
// P stays in registers: cvt_pk pairs + shfl_xor(32) build PV B-frags (T12).
// O^T = mfma(V,P): lane holds O[d=(r&3)+8*(r>>2)+4*hi][q=lane&31].
// K_lds rows padded to 80B (20 banks): conflict-free. r8-proven single-buffer staging.
__global__ __launch_bounds__(256)
void k_flash32(const unsigned short* __restrict__ qt,
               const unsigned short* __restrict__ kt,
               const unsigned short* __restrict__ vt,
               unsigned short* __restrict__ opart, float* __restrict__ lpart) {
    const int h = blockIdx.y, b = blockIdx.z;
    const int s = blockIdx.x >> 5;
    const int t = threadIdx.x, lane = t & 63, w = t >> 6;
    const int lo32 = lane & 31, hi = lane >> 5;
    const int q0 = (blockIdx.x & 31) * 128 + w * 32;
    const int j0base = s * (NSP / NSPLIT);
    const unsigned short* qp = qt + ((size_t)(b * 8 + h) * NSP) * HD;
    const unsigned short* kp = kt + ((size_t)(b * 8 + h) * NSP) * HD;
    const unsigned short* vp = vt + ((size_t)(b * 8 + h) * HD) * NSP;
    __shared__ __align__(16) unsigned short K_lds[64 * 40];   // 80B rows, conflict-free
    __shared__ __align__(16) unsigned short V_lds[32 * 64];   // 128B rows, XOR slot swizzle

    short8 qf0 = *(const short8*)(qp + (size_t)(q0 + lo32) * HD + hi * 8);
    short8 qf1 = *(const short8*)(qp + (size_t)(q0 + lo32) * HD + 16 + hi * 8);
    f32x16 oacc;
    #pragma unroll
    for (int i = 0; i < 16; i++) oacc[i] = 0.f;
    float l = 0.f;

    // staging: K remapped so 8-lane phases hit rows 0-7 (bank-tiling); 1KB-coalesced/wave
    const int krow = (t & 7) + 8 * (t >> 5);
    const int kslot = (t >> 3) & 3;
    const int vd = t >> 3, vslot = t & 7;
    const unsigned short* kga = kp + (size_t)(j0base + krow) * HD + kslot * 8;
    const unsigned short* vga = vp + (size_t)vd * NSP + j0base + vslot * 8;
    uint4 kreg = *(const uint4*)kga;
    uint4 vreg = *(const uint4*)vga;
    const int kws = krow * 40 + kslot * 8;
    const int vws = vd * 64 + ((vslot ^ (vd & 7)) * 8);

    const int NT = NSP / NSPLIT / 64;
    for (int it = 0; it < NT; ++it) {
        *(uint4*)&K_lds[kws] = kreg;
        *(uint4*)&V_lds[vws] = vreg;
        __syncthreads();
        if (it + 1 < NT) {   // T14: issue next-tile loads; land under compute
            kreg = *(const uint4*)(kga + (size_t)(it + 1) * 64 * HD);
            vreg = *(const uint4*)(vga + (it + 1) * 64);
        }
        // ---- S^T = K Q^T : two 32x32 tiles, K=32 chained as 2x k16 ----
        const int jA = lo32, jB = 32 + lo32;
        short8 k00 = *(const short8*)&K_lds[jA * 40 + hi * 8];
        short8 k01 = *(const short8*)&K_lds[jA * 40 + (2 + hi) * 8];
        short8 k10 = *(const short8*)&K_lds[jB * 40 + hi * 8];
        short8 k11 = *(const short8*)&K_lds[jB * 40 + (2 + hi) * 8];
        f32x16 sv0, sv1;
        __builtin_amdgcn_s_setprio(1);
        sv0 = __builtin_amdgcn_mfma_f32_32x32x16_bf16(k00, qf0, ZERO16, 0, 0, 0);
        sv0 = __builtin_amdgcn_mfma_f32_32x32x16_bf16(k01, qf1, sv0, 0, 0, 0);
        sv1 = __builtin_amdgcn_mfma_f32_32x32x16_bf16(k10, qf0, ZERO16, 0, 0, 0);
        sv1 = __builtin_amdgcn_mfma_f32_32x32x16_bf16(k11, qf1, sv1, 0, 0, 0);
        __builtin_amdgcn_s_setprio(0);
        // ---- P' = exp2(S), unnormalized (no max tracking) ----
        #pragma unroll
        for (int i = 0; i < 16; i++) {
            sv0[i] = __builtin_amdgcn_exp2f(sv0[i]);
            sv1[i] = __builtin_amdgcn_exp2f(sv1[i]);
        }
        // ---- row sum: v_pk_add_f32 tree + shfl partner exchange ----
        {
            #define SH2(V, I) __builtin_shufflevector(V, V, 2*(I), 2*(I)+1)
            f32x2 t0 = (SH2(sv0,0) + SH2(sv0,1)) + (SH2(sv0,2) + SH2(sv0,3));
            f32x2 t1 = (SH2(sv0,4) + SH2(sv0,5)) + (SH2(sv0,6) + SH2(sv0,7));
            f32x2 t2 = (SH2(sv1,0) + SH2(sv1,1)) + (SH2(sv1,2) + SH2(sv1,3));
            f32x2 t3 = (SH2(sv1,4) + SH2(sv1,5)) + (SH2(sv1,6) + SH2(sv1,7));
            f32x2 tt = (t0 + t1) + (t2 + t3);
            float sm = tt[0] + tt[1];
            #undef SH2
            sm += __shfl_xor(sm, 32);
            l += sm;
        }
        // ---- P->bf16 + shfl_xor(32) exchange (r5-proven form); O^T += V P ----
        #define PVSTEP(SV, BB, C) { \
            unsigned p0 = pkbf(SV[BB + 0], SV[BB + 1]); \
            unsigned p1 = pkbf(SV[BB + 2], SV[BB + 3]); \
            unsigned p2 = pkbf(SV[BB + 4], SV[BB + 5]); \
            unsigned p3 = pkbf(SV[BB + 6], SV[BB + 7]); \
            unsigned s0 = hi ? p0 : p2, s1 = hi ? p1 : p3; \
            unsigned r0 = __shfl_xor(s0, 32), r1 = __shfl_xor(s1, 32); \
            uint4 fu = hi ? make_uint4(r0, r1, p2, p3) : make_uint4(p0, p1, r0, r1); \
            short8 pa = *(short8*)&fu; \
            short8 vf = *(const short8*)&V_lds[lo32 * 64 + ((((C) * 2 + hi) ^ (lo32 & 7)) * 8)]; \
            oacc = __builtin_amdgcn_mfma_f32_32x32x16_bf16(vf, pa, oacc, 0, 0, 0); \
        }
        __builtin_amdgcn_s_setprio(1);
        PVSTEP(sv0, 0, 0)
        PVSTEP(sv0, 8, 1)
        PVSTEP(sv1, 0, 2)
        PVSTEP(sv1, 8, 3)
        __builtin_amdgcn_s_setprio(0);
        #undef PVSTEP
        __syncthreads();   // protect K_lds/V_lds before next stage
    }
    // bf16 unnormalized partials: lane q = q0+lo32, d = 8*rr + 4*hi + 0..3
    unsigned short* op = opart + ((((size_t)s * BATCH + b) * HEADS + h) * NSP + q0 + lo32) * HD;
    #pragma unroll
    for (int rr = 0; rr < 4; rr++) {
        ushort4 pk4;
        pk4.x = f2bf(oacc[rr * 4 + 0]);
        pk4.y = f2bf(oacc[rr * 4 + 1]);
        pk4.z = f2bf(oacc[rr * 4 + 2]);
        pk4.w = f2bf(oacc[rr * 4 + 3]);
        *(ushort4*)(op + rr * 8 + hi * 4) = pk4;
    }
    if (hi == 0)
        lpart[(((size_t)s * BATCH + b) * HEADS + h) * NSP + q0 + lo32] = l;
}

// ------------- K7: combine NSPLIT partials -> att bf16 (b,p,c) -------------
__global__ __launch_bounds__(256)
void k_combine(const unsigned short* __restrict__ opart, const float* __restrict__ lpart,
               unsigned short* __restrict__ att) {
    int flat = blockIdx.x * 256 + threadIdx.x;   // 2*8*4096*4 = 262144
    int dchunk = flat & 3;
    int q = (flat >> 2) & (NSP - 1);
    int bh = flat >> 14;
    const size_t sO = (size_t)BATCH * HEADS * NSP * HD;
    const size_t sL = (size_t)BATCH * HEADS * NSP;
    size_t rowq = (size_t)bh * NSP + q;
    float den = 0.f;
    #pragma unroll
    for (int s2 = 0; s2 < NSPLIT; s2++) den += lpart[s2 * sL + rowq];
    float inv = 1.0f / den;
    float acc[8];
    #pragma unroll
    for (int e = 0; e < 8; e++) acc[e] = 0.f;
    #pragma unroll
    for (int s2 = 0; s2 < NSPLIT; s2++) {
        uint4 v = *(const uint4*)(opart + s2 * sO + rowq * HD + dchunk * 8);
        const unsigned short* pv = (const unsigned short*)&v;
        #pragma unroll
        for (int e = 0; e < 8; e++) {
            unsigned u = (unsigned)pv[e] << 16;
            acc[e] += *(float*)&u;
        }
    }
    uint4 o;
    o.x = (unsigned)f2bf(acc[0] * inv) | ((unsigned)f2bf(acc[1] * inv) << 16);
    o.y = (unsigned)f2bf(acc[2] * inv) | ((unsigned)f2bf(acc[3] * inv) << 16);
    o.z = (unsigned)f2bf(acc[4] * inv) | ((unsigned)f2bf(acc[5] * inv) << 16);
    o.w = (unsigned)f2bf(acc[6] * inv) | ((unsigned)f2bf(acc[7] * inv) << 16);
    *(uint4*)(att + ((size_t)((bh >> 3) * NSP + q)) * CH + (bh & 7) * HD + dchunk * 8) = o;
}

extern "C" void kernel_launch(void* const* d_in, const int* in_sizes, int n_in,
                              void* d_out, int out_size, void* d_ws, size_t ws_size,
                              hipStream_t stream) {
    const float* x       = (const float*)d_in[0];
    const float* gn_w    = (const float*)d_in[1];
    const float* gn_b    = (const float*)d_in[2];
    const float* qkv_w   = (const float*)d_in[3];
    const float* qkv_b   = (const float*)d_in[4];
    const float* proj_w  = (const float*)d_in[5];
    const float* proj_b  = (const float*)d_in[6];
    const float* gproj_w = (const float*)d_in[7];
    const float* gproj_b = (const float*)d_in[8];
    char* ws = (char*)d_ws;
    float*          stats  = (float*)(ws);                      // 512 B
    float*          gpart  = (float*)(ws + 1024);               // 128 KB
    float*          gfeat  = (float*)(ws + 132096);             // 2 KB
    unsigned short* wbf    = (unsigned short*)(ws + 134144);    // 512 KB bf16 weights
    unsigned short* xnt    = (unsigned short*)(ws + 658432);    // (b,p,c) bf16, 4 MB (dead after qkv GEMM)
    float*          lpart  = (float*)(ws + 658432);             // overlays xnt: 1 MB l per (s,q)
    unsigned short* qt     = (unsigned short*)(ws + 4852736);   // (b,h,n,hd) bf16, 4 MB
    unsigned short* kt     = (unsigned short*)(ws + 9047040);   // (b,h,n,hd) bf16, 4 MB
    unsigned short* vt     = (unsigned short*)(ws + 13241344);  // (b,h,hd,n) bf16, 4 MB
    unsigned short* att    = (unsigned short*)(ws + 17435648);  // (b,p,c) bf16, 4 MB
    unsigned short* opart  = (unsigned short*)(ws + 21629952);  // 4 splits bf16 O, 16.8 MB
    float* out = (float*)d_out;

    hipLaunchKernelGGL(k_gnstats, dim3(64), dim3(256), 0, stream, x, stats);
    hipLaunchKernelGGL(k_gnapply, dim3(64, 4, 2), dim3(256), 0, stream,
                       x, gn_w, gn_b, stats, xnt, gpart);
    hipLaunchKernelGGL(k_gproj, dim3(2), dim3(256), 0, stream,
                       gpart, gproj_w, gproj_b, gfeat);
    hipLaunchKernelGGL(k_convert, dim3(256), dim3(256), 0, stream, qkv_w, proj_w, wbf);
    hipLaunchKernelGGL(k_gemm_qkv, dim3(32, 12, 2), dim3(256), 0, stream,
                       wbf, xnt, qkv_b, gfeat, qt, kt, vt);
    hipLaunchKernelGGL(k_flash32, dim3(32 * NSPLIT, 8, 2), dim3(256), 0, stream,
                       qt, kt, vt, opart, lpart);
    hipLaunchKernelGGL(k_combine, dim3(1024), dim3(256), 0, stream,
                       opart, lpart, att);
    hipLaunchKernelGGL(k_gemm_proj, dim3(32, 4, 2), dim3(256), 0, stream,
                       wbf + 196608, att, proj_b, gfeat, x, out);
}

// Round 11
// 120.282 us; speedup vs baseline: 1.0755x; 1.0159x over previous
//
#include <hip/hip_runtime.h>
#include <hip/hip_bf16.h>
#include <stdint.h>

#define BATCH 2
#define CH 256
#define NSP 4096          // 64*64 spatial
#define HEADS 8
#define HD 32
#define GROUPS 32
#define EPS_GN 1e-5f
#define NSPLIT 4          // flash KV-sequence splits

// hd^-0.5 * log2(e): folds softmax scale AND exp->exp2 conversion into k
#define ATT_SCALE (0.17677669529663687f * 1.4426950408889634f)

typedef __attribute__((ext_vector_type(8))) short short8;    // 8 bf16 (MFMA A/B frag)
typedef __attribute__((ext_vector_type(4))) float f32x4;     // 16x16 C/D frag
typedef __attribute__((ext_vector_type(16))) float f32x16;   // 32x32 C/D frag
typedef __attribute__((ext_vector_type(2))) float f32x2;     // v_pk_add_f32 operand

#define ZERO16 ((f32x16){0.f,0.f,0.f,0.f,0.f,0.f,0.f,0.f,0.f,0.f,0.f,0.f,0.f,0.f,0.f,0.f})

static __device__ __forceinline__ unsigned short f2bf(float f) {
    union { float f; unsigned u; } v; v.f = f;
    unsigned r = v.u + 0x7fffu + ((v.u >> 16) & 1u);  // RNE
    return (unsigned short)(r >> 16);
}
static __device__ __forceinline__ unsigned pkbf(float x, float y) {
    __hip_bfloat162 h = __float22bfloat162_rn(make_float2(x, y));  // -> v_cvt_pk_bf16_f32
    return *(unsigned*)&h;
}

// ---------------- K1: GroupNorm stats: one block per (b,group) ----------------
__global__ void k_gnstats(const float* __restrict__ x, float* __restrict__ stats) {
    int bg = blockIdx.x;
    int t = threadIdx.x;
    const float4* b4 = (const float4*)(x + (size_t)bg * (8 * NSP));
    float s = 0.f, sq = 0.f;
    #pragma unroll
    for (int i = 0; i < 32; i++) {
        float4 v = b4[t + i * 256];
        s  += v.x + v.y + v.z + v.w;
        sq += v.x * v.x + v.y * v.y + v.z * v.z + v.w * v.w;
    }
    #pragma unroll
    for (int off = 32; off > 0; off >>= 1) {
        s  += __shfl_down(s, off);
        sq += __shfl_down(sq, off);
    }
    __shared__ float rs[4], rq[4];
    int w = t >> 6;
    if ((t & 63) == 0) { rs[w] = s; rq[w] = sq; }
    __syncthreads();
    if (t == 0) {
        float S = rs[0] + rs[1] + rs[2] + rs[3];
        float Q = rq[0] + rq[1] + rq[2] + rq[3];
        float mu  = S * (1.0f / 32768.0f);
        float var = Q * (1.0f / 32768.0f) - mu * mu;
        stats[bg * 2]     = mu;
        stats[bg * 2 + 1] = rsqrtf(var + EPS_GN);
    }
}

// ------ K2: apply GN, write xn^T (b,p,c) bf16, per-channel partial sums ------
__global__ void k_gnapply(const float* __restrict__ x, const float* __restrict__ gn_w,
                          const float* __restrict__ gn_b, const float* __restrict__ stats,
                          unsigned short* __restrict__ xnt, float* __restrict__ gpart) {
    int p0 = blockIdx.x * 64, c0 = blockIdx.y * 64, b = blockIdx.z;
    int t = threadIdx.x;
    __shared__ float tile[64][65];
    int ci0 = t >> 4, pq = t & 15;
    #pragma unroll
    for (int k = 0; k < 4; k++) {
        int ci = ci0 + k * 16;
        int c = c0 + ci;
        float mu   = stats[(b * GROUPS + (c >> 3)) * 2];
        float rstd = stats[(b * GROUPS + (c >> 3)) * 2 + 1];
        float w  = gn_w[c] * rstd;
        float bb = gn_b[c] - mu * w;
        float4 v = *(const float4*)(x + ((size_t)(b * CH + c)) * NSP + p0 + pq * 4);
        tile[ci][pq * 4 + 0] = v.x * w + bb;
        tile[ci][pq * 4 + 1] = v.y * w + bb;
        tile[ci][pq * 4 + 2] = v.z * w + bb;
        tile[ci][pq * 4 + 3] = v.w * w + bb;
    }
    __syncthreads();
    int pi = t >> 2, cb = (t & 3) * 16;
    unsigned pack[8];
    #pragma unroll
    for (int e = 0; e < 8; e++) {
        float a  = tile[cb + 2 * e][pi];
        float bv = tile[cb + 2 * e + 1][pi];
        pack[e] = (unsigned)f2bf(a) | ((unsigned)f2bf(bv) << 16);
    }
    uint4* dst = (uint4*)(xnt + ((size_t)(b * NSP + p0 + pi)) * CH + c0 + cb);
    dst[0] = make_uint4(pack[0], pack[1], pack[2], pack[3]);
    dst[1] = make_uint4(pack[4], pack[5], pack[6], pack[7]);
    if (t < 64) {
        float s = 0.f;
        #pragma unroll
        for (int j = 0; j < 64; j++) s += tile[t][j];
        gpart[((size_t)(b * CH + c0 + t)) * 64 + blockIdx.x] = s;
    }
}

// -------- K3: gfeat = mean(xn) @ gproj_w^T + gproj_b --------
__global__ void k_gproj(const float* __restrict__ gpart, const float* __restrict__ gproj_w,
                        const float* __restrict__ gproj_b, float* __restrict__ gfeat) {
    int b = blockIdx.x, t = threadIdx.x;
    __shared__ float graw[256];
    const float* p = gpart + ((size_t)(b * CH + t)) * 64;
    float s = 0.f;
    #pragma unroll
    for (int i = 0; i < 64; i++) s += p[i];
    graw[t] = s * (1.0f / 4096.0f);
    __syncthreads();
    float acc = gproj_b[t];
    const float* wr = gproj_w + (size_t)t * CH;
    #pragma unroll 8
    for (int c = 0; c < 256; c++) acc += graw[c] * wr[c];
    gfeat[b * CH + t] = acc;
}

// ---------------- K4: convert qkv_w + proj_w to bf16 ----------------
__global__ void k_convert(const float* __restrict__ qkv_w, const float* __restrict__ proj_w,
                          unsigned short* __restrict__ wbf) {
    int i4 = blockIdx.x * 256 + threadIdx.x;
    const float* src = (i4 < 49152) ? (qkv_w + (size_t)i4 * 4)
                                    : (proj_w + (size_t)(i4 - 49152) * 4);
    float4 v = *(const float4*)src;
    ushort4 o;
    o.x = f2bf(v.x); o.y = f2bf(v.y); o.z = f2bf(v.z); o.w = f2bf(v.w);
    *(ushort4*)(wbf + (size_t)i4 * 4) = o;
}

// ---------------- K5a: QKV GEMM -> bf16 q/k/v in attention layouts ----------------
__global__ void k_gemm_qkv(const unsigned short* __restrict__ Ag,
                           const unsigned short* __restrict__ Btg,
                           const float* __restrict__ bias,
                           const float* __restrict__ gfeat,
                           unsigned short* __restrict__ qt,
                           unsigned short* __restrict__ kt,
                           unsigned short* __restrict__ vt) {
    int n0 = blockIdx.x * 128, m0 = blockIdx.y * 64, b = blockIdx.z;
    int t = threadIdx.x, lane = t & 63, w = t >> 6;
    int wm = w >> 1, wn = w & 1;
    __shared__ short A_lds[64][40];
    __shared__ short B_lds[128][40];
    const unsigned short* Bb = Btg + (size_t)b * NSP * CH;
    f32x4 acc[2][4];
    #pragma unroll
    for (int m = 0; m < 2; m++)
        #pragma unroll
        for (int n = 0; n < 4; n++) acc[m][n] = (f32x4){0.f, 0.f, 0.f, 0.f};
    int arow = t >> 2, akk = (t & 3) * 8;
    for (int k0 = 0; k0 < 256; k0 += 32) {
        __syncthreads();
        *(uint4*)&A_lds[arow][akk] = *(const uint4*)(Ag + (size_t)(m0 + arow) * CH + k0 + akk);
        #pragma unroll
        for (int hh = 0; hh < 2; hh++) {
            int f = t + hh * 256;
            int j = f >> 2, kk = (f & 3) * 8;
            *(uint4*)&B_lds[j][kk] = *(const uint4*)(Bb + (size_t)(n0 + j) * CH + k0 + kk);
        }
        __syncthreads();
        short8 a[2], bf[4];
        #pragma unroll
        for (int m = 0; m < 2; m++)
            a[m] = *(const short8*)&A_lds[wm * 32 + m * 16 + (lane & 15)][(lane >> 4) * 8];
        #pragma unroll
        for (int n = 0; n < 4; n++)
            bf[n] = *(const short8*)&B_lds[wn * 64 + n * 16 + (lane & 15)][(lane >> 4) * 8];
        #pragma unroll
        for (int m = 0; m < 2; m++)
            #pragma unroll
            for (int n = 0; n < 4; n++)
                acc[m][n] = __builtin_amdgcn_mfma_f32_16x16x32_bf16(a[m], bf[n], acc[m][n], 0, 0, 0);
    }
    int rbase = m0 + wm * 32 + ((lane >> 4) << 2);
    int cbase = n0 + wn * 64 + (lane & 15);
    #pragma unroll
    for (int m = 0; m < 2; m++) {
        int row0 = rbase + m * 16;
        int sec = row0 >> 8;
        int ch  = row0 & 255;
        int h = ch >> 5, d0 = ch & 31;
        #pragma unroll
        for (int n = 0; n < 4; n++) {
            int col = cbase + n * 16;
            if (sec == 0) {
                ushort4 pk;
                pk.x = f2bf(acc[m][n][0] + bias[row0 + 0]);
                pk.y = f2bf(acc[m][n][1] + bias[row0 + 1]);
                pk.z = f2bf(acc[m][n][2] + bias[row0 + 2]);
                pk.w = f2bf(acc[m][n][3] + bias[row0 + 3]);
                *(ushort4*)(qt + ((size_t)((b * 8 + h) * NSP + col)) * HD + d0) = pk;
            } else if (sec == 1) {
                ushort4 pk;
                #pragma unroll
                for (int i = 0; i < 4; i++) {
                    float v = (acc[m][n][i] + bias[row0 + i]
                               + 0.1f * gfeat[b * CH + ch + i]) * ATT_SCALE;
                    ((unsigned short*)&pk)[i] = f2bf(v);
                }
                *(ushort4*)(kt + ((size_t)((b * 8 + h) * NSP + col)) * HD + d0) = pk;
            } else {
                #pragma unroll
                for (int i = 0; i < 4; i++) {
                    float v = acc[m][n][i] + bias[row0 + i];
                    vt[((size_t)((b * 8 + h) * HD + d0 + i)) * NSP + col] = f2bf(v);
                }
            }
        }
    }
}

// ---------------- K5b: proj GEMM (reads att bf16, adds residuals) ----------------
__global__ void k_gemm_proj(const unsigned short* __restrict__ Ag,
                            const unsigned short* __restrict__ Btg,
                            const float* __restrict__ bias,
                            const float* __restrict__ gfeat,
                            const float* __restrict__ xres,
                            float* __restrict__ out) {
    int n0 = blockIdx.x * 128, m0 = blockIdx.y * 64, b = blockIdx.z;
    int t = threadIdx.x, lane = t & 63, w = t >> 6;
    int wm = w >> 1, wn = w & 1;
    __shared__ short A_lds[64][40];
    __shared__ short B_lds[128][40];
    const unsigned short* Bb = Btg + (size_t)b * NSP * CH;
    f32x4 acc[2][4];
    #pragma unroll
    for (int m = 0; m < 2; m++)
        #pragma unroll
        for (int n = 0; n < 4; n++) acc[m][n] = (f32x4){0.f, 0.f, 0.f, 0.f};
    int arow = t >> 2, akk = (t & 3) * 8;
    for (int k0 = 0; k0 < 256; k0 += 32) {
        __syncthreads();
        *(uint4*)&A_lds[arow][akk] = *(const uint4*)(Ag + (size_t)(m0 + arow) * CH + k0 + akk);
        #pragma unroll
        for (int hh = 0; hh < 2; hh++) {
            int f = t + hh * 256;
            int j = f >> 2, kk = (f & 3) * 8;
            *(uint4*)&B_lds[j][kk] = *(const uint4*)(Bb + (size_t)(n0 + j) * CH + k0 + kk);
        }
        __syncthreads();
        short8 a[2], bf[4];
        #pragma unroll
        for (int m = 0; m < 2; m++)
            a[m] = *(const short8*)&A_lds[wm * 32 + m * 16 + (lane & 15)][(lane >> 4) * 8];
        #pragma unroll
        for (int n = 0; n < 4; n++)
            bf[n] = *(const short8*)&B_lds[wn * 64 + n * 16 + (lane & 15)][(lane >> 4) * 8];
        #pragma unroll
        for (int m = 0; m < 2; m++)
            #pragma unroll
            for (int n = 0; n < 4; n++)
                acc[m][n] = __builtin_amdgcn_mfma_f32_16x16x32_bf16(a[m], bf[n], acc[m][n], 0, 0, 0);
    }
    int rbase = m0 + wm * 32 + ((lane >> 4) << 2);
    int cbase = n0 + wn * 64 + (lane & 15);
    #pragma unroll
    for (int m = 0; m < 2; m++) {
        #pragma unroll
        for (int n = 0; n < 4; n++) {
            int col = cbase + n * 16;
            #pragma unroll
            for (int i = 0; i < 4; i++) {
                int row = rbase + m * 16 + i;
                float add = bias[row] + 0.1f * gfeat[b * CH + row]
                          + xres[((size_t)(b * CH + row)) * NSP + col];
                out[((size_t)(b * CH + row)) * NSP + col] = acc[m][n][i] + add;
            }
        }
    }
}

// ------------- K6: 32x32 MFMA flash attention, NO-MAX, two j-half passes -------------
// S^T = mfma(K,Q): lane holds S[j][q=lane&31], j = jhalf*32 + (r&3) + 8*(r>>2) + 4*hi.
// P' = exp2(S) UNNORMALIZED (|S| <~ 20 << 127; max cancels in the split combine).
// Two sequential 32-j half passes: sv dead between halves -> peak VGPR drops ~16,
// letting __launch_bounds__(256,8) pin VGPR<=64 for 8 waves/SIMD residency.
// K_lds rows padded to 80B (20 banks): conflict-free. r8-proven single-buffer staging.
__global__ __launch_bounds__(256, 8)
void k_flash32(const unsigned short* __restrict__ qt,
               const unsigned short* __restrict__ kt,
               const unsigned short* __restrict__ vt,
               unsigned short* __restrict__ opart, float* __restrict__ lpart) {
    const int h = blockIdx.y, b = blockIdx.z;
    const int s = blockIdx.x >> 5;
    const int t = threadIdx.x, lane = t & 63, w = t >> 6;
    const int lo32 = lane & 31, hi = lane >> 5;
    const int q0 = (blockIdx.x & 31) * 128 + w * 32;
    const int j0base = s * (NSP / NSPLIT);
    const unsigned short* qp = qt + ((size_t)(b * 8 + h) * NSP) * HD;
    const unsigned short* kp = kt + ((size_t)(b * 8 + h) * NSP) * HD;
    const unsigned short* vp = vt + ((size_t)(b * 8 + h) * HD) * NSP;
    __shared__ __align__(16) unsigned short K_lds[64 * 40];   // 80B rows, conflict-free
    __shared__ __align__(16) unsigned short V_lds[32 * 64];   // 128B rows, XOR slot swizzle

    short8 qf0 = *(const short8*)(qp + (size_t)(q0 + lo32) * HD + hi * 8);
    short8 qf1 = *(const short8*)(qp + (size_t)(q0 + lo32) * HD + 16 + hi * 8);
    f32x16 oacc;
    #pragma unroll
    for (int i = 0; i < 16; i++) oacc[i] = 0.f;
    float l = 0.f;

    // staging: K remapped so 8-lane phases hit rows 0-7 (bank-tiling); 1KB-coalesced/wave
    const int krow = (t & 7) + 8 * (t >> 5);
    const int kslot = (t >> 3) & 3;
    const int vd = t >> 3, vslot = t & 7;
    const unsigned short* kga = kp + (size_t)(j0base + krow) * HD + kslot * 8;
    const unsigned short* vga = vp + (size_t)vd * NSP + j0base + vslot * 8;
    uint4 kreg = *(const uint4*)kga;
    uint4 vreg = *(const uint4*)vga;
    const int kws = krow * 40 + kslot * 8;
    const int vws = vd * 64 + ((vslot ^ (vd & 7)) * 8);

    const int NT = NSP / NSPLIT / 64;
    for (int it = 0; it < NT; ++it) {
        *(uint4*)&K_lds[kws] = kreg;
        *(uint4*)&V_lds[vws] = vreg;
        __syncthreads();
        if (it + 1 < NT) {   // T14: issue next-tile loads; land under compute
            kreg = *(const uint4*)(kga + (size_t)(it + 1) * 64 * HD);
            vreg = *(const uint4*)(vga + (it + 1) * 64);
        }
        // ---- two independent 32-j half passes (sv dead between them) ----
        #pragma unroll
        for (int hf = 0; hf < 2; hf++) {
            const int jj = hf * 32 + lo32;
            short8 kf0 = *(const short8*)&K_lds[jj * 40 + hi * 8];
            short8 kf1 = *(const short8*)&K_lds[jj * 40 + (2 + hi) * 8];
            f32x16 sv;
            __builtin_amdgcn_s_setprio(1);
            sv = __builtin_amdgcn_mfma_f32_32x32x16_bf16(kf0, qf0, ZERO16, 0, 0, 0);
            sv = __builtin_amdgcn_mfma_f32_32x32x16_bf16(kf1, qf1, sv, 0, 0, 0);
            __builtin_amdgcn_s_setprio(0);
            // P' = exp2(S), unnormalized (no max tracking)
            #pragma unroll
            for (int i = 0; i < 16; i++) sv[i] = __builtin_amdgcn_exp2f(sv[i]);
            // row sum: v_pk_add_f32 tree + shfl partner exchange
            {
                #define SH2(V, I) __builtin_shufflevector(V, V, 2*(I), 2*(I)+1)
                f32x2 t0 = (SH2(sv,0) + SH2(sv,1)) + (SH2(sv,2) + SH2(sv,3));
                f32x2 t1 = (SH2(sv,4) + SH2(sv,5)) + (SH2(sv,6) + SH2(sv,7));
                f32x2 tt = t0 + t1;
                float sm = tt[0] + tt[1];
                #undef SH2
                sm += __shfl_xor(sm, 32);
                l += sm;
            }
            // P->bf16 + shfl_xor(32) exchange (r5-proven form); O^T += V P
            #define PVSTEP(SV, BB, C) { \
                unsigned p0 = pkbf(SV[BB + 0], SV[BB + 1]); \
                unsigned p1 = pkbf(SV[BB + 2], SV[BB + 3]); \
                unsigned p2 = pkbf(SV[BB + 4], SV[BB + 5]); \
                unsigned p3 = pkbf(SV[BB + 6], SV[BB + 7]); \
                unsigned s0 = hi ? p0 : p2, s1 = hi ? p1 : p3; \
                unsigned r0 = __shfl_xor(s0, 32), r1 = __shfl_xor(s1, 32); \
                uint4 fu = hi ? make_uint4(r0, r1, p2, p3) : make_uint4(p0, p1, r0, r1); \
                short8 pa = *(short8*)&fu; \
                short8 vf = *(const short8*)&V_lds[lo32 * 64 + ((((C) * 2 + hi) ^ (lo32 & 7)) * 8)]; \
                oacc = __builtin_amdgcn_mfma_f32_32x32x16_bf16(vf, pa, oacc, 0, 0, 0); \
            }
            __builtin_amdgcn_s_setprio(1);
            PVSTEP(sv, 0, hf * 2)
            PVSTEP(sv, 8, hf * 2 + 1)
            __builtin_amdgcn_s_setprio(0);
            #undef PVSTEP
        }
        __syncthreads();   // protect K_lds/V_lds before next stage
    }
    // bf16 unnormalized partials: lane q = q0+lo32, d = 8*rr + 4*hi + 0..3
    unsigned short* op = opart + ((((size_t)s * BATCH + b) * HEADS + h) * NSP + q0 + lo32) * HD;
    #pragma unroll
    for (int rr = 0; rr < 4; rr++) {
        ushort4 pk4;
        pk4.x = f2bf(oacc[rr * 4 + 0]);
        pk4.y = f2bf(oacc[rr * 4 + 1]);
        pk4.z = f2bf(oacc[rr * 4 + 2]);
        pk4.w = f2bf(oacc[rr * 4 + 3]);
        *(ushort4*)(op + rr * 8 + hi * 4) = pk4;
    }
    if (hi == 0)
        lpart[(((size_t)s * BATCH + b) * HEADS + h) * NSP + q0 + lo32] = l;
}

// ------------- K7: combine NSPLIT partials -> att bf16 (b,p,c) -------------
__global__ __launch_bounds__(256)
void k_combine(const unsigned short* __restrict__ opart, const float* __restrict__ lpart,
               unsigned short* __restrict__ att) {
    int flat = blockIdx.x * 256 + threadIdx.x;   // 2*8*4096*4 = 262144
    int dchunk = flat & 3;
    int q = (flat >> 2) & (NSP - 1);
    int bh = flat >> 14;
    const size_t sO = (size_t)BATCH * HEADS * NSP * HD;
    const size_t sL = (size_t)BATCH * HEADS * NSP;
    size_t rowq = (size_t)bh * NSP + q;
    float den = 0.f;
    #pragma unroll
    for (int s2 = 0; s2 < NSPLIT; s2++) den += lpart[s2 * sL + rowq];
    float inv = 1.0f / den;
    float acc[8];
    #pragma unroll
    for (int e = 0; e < 8; e++) acc[e] = 0.f;
    #pragma unroll
    for (int s2 = 0; s2 < NSPLIT; s2++) {
        uint4 v = *(const uint4*)(opart + s2 * sO + rowq * HD + dchunk * 8);
        const unsigned short* pv = (const unsigned short*)&v;
        #pragma unroll
        for (int e = 0; e < 8; e++) {
            unsigned u = (unsigned)pv[e] << 16;
            acc[e] += *(float*)&u;
        }
    }
    uint4 o;
    o.x = (unsigned)f2bf(acc[0] * inv) | ((unsigned)f2bf(acc[1] * inv) << 16);
    o.y = (unsigned)f2bf(acc[2] * inv) | ((unsigned)f2bf(acc[3] * inv) << 16);
    o.z = (unsigned)f2bf(acc[4] * inv) | ((unsigned)f2bf(acc[5] * inv) << 16);
    o.w = (unsigned)f2bf(acc[6] * inv) | ((unsigned)f2bf(acc[7] * inv) << 16);
    *(uint4*)(att + ((size_t)((bh >> 3) * NSP + q)) * CH + (bh & 7) * HD + dchunk * 8) = o;
}

extern "C" void kernel_launch(void* const* d_in, const int* in_sizes, int n_in,
                              void* d_out, int out_size, void* d_ws, size_t ws_size,
                              hipStream_t stream) {
    const float* x       = (const float*)d_in[0];
    const float* gn_w    = (const float*)d_in[1];
    const float* gn_b    = (const float*)d_in[2];
    const float* qkv_w   = (const float*)d_in[3];
    const float* qkv_b   = (const float*)d_in[4];
    const float* proj_w  = (const float*)d_in[5];
    const float* proj_b  = (const float*)d_in[6];
    const float* gproj_w = (const float*)d_in[7];
    const float* gproj_b = (const float*)d_in[8];
    char* ws = (char*)d_ws;
    float*          stats  = (float*)(ws);                      // 512 B
    float*          gpart  = (float*)(ws + 1024);               // 128 KB
    float*          gfeat  = (float*)(ws + 132096);             // 2 KB
    unsigned short* wbf    = (unsigned short*)(ws + 134144);    // 512 KB bf16 weights
    unsigned short* xnt    = (unsigned short*)(ws + 658432);    // (b,p,c) bf16, 4 MB (dead after qkv GEMM)
    float*          lpart  = (float*)(ws + 658432);             // overlays xnt: 1 MB l per (s,q)
    unsigned short* qt     = (unsigned short*)(ws + 4852736);   // (b,h,n,hd) bf16, 4 MB
    unsigned short* kt     = (unsigned short*)(ws + 9047040);   // (b,h,n,hd) bf16, 4 MB
    unsigned short* vt     = (unsigned short*)(ws + 13241344);  // (b,h,hd,n) bf16, 4 MB
    unsigned short* att    = (unsigned short*)(ws + 17435648);  // (b,p,c) bf16, 4 MB
    unsigned short* opart  = (unsigned short*)(ws + 21629952);  // 4 splits bf16 O, 16.8 MB
    float* out = (float*)d_out;

    hipLaunchKernelGGL(k_gnstats, dim3(64), dim3(256), 0, stream, x, stats);
    hipLaunchKernelGGL(k_gnapply, dim3(64, 4, 2), dim3(256), 0, stream,
                       x, gn_w, gn_b, stats, xnt, gpart);
    hipLaunchKernelGGL(k_gproj, dim3(2), dim3(256), 0, stream,
                       gpart, gproj_w, gproj_b, gfeat);
    hipLaunchKernelGGL(k_convert, dim3(256), dim3(256), 0, stream, qkv_w, proj_w, wbf);
    hipLaunchKernelGGL(k_gemm_qkv, dim3(32, 12, 2), dim3(256), 0, stream,
                       wbf, xnt, qkv_b, gfeat, qt, kt, vt);
    hipLaunchKernelGGL(k_flash32, dim3(32 * NSPLIT, 8, 2), dim3(256), 0, stream,
                       qt, kt, vt, opart, lpart);
    hipLaunchKernelGGL(k_combine, dim3(1024), dim3(256), 0, stream,
                       opart, lpart, att);
    hipLaunchKernelGGL(k_gemm_proj, dim3(32, 4, 2), dim3(256), 0, stream,
                       wbf + 196608, att, proj_b, gfeat, x, out);
}

// Round 12
// 116.117 us; speedup vs baseline: 1.1141x; 1.0359x over previous
//
#include <hip/hip_runtime.h>
#include <hip/hip_bf16.h>
#include <stdint.h>

#define BATCH 2
#define CH 256
#define NSP 4096          // 64*64 spatial
#define HEADS 8
#define HD 32
#define GROUPS 32
#define EPS_GN 1e-5f
#define NSPLIT 4          // flash KV-sequence splits

// hd^-0.5 * log2(e): folds softmax scale AND exp->exp2 conversion into k
#define ATT_SCALE (0.17677669529663687f * 1.4426950408889634f)

typedef __attribute__((ext_vector_type(8))) short short8;    // 8 bf16 (MFMA A/B frag)
typedef __attribute__((ext_vector_type(4))) float f32x4;     // 16x16 C/D frag
typedef __attribute__((ext_vector_type(16))) float f32x16;   // 32x32 C/D frag
typedef __attribute__((ext_vector_type(2))) float f32x2;     // v_pk_add_f32 operand

#define ZERO16 ((f32x16){0.f,0.f,0.f,0.f,0.f,0.f,0.f,0.f,0.f,0.f,0.f,0.f,0.f,0.f,0.f,0.f})

static __device__ __forceinline__ unsigned short f2bf(float f) {
    union { float f; unsigned u; } v; v.f = f;
    unsigned r = v.u + 0x7fffu + ((v.u >> 16) & 1u);  // RNE
    return (unsigned short)(r >> 16);
}
static __device__ __forceinline__ unsigned pkbf(float x, float y) {
    __hip_bfloat162 h = __float22bfloat162_rn(make_float2(x, y));  // -> v_cvt_pk_bf16_f32
    return *(unsigned*)&h;
}

// ---------------- K1: GroupNorm stats: one block per (b,group) ----------------
__global__ void k_gnstats(const float* __restrict__ x, float* __restrict__ stats) {
    int bg = blockIdx.x;
    int t = threadIdx.x;
    const float4* b4 = (const float4*)(x + (size_t)bg * (8 * NSP));
    float s = 0.f, sq = 0.f;
    #pragma unroll
    for (int i = 0; i < 32; i++) {
        float4 v = b4[t + i * 256];
        s  += v.x + v.y + v.z + v.w;
        sq += v.x * v.x + v.y * v.y + v.z * v.z + v.w * v.w;
    }
    #pragma unroll
    for (int off = 32; off > 0; off >>= 1) {
        s  += __shfl_down(s, off);
        sq += __shfl_down(sq, off);
    }
    __shared__ float rs[4], rq[4];
    int w = t >> 6;
    if ((t & 63) == 0) { rs[w] = s; rq[w] = sq; }
    __syncthreads();
    if (t == 0) {
        float S = rs[0] + rs[1] + rs[2] + rs[3];
        float Q = rq[0] + rq[1] + rq[2] + rq[3];
        float mu  = S * (1.0f / 32768.0f);
        float var = Q * (1.0f / 32768.0f) - mu * mu;
        stats[bg * 2]     = mu;
        stats[bg * 2 + 1] = rsqrtf(var + EPS_GN);
    }
}

// ------ K2: apply GN, write xn^T (b,p,c) bf16, per-channel partial sums ------
__global__ void k_gnapply(const float* __restrict__ x, const float* __restrict__ gn_w,
                          const float* __restrict__ gn_b, const float* __restrict__ stats,
                          unsigned short* __restrict__ xnt, float* __restrict__ gpart) {
    int p0 = blockIdx.x * 64, c0 = blockIdx.y * 64, b = blockIdx.z;
    int t = threadIdx.x;
    __shared__ float tile[64][65];
    int ci0 = t >> 4, pq = t & 15;
    #pragma unroll
    for (int k = 0; k < 4; k++) {
        int ci = ci0 + k * 16;
        int c = c0 + ci;
        float mu   = stats[(b * GROUPS + (c >> 3)) * 2];
        float rstd = stats[(b * GROUPS + (c >> 3)) * 2 + 1];
        float w  = gn_w[c] * rstd;
        float bb = gn_b[c] - mu * w;
        float4 v = *(const float4*)(x + ((size_t)(b * CH + c)) * NSP + p0 + pq * 4);
        tile[ci][pq * 4 + 0] = v.x * w + bb;
        tile[ci][pq * 4 + 1] = v.y * w + bb;
        tile[ci][pq * 4 + 2] = v.z * w + bb;
        tile[ci][pq * 4 + 3] = v.w * w + bb;
    }
    __syncthreads();
    int pi = t >> 2, cb = (t & 3) * 16;
    unsigned pack[8];
    #pragma unroll
    for (int e = 0; e < 8; e++) {
        float a  = tile[cb + 2 * e][pi];
        float bv = tile[cb + 2 * e + 1][pi];
        pack[e] = (unsigned)f2bf(a) | ((unsigned)f2bf(bv) << 16);
    }
    uint4* dst = (uint4*)(xnt + ((size_t)(b * NSP + p0 + pi)) * CH + c0 + cb);
    dst[0] = make_uint4(pack[0], pack[1], pack[2], pack[3]);
    dst[1] = make_uint4(pack[4], pack[5], pack[6], pack[7]);
    if (t < 64) {
        float s = 0.f;
        #pragma unroll
        for (int j = 0; j < 64; j++) s += tile[t][j];
        gpart[((size_t)(b * CH + c0 + t)) * 64 + blockIdx.x] = s;
    }
}

// -------- K3: gfeat = mean(xn) @ gproj_w^T + gproj_b --------
__global__ void k_gproj(const float* __restrict__ gpart, const float* __restrict__ gproj_w,
                        const float* __restrict__ gproj_b, float* __restrict__ gfeat) {
    int b = blockIdx.x, t = threadIdx.x;
    __shared__ float graw[256];
    const float* p = gpart + ((size_t)(b * CH + t)) * 64;
    float s = 0.f;
    #pragma unroll
    for (int i = 0; i < 64; i++) s += p[i];
    graw[t] = s * (1.0f / 4096.0f);
    __syncthreads();
    float acc = gproj_b[t];
    const float* wr = gproj_w + (size_t)t * CH;
    #pragma unroll 8
    for (int c = 0; c < 256; c++) acc += graw[c] * wr[c];
    gfeat[b * CH + t] = acc;
}

// ---------------- K4: convert qkv_w + proj_w to bf16 ----------------
__global__ void k_convert(const float* __restrict__ qkv_w, const float* __restrict__ proj_w,
                          unsigned short* __restrict__ wbf) {
    int i4 = blockIdx.x * 256 + threadIdx.x;
    const float* src = (i4 < 49152) ? (qkv_w + (size_t)i4 * 4)
                                    : (proj_w + (size_t)(i4 - 49152) * 4);
    float4 v = *(const float4*)src;
    ushort4 o;
    o.x = f2bf(v.x); o.y = f2bf(v.y); o.z = f2bf(v.z); o.w = f2bf(v.w);
    *(ushort4*)(wbf + (size_t)i4 * 4) = o;
}

// ---------------- K5a: QKV GEMM -> bf16 q/k/v in attention layouts ----------------
__global__ void k_gemm_qkv(const unsigned short* __restrict__ Ag,
                           const unsigned short* __restrict__ Btg,
                           const float* __restrict__ bias,
                           const float* __restrict__ gfeat,
                           unsigned short* __restrict__ qt,
                           unsigned short* __restrict__ kt,
                           unsigned short* __restrict__ vt) {
    int n0 = blockIdx.x * 128, m0 = blockIdx.y * 64, b = blockIdx.z;
    int t = threadIdx.x, lane = t & 63, w = t >> 6;
    int wm = w >> 1, wn = w & 1;
    __shared__ short A_lds[64][40];
    __shared__ short B_lds[128][40];
    const unsigned short* Bb = Btg + (size_t)b * NSP * CH;
    f32x4 acc[2][4];
    #pragma unroll
    for (int m = 0; m < 2; m++)
        #pragma unroll
        for (int n = 0; n < 4; n++) acc[m][n] = (f32x4){0.f, 0.f, 0.f, 0.f};
    int arow = t >> 2, akk = (t & 3) * 8;
    for (int k0 = 0; k0 < 256; k0 += 32) {
        __syncthreads();
        *(uint4*)&A_lds[arow][akk] = *(const uint4*)(Ag + (size_t)(m0 + arow) * CH + k0 + akk);
        #pragma unroll
        for (int hh = 0; hh < 2; hh++) {
            int f = t + hh * 256;
            int j = f >> 2, kk = (f & 3) * 8;
            *(uint4*)&B_lds[j][kk] = *(const uint4*)(Bb + (size_t)(n0 + j) * CH + k0 + kk);
        }
        __syncthreads();
        short8 a[2], bf[4];
        #pragma unroll
        for (int m = 0; m < 2; m++)
            a[m] = *(const short8*)&A_lds[wm * 32 + m * 16 + (lane & 15)][(lane >> 4) * 8];
        #pragma unroll
        for (int n = 0; n < 4; n++)
            bf[n] = *(const short8*)&B_lds[wn * 64 + n * 16 + (lane & 15)][(lane >> 4) * 8];
        #pragma unroll
        for (int m = 0; m < 2; m++)
            #pragma unroll
            for (int n = 0; n < 4; n++)
                acc[m][n] = __builtin_amdgcn_mfma_f32_16x16x32_bf16(a[m], bf[n], acc[m][n], 0, 0, 0);
    }
    int rbase = m0 + wm * 32 + ((lane >> 4) << 2);
    int cbase = n0 + wn * 64 + (lane & 15);
    #pragma unroll
    for (int m = 0; m < 2; m++) {
        int row0 = rbase + m * 16;
        int sec = row0 >> 8;
        int ch  = row0 & 255;
        int h = ch >> 5, d0 = ch & 31;
        #pragma unroll
        for (int n = 0; n < 4; n++) {
            int col = cbase + n * 16;
            if (sec == 0) {
                ushort4 pk;
                pk.x = f2bf(acc[m][n][0] + bias[row0 + 0]);
                pk.y = f2bf(acc[m][n][1] + bias[row0 + 1]);
                pk.z = f2bf(acc[m][n][2] + bias[row0 + 2]);
                pk.w = f2bf(acc[m][n][3] + bias[row0 + 3]);
                *(ushort4*)(qt + ((size_t)((b * 8 + h) * NSP + col)) * HD + d0) = pk;
            } else if (sec == 1) {
                ushort4 pk;
                #pragma unroll
                for (int i = 0; i < 4; i++) {
                    float v = (acc[m][n][i] + bias[row0 + i]
                               + 0.1f * gfeat[b * CH + ch + i]) * ATT_SCALE;
                    ((unsigned short*)&pk)[i] = f2bf(v);
                }
                *(ushort4*)(kt + ((size_t)((b * 8 + h) * NSP + col)) * HD + d0) = pk;
            } else {
                #pragma unroll
                for (int i = 0; i < 4; i++) {
                    float v = acc[m][n][i] + bias[row0 + i];
                    vt[((size_t)((b * 8 + h) * HD + d0 + i)) * NSP + col] = f2bf(v);
                }
            }
        }
    }
}

// ---------------- K5b: proj GEMM (reads att bf16, adds residuals) ----------------
__global__ void k_gemm_proj(const unsigned short* __restrict__ Ag,
                            const unsigned short* __restrict__ Btg,
                            const float* __restrict__ bias,
                            const float* __restrict__ gfeat,
                            const float* __restrict__ xres,
                            float* __restrict__ out) {
    int n0 = blockIdx.x * 128, m0 = blockIdx.y * 64, b = blockIdx.z;
    int t = threadIdx.x, lane = t & 63, w = t >> 6;
    int wm = w >> 1, wn = w & 1;
    __shared__ short A_lds[64][40];
    __shared__ short B_lds[128][40];
    const unsigned short* Bb = Btg + (size_t)b * NSP * CH;
    f32x4 acc[2][4];
    #pragma unroll
    for (int m = 0; m < 2; m++)
        #pragma unroll
        for (int n = 0; n < 4; n++) acc[m][n] = (f32x4){0.f, 0.f, 0.f, 0.f};
    int arow = t >> 2, akk = (t & 3) * 8;
    for (int k0 = 0; k0 < 256; k0 += 32) {
        __syncthreads();
        *(uint4*)&A_lds[arow][akk] = *(const uint4*)(Ag + (size_t)(m0 + arow) * CH + k0 + akk);
        #pragma unroll
        for (int hh = 0; hh < 2; hh++) {
            int f = t + hh * 256;
            int j = f >> 2, kk = (f & 3) * 8;
            *(uint4*)&B_lds[j][kk] = *(const uint4*)(Bb + (size_t)(n0 + j) * CH + k0 + kk);
        }
        __syncthreads();
        short8 a[2], bf[4];
        #pragma unroll
        for (int m = 0; m < 2; m++)
            a[m] = *(const short8*)&A_lds[wm * 32 + m * 16 + (lane & 15)][(lane >> 4) * 8];
        #pragma unroll
        for (int n = 0; n < 4; n++)
            bf[n] = *(const short8*)&B_lds[wn * 64 + n * 16 + (lane & 15)][(lane >> 4) * 8];
        #pragma unroll
        for (int m = 0; m < 2; m++)
            #pragma unroll
            for (int n = 0; n < 4; n++)
                acc[m][n] = __builtin_amdgcn_mfma_f32_16x16x32_bf16(a[m], bf[n], acc[m][n], 0, 0, 0);
    }
    int rbase = m0 + wm * 32 + ((lane >> 4) << 2);
    int cbase = n0 + wn * 64 + (lane & 15);
    #pragma unroll
    for (int m = 0; m < 2; m++) {
        #pragma unroll
        for (int n = 0; n < 4; n++) {
            int col = cbase + n * 16;
            #pragma unroll
            for (int i = 0; i < 4; i++) {
                int row = rbase + m * 16 + i;
                float add = bias[row] + 0.1f * gfeat[b * CH + row]
                          + xres[((size_t)(b * CH + row)) * NSP + col];
                out[((size_t)(b * CH + row)) * NSP + col] = acc[m][n][i] + add;
            }
        }
    }
}

// ------------- K6: 32x32 MFMA flash attention, NO-MAX, two j-half passes -------------
// S^T = mfma(K,Q): lane holds S[j][q=lane&31], j = jhalf*32 + (r&3) + 8*(r>>2) + 4*hi.
// P' = exp2(S) UNNORMALIZED (|S| <~ 20 << 127; max cancels in the split combine).
// No register prefetch: kt/vt total 8MB -> L2-resident; ~250cy L2 hits are hidden by
// 8-wave/SIMD TLP (T14 is null at high occupancy). Loads at loop top, transient regs.
// K_lds rows padded to 80B (20 banks): conflict-free b128 reads+writes.
__global__ __launch_bounds__(256, 8)
void k_flash32(const unsigned short* __restrict__ qt,
               const unsigned short* __restrict__ kt,
               const unsigned short* __restrict__ vt,
               unsigned short* __restrict__ opart, float* __restrict__ lpart) {
    const int h = blockIdx.y, b = blockIdx.z;
    const int s = blockIdx.x >> 5;
    const int t = threadIdx.x, lane = t & 63, w = t >> 6;
    const int lo32 = lane & 31, hi = lane >> 5;
    const int q0 = (blockIdx.x & 31) * 128 + w * 32;
    const int j0base = s * (NSP / NSPLIT);
    const unsigned short* qp = qt + ((size_t)(b * 8 + h) * NSP) * HD;
    const unsigned short* kp = kt + ((size_t)(b * 8 + h) * NSP) * HD;
    const unsigned short* vp = vt + ((size_t)(b * 8 + h) * HD) * NSP;
    __shared__ __align__(16) unsigned short K_lds[64 * 40];   // 80B rows, conflict-free
    __shared__ __align__(16) unsigned short V_lds[32 * 64];   // 128B rows, XOR slot swizzle

    short8 qf0 = *(const short8*)(qp + (size_t)(q0 + lo32) * HD + hi * 8);
    short8 qf1 = *(const short8*)(qp + (size_t)(q0 + lo32) * HD + 16 + hi * 8);
    f32x16 oacc;
    #pragma unroll
    for (int i = 0; i < 16; i++) oacc[i] = 0.f;
    float l = 0.f;

    // staging: K remapped so 8-lane phases hit rows 0-7 (bank-tiling); 1KB-coalesced/wave
    const int krow = (t & 7) + 8 * (t >> 5);
    const int kslot = (t >> 3) & 3;
    const int vd = t >> 3, vslot = t & 7;
    const unsigned short* kga = kp + (size_t)(j0base + krow) * HD + kslot * 8;
    const unsigned short* vga = vp + (size_t)vd * NSP + j0base + vslot * 8;
    const int kws = krow * 40 + kslot * 8;
    const int vws = vd * 64 + ((vslot ^ (vd & 7)) * 8);

    const int NT = NSP / NSPLIT / 64;
    for (int it = 0; it < NT; ++it) {
        {   // stage current tile (transient regs; L2-hit latency hidden by TLP)
            uint4 kreg = *(const uint4*)(kga + (size_t)it * 64 * HD);
            uint4 vreg = *(const uint4*)(vga + it * 64);
            *(uint4*)&K_lds[kws] = kreg;
            *(uint4*)&V_lds[vws] = vreg;
        }
        __syncthreads();
        // ---- two independent 32-j half passes (sv dead between them) ----
        #pragma unroll
        for (int hf = 0; hf < 2; hf++) {
            const int jj = hf * 32 + lo32;
            short8 kf0 = *(const short8*)&K_lds[jj * 40 + hi * 8];
            short8 kf1 = *(const short8*)&K_lds[jj * 40 + (2 + hi) * 8];
            f32x16 sv;
            __builtin_amdgcn_s_setprio(1);
            sv = __builtin_amdgcn_mfma_f32_32x32x16_bf16(kf0, qf0, ZERO16, 0, 0, 0);
            sv = __builtin_amdgcn_mfma_f32_32x32x16_bf16(kf1, qf1, sv, 0, 0, 0);
            __builtin_amdgcn_s_setprio(0);
            // P' = exp2(S), unnormalized (no max tracking)
            #pragma unroll
            for (int i = 0; i < 16; i++) sv[i] = __builtin_amdgcn_exp2f(sv[i]);
            // row sum: v_pk_add_f32 tree + shfl partner exchange
            {
                #define SH2(V, I) __builtin_shufflevector(V, V, 2*(I), 2*(I)+1)
                f32x2 t0 = (SH2(sv,0) + SH2(sv,1)) + (SH2(sv,2) + SH2(sv,3));
                f32x2 t1 = (SH2(sv,4) + SH2(sv,5)) + (SH2(sv,6) + SH2(sv,7));
                f32x2 tt = t0 + t1;
                float sm = tt[0] + tt[1];
                #undef SH2
                sm += __shfl_xor(sm, 32);
                l += sm;
            }
            // P->bf16 + shfl_xor(32) exchange (r5-proven form); O^T += V P
            #define PVSTEP(SV, BB, C) { \
                unsigned p0 = pkbf(SV[BB + 0], SV[BB + 1]); \
                unsigned p1 = pkbf(SV[BB + 2], SV[BB + 3]); \
                unsigned p2 = pkbf(SV[BB + 4], SV[BB + 5]); \
                unsigned p3 = pkbf(SV[BB + 6], SV[BB + 7]); \
                unsigned s0 = hi ? p0 : p2, s1 = hi ? p1 : p3; \
                unsigned r0 = __shfl_xor(s0, 32), r1 = __shfl_xor(s1, 32); \
                uint4 fu = hi ? make_uint4(r0, r1, p2, p3) : make_uint4(p0, p1, r0, r1); \
                short8 pa = *(short8*)&fu; \
                short8 vf = *(const short8*)&V_lds[lo32 * 64 + ((((C) * 2 + hi) ^ (lo32 & 7)) * 8)]; \
                oacc = __builtin_amdgcn_mfma_f32_32x32x16_bf16(vf, pa, oacc, 0, 0, 0); \
            }
            __builtin_amdgcn_s_setprio(1);
            PVSTEP(sv, 0, hf * 2)
            PVSTEP(sv, 8, hf * 2 + 1)
            __builtin_amdgcn_s_setprio(0);
            #undef PVSTEP
        }
        __syncthreads();   // protect K_lds/V_lds before next stage
    }
    // bf16 unnormalized partials: lane q = q0+lo32, d = 8*rr + 4*hi + 0..3
    unsigned short* op = opart + ((((size_t)s * BATCH + b) * HEADS + h) * NSP + q0 + lo32) * HD;
    #pragma unroll
    for (int rr = 0; rr < 4; rr++) {
        ushort4 pk4;
        pk4.x = f2bf(oacc[rr * 4 + 0]);
        pk4.y = f2bf(oacc[rr * 4 + 1]);
        pk4.z = f2bf(oacc[rr * 4 + 2]);
        pk4.w = f2bf(oacc[rr * 4 + 3]);
        *(ushort4*)(op + rr * 8 + hi * 4) = pk4;
    }
    if (hi == 0)
        lpart[(((size_t)s * BATCH + b) * HEADS + h) * NSP + q0 + lo32] = l;
}

// ------------- K7: combine NSPLIT partials -> att bf16 (b,p,c) -------------
__global__ __launch_bounds__(256)
void k_combine(const unsigned short* __restrict__ opart, const float* __restrict__ lpart,
               unsigned short* __restrict__ att) {
    int flat = blockIdx.x * 256 + threadIdx.x;   // 2*8*4096*4 = 262144
    int dchunk = flat & 3;
    int q = (flat >> 2) & (NSP - 1);
    int bh = flat >> 14;
    const size_t sO = (size_t)BATCH * HEADS * NSP * HD;
    const size_t sL = (size_t)BATCH * HEADS * NSP;
    size_t rowq = (size_t)bh * NSP + q;
    float den = 0.f;
    #pragma unroll
    for (int s2 = 0; s2 < NSPLIT; s2++) den += lpart[s2 * sL + rowq];
    float inv = 1.0f / den;
    float acc[8];
    #pragma unroll
    for (int e = 0; e < 8; e++) acc[e] = 0.f;
    #pragma unroll
    for (int s2 = 0; s2 < NSPLIT; s2++) {
        uint4 v = *(const uint4*)(opart + s2 * sO + rowq * HD + dchunk * 8);
        const unsigned short* pv = (const unsigned short*)&v;
        #pragma unroll
        for (int e = 0; e < 8; e++) {
            unsigned u = (unsigned)pv[e] << 16;
            acc[e] += *(float*)&u;
        }
    }
    uint4 o;
    o.x = (unsigned)f2bf(acc[0] * inv) | ((unsigned)f2bf(acc[1] * inv) << 16);
    o.y = (unsigned)f2bf(acc[2] * inv) | ((unsigned)f2bf(acc[3] * inv) << 16);
    o.z = (unsigned)f2bf(acc[4] * inv) | ((unsigned)f2bf(acc[5] * inv) << 16);
    o.w = (unsigned)f2bf(acc[6] * inv) | ((unsigned)f2bf(acc[7] * inv) << 16);
    *(uint4*)(att + ((size_t)((bh >> 3) * NSP + q)) * CH + (bh & 7) * HD + dchunk * 8) = o;
}

extern "C" void kernel_launch(void* const* d_in, const int* in_sizes, int n_in,
                              void* d_out, int out_size, void* d_ws, size_t ws_size,
                              hipStream_t stream) {
    const float* x       = (const float*)d_in[0];
    const float* gn_w    = (const float*)d_in[1];
    const float* gn_b    = (const float*)d_in[2];
    const float* qkv_w   = (const float*)d_in[3];
    const float* qkv_b   = (const float*)d_in[4];
    const float* proj_w  = (const float*)d_in[5];
    const float* proj_b  = (const float*)d_in[6];
    const float* gproj_w = (const float*)d_in[7];
    const float* gproj_b = (const float*)d_in[8];
    char* ws = (char*)d_ws;
    float*          stats  = (float*)(ws);                      // 512 B
    float*          gpart  = (float*)(ws + 1024);               // 128 KB
    float*          gfeat  = (float*)(ws + 132096);             // 2 KB
    unsigned short* wbf    = (unsigned short*)(ws + 134144);    // 512 KB bf16 weights
    unsigned short* xnt    = (unsigned short*)(ws + 658432);    // (b,p,c) bf16, 4 MB (dead after qkv GEMM)
    float*          lpart  = (float*)(ws + 658432);             // overlays xnt: 1 MB l per (s,q)
    unsigned short* qt     = (unsigned short*)(ws + 4852736);   // (b,h,n,hd) bf16, 4 MB
    unsigned short* kt     = (unsigned short*)(ws + 9047040);   // (b,h,n,hd) bf16, 4 MB
    unsigned short* vt     = (unsigned short*)(ws + 13241344);  // (b,h,hd,n) bf16, 4 MB
    unsigned short* att    = (unsigned short*)(ws + 17435648);  // (b,p,c) bf16, 4 MB
    unsigned short* opart  = (unsigned short*)(ws + 21629952);  // 4 splits bf16 O, 16.8 MB
    float* out = (float*)d_out;

    hipLaunchKernelGGL(k_gnstats, dim3(64), dim3(256), 0, stream, x, stats);
    hipLaunchKernelGGL(k_gnapply, dim3(64, 4, 2), dim3(256), 0, stream,
                       x, gn_w, gn_b, stats, xnt, gpart);
    hipLaunchKernelGGL(k_gproj, dim3(2), dim3(256), 0, stream,
                       gpart, gproj_w, gproj_b, gfeat);
    hipLaunchKernelGGL(k_convert, dim3(256), dim3(256), 0, stream, qkv_w, proj_w, wbf);
    hipLaunchKernelGGL(k_gemm_qkv, dim3(32, 12, 2), dim3(256), 0, stream,
                       wbf, xnt, qkv_b, gfeat, qt, kt, vt);
    hipLaunchKernelGGL(k_flash32, dim3(32 * NSPLIT, 8, 2), dim3(256), 0, stream,
                       qt, kt, vt, opart, lpart);
    hipLaunchKernelGGL(k_combine, dim3(1024), dim3(256), 0, stream,
                       opart, lpart, att);
    hipLaunchKernelGGL(k_gemm_proj, dim3(32, 4, 2), dim3(256), 0, stream,
                       wbf + 196608, att, proj_b, gfeat, x, out);
}

// Round 13
// 111.819 us; speedup vs baseline: 1.1569x; 1.0384x over previous
//
#include <hip/hip_runtime.h>
#include <hip/hip_bf16.h>
#include <stdint.h>

#define BATCH 2
#define CH 256
#define NSP 4096          // 64*64 spatial
#define HEADS 8
#define HD 32
#define GROUPS 32
#define EPS_GN 1e-5f
#define NSPLIT 4          // flash KV-sequence splits

// hd^-0.5 * log2(e): folds softmax scale AND exp->exp2 conversion into k
#define ATT_SCALE (0.17677669529663687f * 1.4426950408889634f)

typedef __attribute__((ext_vector_type(8))) short short8;    // 8 bf16 (MFMA A/B frag)
typedef __attribute__((ext_vector_type(4))) float f32x4;     // 16x16 C/D frag
typedef __attribute__((ext_vector_type(16))) float f32x16;   // 32x32 C/D frag
typedef __attribute__((ext_vector_type(2))) float f32x2;     // v_pk_add_f32 operand

#define ZERO16 ((f32x16){0.f,0.f,0.f,0.f,0.f,0.f,0.f,0.f,0.f,0.f,0.f,0.f,0.f,0.f,0.f,0.f})

static __device__ __forceinline__ unsigned short f2bf(float f) {
    union { float f; unsigned u; } v; v.f = f;
    unsigned r = v.u + 0x7fffu + ((v.u >> 16) & 1u);  // RNE
    return (unsigned short)(r >> 16);
}
static __device__ __forceinline__ unsigned pkbf(float x, float y) {
    __hip_bfloat162 h = __float22bfloat162_rn(make_float2(x, y));  // -> v_cvt_pk_bf16_f32
    return *(unsigned*)&h;
}

// ---------------- K1: GroupNorm stats: one block per (b,group) ----------------
__global__ void k_gnstats(const float* __restrict__ x, float* __restrict__ stats) {
    int bg = blockIdx.x;
    int t = threadIdx.x;
    const float4* b4 = (const float4*)(x + (size_t)bg * (8 * NSP));
    float s = 0.f, sq = 0.f;
    #pragma unroll
    for (int i = 0; i < 32; i++) {
        float4 v = b4[t + i * 256];
        s  += v.x + v.y + v.z + v.w;
        sq += v.x * v.x + v.y * v.y + v.z * v.z + v.w * v.w;
    }
    #pragma unroll
    for (int off = 32; off > 0; off >>= 1) {
        s  += __shfl_down(s, off);
        sq += __shfl_down(sq, off);
    }
    __shared__ float rs[4], rq[4];
    int w = t >> 6;
    if ((t & 63) == 0) { rs[w] = s; rq[w] = sq; }
    __syncthreads();
    if (t == 0) {
        float S = rs[0] + rs[1] + rs[2] + rs[3];
        float Q = rq[0] + rq[1] + rq[2] + rq[3];
        float mu  = S * (1.0f / 32768.0f);
        float var = Q * (1.0f / 32768.0f) - mu * mu;
        stats[bg * 2]     = mu;
        stats[bg * 2 + 1] = rsqrtf(var + EPS_GN);
    }
}

// ------ K2: apply GN, write xn^T (b,p,c) bf16, per-channel partial sums ------
__global__ void k_gnapply(const float* __restrict__ x, const float* __restrict__ gn_w,
                          const float* __restrict__ gn_b, const float* __restrict__ stats,
                          unsigned short* __restrict__ xnt, float* __restrict__ gpart) {
    int p0 = blockIdx.x * 64, c0 = blockIdx.y * 64, b = blockIdx.z;
    int t = threadIdx.x;
    __shared__ float tile[64][65];
    int ci0 = t >> 4, pq = t & 15;
    #pragma unroll
    for (int k = 0; k < 4; k++) {
        int ci = ci0 + k * 16;
        int c = c0 + ci;
        float mu   = stats[(b * GROUPS + (c >> 3)) * 2];
        float rstd = stats[(b * GROUPS + (c >> 3)) * 2 + 1];
        float w  = gn_w[c] * rstd;
        float bb = gn_b[c] - mu * w;
        float4 v = *(const float4*)(x + ((size_t)(b * CH + c)) * NSP + p0 + pq * 4);
        tile[ci][pq * 4 + 0] = v.x * w + bb;
        tile[ci][pq * 4 + 1] = v.y * w + bb;
        tile[ci][pq * 4 + 2] = v.z * w + bb;
        tile[ci][pq * 4 + 3] = v.w * w + bb;
    }
    __syncthreads();
    int pi = t >> 2, cb = (t & 3) * 16;
    unsigned pack[8];
    #pragma unroll
    for (int e = 0; e < 8; e++) {
        float a  = tile[cb + 2 * e][pi];
        float bv = tile[cb + 2 * e + 1][pi];
        pack[e] = (unsigned)f2bf(a) | ((unsigned)f2bf(bv) << 16);
    }
    uint4* dst = (uint4*)(xnt + ((size_t)(b * NSP + p0 + pi)) * CH + c0 + cb);
    dst[0] = make_uint4(pack[0], pack[1], pack[2], pack[3]);
    dst[1] = make_uint4(pack[4], pack[5], pack[6], pack[7]);
    if (t < 64) {
        float s = 0.f;
        #pragma unroll
        for (int j = 0; j < 64; j++) s += tile[t][j];
        gpart[((size_t)(b * CH + c0 + t)) * 64 + blockIdx.x] = s;
    }
}

// -------- K3: gfeat = mean(xn) @ gproj_w^T + gproj_b --------
__global__ void k_gproj(const float* __restrict__ gpart, const float* __restrict__ gproj_w,
                        const float* __restrict__ gproj_b, float* __restrict__ gfeat) {
    int b = blockIdx.x, t = threadIdx.x;
    __shared__ float graw[256];
    const float* p = gpart + ((size_t)(b * CH + t)) * 64;
    float s = 0.f;
    #pragma unroll
    for (int i = 0; i < 64; i++) s += p[i];
    graw[t] = s * (1.0f / 4096.0f);
    __syncthreads();
    float acc = gproj_b[t];
    const float* wr = gproj_w + (size_t)t * CH;
    #pragma unroll 8
    for (int c = 0; c < 256; c++) acc += graw[c] * wr[c];
    gfeat[b * CH + t] = acc;
}

// ---------------- K4: convert qkv_w + proj_w to bf16 ----------------
__global__ void k_convert(const float* __restrict__ qkv_w, const float* __restrict__ proj_w,
                          unsigned short* __restrict__ wbf) {
    int i4 = blockIdx.x * 256 + threadIdx.x;
    const float* src = (i4 < 49152) ? (qkv_w + (size_t)i4 * 4)
                                    : (proj_w + (size_t)(i4 - 49152) * 4);
    float4 v = *(const float4*)src;
    ushort4 o;
    o.x = f2bf(v.x); o.y = f2bf(v.y); o.z = f2bf(v.z); o.w = f2bf(v.w);
    *(ushort4*)(wbf + (size_t)i4 * 4) = o;
}

// ---------------- K5a: QKV GEMM -> bf16 q/k/v in attention layouts ----------------
__global__ void k_gemm_qkv(const unsigned short* __restrict__ Ag,
                           const unsigned short* __restrict__ Btg,
                           const float* __restrict__ bias,
                           const float* __restrict__ gfeat,
                           unsigned short* __restrict__ qt,
                           unsigned short* __restrict__ kt,
                           unsigned short* __restrict__ vt) {
    int n0 = blockIdx.x * 128, m0 = blockIdx.y * 64, b = blockIdx.z;
    int t = threadIdx.x, lane = t & 63, w = t >> 6;
    int wm = w >> 1, wn = w & 1;
    __shared__ short A_lds[64][40];
    __shared__ short B_lds[128][40];
    const unsigned short* Bb = Btg + (size_t)b * NSP * CH;
    f32x4 acc[2][4];
    #pragma unroll
    for (int m = 0; m < 2; m++)
        #pragma unroll
        for (int n = 0; n < 4; n++) acc[m][n] = (f32x4){0.f, 0.f, 0.f, 0.f};
    int arow = t >> 2, akk = (t & 3) * 8;
    for (int k0 = 0; k0 < 256; k0 += 32) {
        __syncthreads();
        *(uint4*)&A_lds[arow][akk] = *(const uint4*)(Ag + (size_t)(m0 + arow) * CH + k0 + akk);
        #pragma unroll
        for (int hh = 0; hh < 2; hh++) {
            int f = t + hh * 256;
            int j = f >> 2, kk = (f & 3) * 8;
            *(uint4*)&B_lds[j][kk] = *(const uint4*)(Bb + (size_t)(n0 + j) * CH + k0 + kk);
        }
        __syncthreads();
        short8 a[2], bf[4];
        #pragma unroll
        for (int m = 0; m < 2; m++)
            a[m] = *(const short8*)&A_lds[wm * 32 + m * 16 + (lane & 15)][(lane >> 4) * 8];
        #pragma unroll
        for (int n = 0; n < 4; n++)
            bf[n] = *(const short8*)&B_lds[wn * 64 + n * 16 + (lane & 15)][(lane >> 4) * 8];
        #pragma unroll
        for (int m = 0; m < 2; m++)
            #pragma unroll
            for (int n = 0; n < 4; n++)
                acc[m][n] = __builtin_amdgcn_mfma_f32_16x16x32_bf16(a[m], bf[n], acc[m][n], 0, 0, 0);
    }
    int rbase = m0 + wm * 32 + ((lane >> 4) << 2);
    int cbase = n0 + wn * 64 + (lane & 15);
    #pragma unroll
    for (int m = 0; m < 2; m++) {
        int row0 = rbase + m * 16;
        int sec = row0 >> 8;
        int ch  = row0 & 255;
        int h = ch >> 5, d0 = ch & 31;
        #pragma unroll
        for (int n = 0; n < 4; n++) {
            int col = cbase + n * 16;
            if (sec == 0) {
                ushort4 pk;
                pk.x = f2bf(acc[m][n][0] + bias[row0 + 0]);
                pk.y = f2bf(acc[m][n][1] + bias[row0 + 1]);
                pk.z = f2bf(acc[m][n][2] + bias[row0 + 2]);
                pk.w = f2bf(acc[m][n][3] + bias[row0 + 3]);
                *(ushort4*)(qt + ((size_t)((b * 8 + h) * NSP + col)) * HD + d0) = pk;
            } else if (sec == 1) {
                ushort4 pk;
                #pragma unroll
                for (int i = 0; i < 4; i++) {
                    float v = (acc[m][n][i] + bias[row0 + i]
                               + 0.1f * gfeat[b * CH + ch + i]) * ATT_SCALE;
                    ((unsigned short*)&pk)[i] = f2bf(v);
                }
                *(ushort4*)(kt + ((size_t)((b * 8 + h) * NSP + col)) * HD + d0) = pk;
            } else {
                #pragma unroll
                for (int i = 0; i < 4; i++) {
                    float v = acc[m][n][i] + bias[row0 + i];
                    vt[((size_t)((b * 8 + h) * HD + d0 + i)) * NSP + col] = f2bf(v);
                }
            }
        }
    }
}

// ---------------- K5b: proj GEMM (reads att bf16, adds residuals) ----------------
__global__ void k_gemm_proj(const unsigned short* __restrict__ Ag,
                            const unsigned short* __restrict__ Btg,
                            const float* __restrict__ bias,
                            const float* __restrict__ gfeat,
                            const float* __restrict__ xres,
                            float* __restrict__ out) {
    int n0 = blockIdx.x * 128, m0 = blockIdx.y * 64, b = blockIdx.z;
    int t = threadIdx.x, lane = t & 63, w = t >> 6;
    int wm = w >> 1, wn = w & 1;
    __shared__ short A_lds[64][40];
    __shared__ short B_lds[128][40];
    const unsigned short* Bb = Btg + (size_t)b * NSP * CH;
    f32x4 acc[2][4];
    #pragma unroll
    for (int m = 0; m < 2; m++)
        #pragma unroll
        for (int n = 0; n < 4; n++) acc[m][n] = (f32x4){0.f, 0.f, 0.f, 0.f};
    int arow = t >> 2, akk = (t & 3) * 8;
    for (int k0 = 0; k0 < 256; k0 += 32) {
        __syncthreads();
        *(uint4*)&A_lds[arow][akk] = *(const uint4*)(Ag + (size_t)(m0 + arow) * CH + k0 + akk);
        #pragma unroll
        for (int hh = 0; hh < 2; hh++) {
            int f = t + hh * 256;
            int j = f >> 2, kk = (f & 3) * 8;
            *(uint4*)&B_lds[j][kk] = *(const uint4*)(Bb + (size_t)(n0 + j) * CH + k0 + kk);
        }
        __syncthreads();
        short8 a[2], bf[4];
        #pragma unroll
        for (int m = 0; m < 2; m++)
            a[m] = *(const short8*)&A_lds[wm * 32 + m * 16 + (lane & 15)][(lane >> 4) * 8];
        #pragma unroll
        for (int n = 0; n < 4; n++)
            bf[n] = *(const short8*)&B_lds[wn * 64 + n * 16 + (lane & 15)][(lane >> 4) * 8];
        #pragma unroll
        for (int m = 0; m < 2; m++)
            #pragma unroll
            for (int n = 0; n < 4; n++)
                acc[m][n] = __builtin_amdgcn_mfma_f32_16x16x32_bf16(a[m], bf[n], acc[m][n], 0, 0, 0);
    }
    int rbase = m0 + wm * 32 + ((lane >> 4) << 2);
    int cbase = n0 + wn * 64 + (lane & 15);
    #pragma unroll
    for (int m = 0; m < 2; m++) {
        #pragma unroll
        for (int n = 0; n < 4; n++) {
            int col = cbase + n * 16;
            #pragma unroll
            for (int i = 0; i < 4; i++) {
                int row = rbase + m * 16 + i;
                float add = bias[row] + 0.1f * gfeat[b * CH + row]
                          + xres[((size_t)(b * CH + row)) * NSP + col];
                out[((size_t)(b * CH + row)) * NSP + col] = acc[m][n][i] + add;
            }
        }
    }
}

// ------------- K6: 32x32 MFMA flash attention, NO-MAX, two j-half passes -------------
// S^T = mfma(K,Q): lane holds S[j][q=lane&31], j = jhalf*32 + (r&3) + 8*(r>>2) + 4*hi.
// P' = exp2(S) UNNORMALIZED (|S| <~ 20 << 127; max cancels in the split combine).
// PV B-frags built with __builtin_amdgcn_permlane32_swap (SSA builtin — r6's asm
// failure was in-place constraint modeling, not the dataflow):
//   swap(p0,p2) = ({p0.lo|p2.lo}, {p0.hi|p2.hi}) = (fu[0], fu[2]); swap(p1,p3) -> fu[1],fu[3].
// K_lds rows padded to 80B (20 banks): conflict-free b128 reads+writes.
__global__ __launch_bounds__(256, 8)
void k_flash32(const unsigned short* __restrict__ qt,
               const unsigned short* __restrict__ kt,
               const unsigned short* __restrict__ vt,
               unsigned short* __restrict__ opart, float* __restrict__ lpart) {
    const int h = blockIdx.y, b = blockIdx.z;
    const int s = blockIdx.x >> 5;
    const int t = threadIdx.x, lane = t & 63, w = t >> 6;
    const int lo32 = lane & 31, hi = lane >> 5;
    const int q0 = (blockIdx.x & 31) * 128 + w * 32;
    const int j0base = s * (NSP / NSPLIT);
    const unsigned short* qp = qt + ((size_t)(b * 8 + h) * NSP) * HD;
    const unsigned short* kp = kt + ((size_t)(b * 8 + h) * NSP) * HD;
    const unsigned short* vp = vt + ((size_t)(b * 8 + h) * HD) * NSP;
    __shared__ __align__(16) unsigned short K_lds[64 * 40];   // 80B rows, conflict-free
    __shared__ __align__(16) unsigned short V_lds[32 * 64];   // 128B rows, XOR slot swizzle

    short8 qf0 = *(const short8*)(qp + (size_t)(q0 + lo32) * HD + hi * 8);
    short8 qf1 = *(const short8*)(qp + (size_t)(q0 + lo32) * HD + 16 + hi * 8);
    f32x16 oacc;
    #pragma unroll
    for (int i = 0; i < 16; i++) oacc[i] = 0.f;
    float l = 0.f;

    // staging: K remapped so 8-lane phases hit rows 0-7 (bank-tiling); 1KB-coalesced/wave
    const int krow = (t & 7) + 8 * (t >> 5);
    const int kslot = (t >> 3) & 3;
    const int vd = t >> 3, vslot = t & 7;
    const unsigned short* kga = kp + (size_t)(j0base + krow) * HD + kslot * 8;
    const unsigned short* vga = vp + (size_t)vd * NSP + j0base + vslot * 8;
    const int kws = krow * 40 + kslot * 8;
    const int vws = vd * 64 + ((vslot ^ (vd & 7)) * 8);

    const int NT = NSP / NSPLIT / 64;
    for (int it = 0; it < NT; ++it) {
        {   // stage current tile (transient regs; L2-hit latency hidden by TLP)
            uint4 kreg = *(const uint4*)(kga + (size_t)it * 64 * HD);
            uint4 vreg = *(const uint4*)(vga + it * 64);
            *(uint4*)&K_lds[kws] = kreg;
            *(uint4*)&V_lds[vws] = vreg;
        }
        __syncthreads();
        // ---- two independent 32-j half passes (sv dead between them) ----
        #pragma unroll
        for (int hf = 0; hf < 2; hf++) {
            const int jj = hf * 32 + lo32;
            short8 kf0 = *(const short8*)&K_lds[jj * 40 + hi * 8];
            short8 kf1 = *(const short8*)&K_lds[jj * 40 + (2 + hi) * 8];
            f32x16 sv;
            __builtin_amdgcn_s_setprio(1);
            sv = __builtin_amdgcn_mfma_f32_32x32x16_bf16(kf0, qf0, ZERO16, 0, 0, 0);
            sv = __builtin_amdgcn_mfma_f32_32x32x16_bf16(kf1, qf1, sv, 0, 0, 0);
            __builtin_amdgcn_s_setprio(0);
            // P' = exp2(S), unnormalized (no max tracking)
            #pragma unroll
            for (int i = 0; i < 16; i++) sv[i] = __builtin_amdgcn_exp2f(sv[i]);
            // row sum: v_pk_add_f32 tree + permlane32_swap exchange
            // (direction-symmetric: {sx[0][l],sx[1][l]} = {own,partner} as a set)
            {
                #define SH2(V, I) __builtin_shufflevector(V, V, 2*(I), 2*(I)+1)
                f32x2 t0 = (SH2(sv,0) + SH2(sv,1)) + (SH2(sv,2) + SH2(sv,3));
                f32x2 t1 = (SH2(sv,4) + SH2(sv,5)) + (SH2(sv,6) + SH2(sv,7));
                f32x2 tt = t0 + t1;
                float sm = tt[0] + tt[1];
                #undef SH2
                unsigned sb = __builtin_bit_cast(unsigned, sm);
                auto sx = __builtin_amdgcn_permlane32_swap(sb, sb, false, false);
                l += __builtin_bit_cast(float, (unsigned)sx[0])
                   + __builtin_bit_cast(float, (unsigned)sx[1]);
            }
            // P->bf16 + permlane32_swap; O^T += V P
            #define PVSTEP(SV, BB, C) { \
                unsigned p0 = pkbf(SV[BB + 0], SV[BB + 1]); \
                unsigned p1 = pkbf(SV[BB + 2], SV[BB + 3]); \
                unsigned p2 = pkbf(SV[BB + 4], SV[BB + 5]); \
                unsigned p3 = pkbf(SV[BB + 6], SV[BB + 7]); \
                auto s02 = __builtin_amdgcn_permlane32_swap(p0, p2, false, false); \
                auto s13 = __builtin_amdgcn_permlane32_swap(p1, p3, false, false); \
                uint4 fu = make_uint4((unsigned)s02[0], (unsigned)s13[0], \
                                      (unsigned)s02[1], (unsigned)s13[1]); \
                short8 pa = *(short8*)&fu; \
                short8 vf = *(const short8*)&V_lds[lo32 * 64 + ((((C) * 2 + hi) ^ (lo32 & 7)) * 8)]; \
                oacc = __builtin_amdgcn_mfma_f32_32x32x16_bf16(vf, pa, oacc, 0, 0, 0); \
            }
            __builtin_amdgcn_s_setprio(1);
            PVSTEP(sv, 0, hf * 2)
            PVSTEP(sv, 8, hf * 2 + 1)
            __builtin_amdgcn_s_setprio(0);
            #undef PVSTEP
        }
        __syncthreads();   // protect K_lds/V_lds before next stage
    }
    // bf16 unnormalized partials: lane q = q0+lo32, d = 8*rr + 4*hi + 0..3
    unsigned short* op = opart + ((((size_t)s * BATCH + b) * HEADS + h) * NSP + q0 + lo32) * HD;
    #pragma unroll
    for (int rr = 0; rr < 4; rr++) {
        ushort4 pk4;
        pk4.x = f2bf(oacc[rr * 4 + 0]);
        pk4.y = f2bf(oacc[rr * 4 + 1]);
        pk4.z = f2bf(oacc[rr * 4 + 2]);
        pk4.w = f2bf(oacc[rr * 4 + 3]);
        *(ushort4*)(op + rr * 8 + hi * 4) = pk4;
    }
    if (hi == 0)
        lpart[(((size_t)s * BATCH + b) * HEADS + h) * NSP + q0 + lo32] = l;
}

// ------------- K7: combine NSPLIT partials -> att bf16 (b,p,c) -------------
__global__ __launch_bounds__(256)
void k_combine(const unsigned short* __restrict__ opart, const float* __restrict__ lpart,
               unsigned short* __restrict__ att) {
    int flat = blockIdx.x * 256 + threadIdx.x;   // 2*8*4096*4 = 262144
    int dchunk = flat & 3;
    int q = (flat >> 2) & (NSP - 1);
    int bh = flat >> 14;
    const size_t sO = (size_t)BATCH * HEADS * NSP * HD;
    const size_t sL = (size_t)BATCH * HEADS * NSP;
    size_t rowq = (size_t)bh * NSP + q;
    float den = 0.f;
    #pragma unroll
    for (int s2 = 0; s2 < NSPLIT; s2++) den += lpart[s2 * sL + rowq];
    float inv = 1.0f / den;
    float acc[8];
    #pragma unroll
    for (int e = 0; e < 8; e++) acc[e] = 0.f;
    #pragma unroll
    for (int s2 = 0; s2 < NSPLIT; s2++) {
        uint4 v = *(const uint4*)(opart + s2 * sO + rowq * HD + dchunk * 8);
        const unsigned short* pv = (const unsigned short*)&v;
        #pragma unroll
        for (int e = 0; e < 8; e++) {
            unsigned u = (unsigned)pv[e] << 16;
            acc[e] += *(float*)&u;
        }
    }
    uint4 o;
    o.x = (unsigned)f2bf(acc[0] * inv) | ((unsigned)f2bf(acc[1] * inv) << 16);
    o.y = (unsigned)f2bf(acc[2] * inv) | ((unsigned)f2bf(acc[3] * inv) << 16);
    o.z = (unsigned)f2bf(acc[4] * inv) | ((unsigned)f2bf(acc[5] * inv) << 16);
    o.w = (unsigned)f2bf(acc[6] * inv) | ((unsigned)f2bf(acc[7] * inv) << 16);
    *(uint4*)(att + ((size_t)((bh >> 3) * NSP + q)) * CH + (bh & 7) * HD + dchunk * 8) = o;
}

extern "C" void kernel_launch(void* const* d_in, const int* in_sizes, int n_in,
                              void* d_out, int out_size, void* d_ws, size_t ws_size,
                              hipStream_t stream) {
    const float* x       = (const float*)d_in[0];
    const float* gn_w    = (const float*)d_in[1];
    const float* gn_b    = (const float*)d_in[2];
    const float* qkv_w   = (const float*)d_in[3];
    const float* qkv_b   = (const float*)d_in[4];
    const float* proj_w  = (const float*)d_in[5];
    const float* proj_b  = (const float*)d_in[6];
    const float* gproj_w = (const float*)d_in[7];
    const float* gproj_b = (const float*)d_in[8];
    char* ws = (char*)d_ws;
    float*          stats  = (float*)(ws);                      // 512 B
    float*          gpart  = (float*)(ws + 1024);               // 128 KB
    float*          gfeat  = (float*)(ws + 132096);             // 2 KB
    unsigned short* wbf    = (unsigned short*)(ws + 134144);    // 512 KB bf16 weights
    unsigned short* xnt    = (unsigned short*)(ws + 658432);    // (b,p,c) bf16, 4 MB (dead after qkv GEMM)
    float*          lpart  = (float*)(ws + 658432);             // overlays xnt: 1 MB l per (s,q)
    unsigned short* qt     = (unsigned short*)(ws + 4852736);   // (b,h,n,hd) bf16, 4 MB
    unsigned short* kt     = (unsigned short*)(ws + 9047040);   // (b,h,n,hd) bf16, 4 MB
    unsigned short* vt     = (unsigned short*)(ws + 13241344);  // (b,h,hd,n) bf16, 4 MB
    unsigned short* att    = (unsigned short*)(ws + 17435648);  // (b,p,c) bf16, 4 MB
    unsigned short* opart  = (unsigned short*)(ws + 21629952);  // 4 splits bf16 O, 16.8 MB
    float* out = (float*)d_out;

    hipLaunchKernelGGL(k_gnstats, dim3(64), dim3(256), 0, stream, x, stats);
    hipLaunchKernelGGL(k_gnapply, dim3(64, 4, 2), dim3(256), 0, stream,
                       x, gn_w, gn_b, stats, xnt, gpart);
    hipLaunchKernelGGL(k_gproj, dim3(2), dim3(256), 0, stream,
                       gpart, gproj_w, gproj_b, gfeat);
    hipLaunchKernelGGL(k_convert, dim3(256), dim3(256), 0, stream, qkv_w, proj_w, wbf);
    hipLaunchKernelGGL(k_gemm_qkv, dim3(32, 12, 2), dim3(256), 0, stream,
                       wbf, xnt, qkv_b, gfeat, qt, kt, vt);
    hipLaunchKernelGGL(k_flash32, dim3(32 * NSPLIT, 8, 2), dim3(256), 0, stream,
                       qt, kt, vt, opart, lpart);
    hipLaunchKernelGGL(k_combine, dim3(1024), dim3(256), 0, stream,
                       opart, lpart, att);
    hipLaunchKernelGGL(k_gemm_proj, dim3(32, 4, 2), dim3(256), 0, stream,
                       wbf + 196608, att, proj_b, gfeat, x, out);
}

// Round 14
// 109.890 us; speedup vs baseline: 1.1772x; 1.0176x over previous
//
#include <hip/hip_runtime.h>
#include <hip/hip_bf16.h>
#include <stdint.h>

#define BATCH 2
#define CH 256
#define NSP 4096          // 64*64 spatial
#define HEADS 8
#define HD 32
#define GROUPS 32
#define EPS_GN 1e-5f
#define NSPLIT 4          // flash KV-sequence splits

// hd^-0.5 * log2(e): folds softmax scale AND exp->exp2 conversion into k
#define ATT_SCALE (0.17677669529663687f * 1.4426950408889634f)

typedef __attribute__((ext_vector_type(8))) short short8;    // 8 bf16 (MFMA A/B frag)
typedef __attribute__((ext_vector_type(4))) float f32x4;     // 16x16 C/D frag
typedef __attribute__((ext_vector_type(16))) float f32x16;   // 32x32 C/D frag
typedef __attribute__((ext_vector_type(2))) float f32x2;     // v_pk_add_f32 operand

#define ZERO16 ((f32x16){0.f,0.f,0.f,0.f,0.f,0.f,0.f,0.f,0.f,0.f,0.f,0.f,0.f,0.f,0.f,0.f})

static __device__ __forceinline__ unsigned short f2bf(float f) {
    union { float f; unsigned u; } v; v.f = f;
    unsigned r = v.u + 0x7fffu + ((v.u >> 16) & 1u);  // RNE
    return (unsigned short)(r >> 16);
}
static __device__ __forceinline__ float bf2f(unsigned short u) {
    unsigned v = (unsigned)u << 16;
    return *(float*)&v;
}
static __device__ __forceinline__ unsigned pkbf(float x, float y) {
    __hip_bfloat162 h = __float22bfloat162_rn(make_float2(x, y));  // -> v_cvt_pk_bf16_f32
    return *(unsigned*)&h;
}

// ---------------- K1: GroupNorm stats: one block per (b,group) ----------------
__global__ void k_gnstats(const float* __restrict__ x, float* __restrict__ stats) {
    int bg = blockIdx.x;
    int t = threadIdx.x;
    const float4* b4 = (const float4*)(x + (size_t)bg * (8 * NSP));
    float s = 0.f, sq = 0.f;
    #pragma unroll
    for (int i = 0; i < 32; i++) {
        float4 v = b4[t + i * 256];
        s  += v.x + v.y + v.z + v.w;
        sq += v.x * v.x + v.y * v.y + v.z * v.z + v.w * v.w;
    }
    #pragma unroll
    for (int off = 32; off > 0; off >>= 1) {
        s  += __shfl_down(s, off);
        sq += __shfl_down(sq, off);
    }
    __shared__ float rs[4], rq[4];
    int w = t >> 6;
    if ((t & 63) == 0) { rs[w] = s; rq[w] = sq; }
    __syncthreads();
    if (t == 0) {
        float S = rs[0] + rs[1] + rs[2] + rs[3];
        float Q = rq[0] + rq[1] + rq[2] + rq[3];
        float mu  = S * (1.0f / 32768.0f);
        float var = Q * (1.0f / 32768.0f) - mu * mu;
        stats[bg * 2]     = mu;
        stats[bg * 2 + 1] = rsqrtf(var + EPS_GN);
    }
}

// ------ K2: apply GN, write xn^T (b,p,c) bf16, per-channel partial sums ------
__global__ void k_gnapply(const float* __restrict__ x, const float* __restrict__ gn_w,
                          const float* __restrict__ gn_b, const float* __restrict__ stats,
                          unsigned short* __restrict__ xnt, float* __restrict__ gpart) {
    int p0 = blockIdx.x * 64, c0 = blockIdx.y * 64, b = blockIdx.z;
    int t = threadIdx.x;
    __shared__ float tile[64][65];
    int ci0 = t >> 4, pq = t & 15;
    #pragma unroll
    for (int k = 0; k < 4; k++) {
        int ci = ci0 + k * 16;
        int c = c0 + ci;
        float mu   = stats[(b * GROUPS + (c >> 3)) * 2];
        float rstd = stats[(b * GROUPS + (c >> 3)) * 2 + 1];
        float w  = gn_w[c] * rstd;
        float bb = gn_b[c] - mu * w;
        float4 v = *(const float4*)(x + ((size_t)(b * CH + c)) * NSP + p0 + pq * 4);
        tile[ci][pq * 4 + 0] = v.x * w + bb;
        tile[ci][pq * 4 + 1] = v.y * w + bb;
        tile[ci][pq * 4 + 2] = v.z * w + bb;
        tile[ci][pq * 4 + 3] = v.w * w + bb;
    }
    __syncthreads();
    int pi = t >> 2, cb = (t & 3) * 16;
    unsigned pack[8];
    #pragma unroll
    for (int e = 0; e < 8; e++) {
        float a  = tile[cb + 2 * e][pi];
        float bv = tile[cb + 2 * e + 1][pi];
        pack[e] = (unsigned)f2bf(a) | ((unsigned)f2bf(bv) << 16);
    }
    uint4* dst = (uint4*)(xnt + ((size_t)(b * NSP + p0 + pi)) * CH + c0 + cb);
    dst[0] = make_uint4(pack[0], pack[1], pack[2], pack[3]);
    dst[1] = make_uint4(pack[4], pack[5], pack[6], pack[7]);
    if (t < 64) {
        float s = 0.f;
        #pragma unroll
        for (int j = 0; j < 64; j++) s += tile[t][j];
        gpart[((size_t)(b * CH + c0 + t)) * 64 + blockIdx.x] = s;
    }
}

// -------- K3: gfeat = mean(xn) @ gproj_w^T + gproj_b --------
__global__ void k_gproj(const float* __restrict__ gpart, const float* __restrict__ gproj_w,
                        const float* __restrict__ gproj_b, float* __restrict__ gfeat) {
    int b = blockIdx.x, t = threadIdx.x;
    __shared__ float graw[256];
    const float* p = gpart + ((size_t)(b * CH + t)) * 64;
    float s = 0.f;
    #pragma unroll
    for (int i = 0; i < 64; i++) s += p[i];
    graw[t] = s * (1.0f / 4096.0f);
    __syncthreads();
    float acc = gproj_b[t];
    const float* wr = gproj_w + (size_t)t * CH;
    #pragma unroll 8
    for (int c = 0; c < 256; c++) acc += graw[c] * wr[c];
    gfeat[b * CH + t] = acc;
}

// ---------------- K4: convert qkv_w + proj_w to bf16 ----------------
__global__ void k_convert(const float* __restrict__ qkv_w, const float* __restrict__ proj_w,
                          unsigned short* __restrict__ wbf) {
    int i4 = blockIdx.x * 256 + threadIdx.x;
    const float* src = (i4 < 49152) ? (qkv_w + (size_t)i4 * 4)
                                    : (proj_w + (size_t)(i4 - 49152) * 4);
    float4 v = *(const float4*)src;
    ushort4 o;
    o.x = f2bf(v.x); o.y = f2bf(v.y); o.z = f2bf(v.z); o.w = f2bf(v.w);
    *(ushort4*)(wbf + (size_t)i4 * 4) = o;
}

// ---------------- K5a: QKV GEMM -> bf16 q/k/v in attention layouts ----------------
__global__ void k_gemm_qkv(const unsigned short* __restrict__ Ag,
                           const unsigned short* __restrict__ Btg,
                           const float* __restrict__ bias,
                           const float* __restrict__ gfeat,
                           unsigned short* __restrict__ qt,
                           unsigned short* __restrict__ kt,
                           unsigned short* __restrict__ vt) {
    int n0 = blockIdx.x * 128, m0 = blockIdx.y * 64, b = blockIdx.z;
    int t = threadIdx.x, lane = t & 63, w = t >> 6;
    int wm = w >> 1, wn = w & 1;
    __shared__ short A_lds[64][40];
    __shared__ short B_lds[128][40];
    const unsigned short* Bb = Btg + (size_t)b * NSP * CH;
    f32x4 acc[2][4];
    #pragma unroll
    for (int m = 0; m < 2; m++)
        #pragma unroll
        for (int n = 0; n < 4; n++) acc[m][n] = (f32x4){0.f, 0.f, 0.f, 0.f};
    int arow = t >> 2, akk = (t & 3) * 8;
    for (int k0 = 0; k0 < 256; k0 += 32) {
        __syncthreads();
        *(uint4*)&A_lds[arow][akk] = *(const uint4*)(Ag + (size_t)(m0 + arow) * CH + k0 + akk);
        #pragma unroll
        for (int hh = 0; hh < 2; hh++) {
            int f = t + hh * 256;
            int j = f >> 2, kk = (f & 3) * 8;
            *(uint4*)&B_lds[j][kk] = *(const uint4*)(Bb + (size_t)(n0 + j) * CH + k0 + kk);
        }
        __syncthreads();
        short8 a[2], bf[4];
        #pragma unroll
        for (int m = 0; m < 2; m++)
            a[m] = *(const short8*)&A_lds[wm * 32 + m * 16 + (lane & 15)][(lane >> 4) * 8];
        #pragma unroll
        for (int n = 0; n < 4; n++)
            bf[n] = *(const short8*)&B_lds[wn * 64 + n * 16 + (lane & 15)][(lane >> 4) * 8];
        #pragma unroll
        for (int m = 0; m < 2; m++)
            #pragma unroll
            for (int n = 0; n < 4; n++)
                acc[m][n] = __builtin_amdgcn_mfma_f32_16x16x32_bf16(a[m], bf[n], acc[m][n], 0, 0, 0);
    }
    int rbase = m0 + wm * 32 + ((lane >> 4) << 2);
    int cbase = n0 + wn * 64 + (lane & 15);
    #pragma unroll
    for (int m = 0; m < 2; m++) {
        int row0 = rbase + m * 16;
        int sec = row0 >> 8;
        int ch  = row0 & 255;
        int h = ch >> 5, d0 = ch & 31;
        #pragma unroll
        for (int n = 0; n < 4; n++) {
            int col = cbase + n * 16;
            if (sec == 0) {
                ushort4 pk;
                pk.x = f2bf(acc[m][n][0] + bias[row0 + 0]);
                pk.y = f2bf(acc[m][n][1] + bias[row0 + 1]);
                pk.z = f2bf(acc[m][n][2] + bias[row0 + 2]);
                pk.w = f2bf(acc[m][n][3] + bias[row0 + 3]);
                *(ushort4*)(qt + ((size_t)((b * 8 + h) * NSP + col)) * HD + d0) = pk;
            } else if (sec == 1) {
                ushort4 pk;
                #pragma unroll
                for (int i = 0; i < 4; i++) {
                    float v = (acc[m][n][i] + bias[row0 + i]
                               + 0.1f * gfeat[b * CH + ch + i]) * ATT_SCALE;
                    ((unsigned short*)&pk)[i] = f2bf(v);
                }
                *(ushort4*)(kt + ((size_t)((b * 8 + h) * NSP + col)) * HD + d0) = pk;
            } else {
                #pragma unroll
                for (int i = 0; i < 4; i++) {
                    float v = acc[m][n][i] + bias[row0 + i];
                    vt[((size_t)((b * 8 + h) * HD + d0 + i)) * NSP + col] = f2bf(v);
                }
            }
        }
    }
}

// -------- K5b: proj GEMM with FUSED split-combine in B-staging --------
// B[p][c] = (sum_s opart[s][b][h(c)][p][c&31]) / (sum_s lpart[s][b][h(c)][p])
// (same fp32 arithmetic as the old k_combine, relocated; h = (k0+kk)>>5 = k0>>5)
__global__ void k_gemm_proj(const unsigned short* __restrict__ Ag,
                            const unsigned short* __restrict__ opart,
                            const float* __restrict__ lpart,
                            const float* __restrict__ bias,
                            const float* __restrict__ gfeat,
                            const float* __restrict__ xres,
                            float* __restrict__ out) {
    int n0 = blockIdx.x * 128, m0 = blockIdx.y * 64, b = blockIdx.z;
    int t = threadIdx.x, lane = t & 63, w = t >> 6;
    int wm = w >> 1, wn = w & 1;
    __shared__ short A_lds[64][40];
    __shared__ short B_lds[128][40];
    const size_t sO = (size_t)BATCH * HEADS * NSP;   // opart row-stride per split (x HD)
    f32x4 acc[2][4];
    #pragma unroll
    for (int m = 0; m < 2; m++)
        #pragma unroll
        for (int n = 0; n < 4; n++) acc[m][n] = (f32x4){0.f, 0.f, 0.f, 0.f};
    int arow = t >> 2, akk = (t & 3) * 8;
    for (int k0 = 0; k0 < 256; k0 += 32) {
        __syncthreads();
        *(uint4*)&A_lds[arow][akk] = *(const uint4*)(Ag + (size_t)(m0 + arow) * CH + k0 + akk);
        int hidx = k0 >> 5;
        #pragma unroll
        for (int hh = 0; hh < 2; hh++) {
            int f = t + hh * 256;
            int j = f >> 2, kk = (f & 3) * 8;
            size_t rowq = ((size_t)(b * HEADS + hidx)) * NSP + n0 + j;
            float den = 0.f;
            float a0 = 0.f, a1 = 0.f, a2 = 0.f, a3 = 0.f,
                  a4 = 0.f, a5 = 0.f, a6 = 0.f, a7 = 0.f;
            #pragma unroll
            for (int s2 = 0; s2 < NSPLIT; s2++) {
                size_t off = (size_t)s2 * sO + rowq;
                den += lpart[off];
                uint4 v = *(const uint4*)(opart + off * HD + kk);
                const unsigned short* pv = (const unsigned short*)&v;
                a0 += bf2f(pv[0]); a1 += bf2f(pv[1]);
                a2 += bf2f(pv[2]); a3 += bf2f(pv[3]);
                a4 += bf2f(pv[4]); a5 += bf2f(pv[5]);
                a6 += bf2f(pv[6]); a7 += bf2f(pv[7]);
            }
            float inv = 1.0f / den;
            uint4 pk;
            pk.x = (unsigned)f2bf(a0 * inv) | ((unsigned)f2bf(a1 * inv) << 16);
            pk.y = (unsigned)f2bf(a2 * inv) | ((unsigned)f2bf(a3 * inv) << 16);
            pk.z = (unsigned)f2bf(a4 * inv) | ((unsigned)f2bf(a5 * inv) << 16);
            pk.w = (unsigned)f2bf(a6 * inv) | ((unsigned)f2bf(a7 * inv) << 16);
            *(uint4*)&B_lds[j][kk] = pk;
        }
        __syncthreads();
        short8 a[2], bf[4];
        #pragma unroll
        for (int m = 0; m < 2; m++)
            a[m] = *(const short8*)&A_lds[wm * 32 + m * 16 + (lane & 15)][(lane >> 4) * 8];
        #pragma unroll
        for (int n = 0; n < 4; n++)
            bf[n] = *(const short8*)&B_lds[wn * 64 + n * 16 + (lane & 15)][(lane >> 4) * 8];
        #pragma unroll
        for (int m = 0; m < 2; m++)
            #pragma unroll
            for (int n = 0; n < 4; n++)
                acc[m][n] = __builtin_amdgcn_mfma_f32_16x16x32_bf16(a[m], bf[n], acc[m][n], 0, 0, 0);
    }
    int rbase = m0 + wm * 32 + ((lane >> 4) << 2);
    int cbase = n0 + wn * 64 + (lane & 15);
    #pragma unroll
    for (int m = 0; m < 2; m++) {
        #pragma unroll
        for (int n = 0; n < 4; n++) {
            int col = cbase + n * 16;
            #pragma unroll
            for (int i = 0; i < 4; i++) {
                int row = rbase + m * 16 + i;
                float add = bias[row] + 0.1f * gfeat[b * CH + row]
                          + xres[((size_t)(b * CH + row)) * NSP + col];
                out[((size_t)(b * CH + row)) * NSP + col] = acc[m][n][i] + add;
            }
        }
    }
}

// ------------- K6: 32x32 MFMA flash attention, NO-MAX, two j-half passes -------------
// S^T = mfma(K,Q): lane holds S[j][q=lane&31], j = jhalf*32 + (r&3) + 8*(r>>2) + 4*hi.
// P' = exp2(S) UNNORMALIZED (|S| <~ 20 << 127; max cancels in the split combine).
// PV B-frags via __builtin_amdgcn_permlane32_swap (SSA builtin, r13-proven).
// K rows 80B (20 banks): conflict-free. V rows padded to 68 shorts (136B == 2 mod 32
// banks): row bank-base walks 2*row -> only lo32<->lo32+16 alias on reads = 2-way = free.
// No XOR swizzle needed on V anymore (also kills the per-PVSTEP xor addressing).
__global__ __launch_bounds__(256, 8)
void k_flash32(const unsigned short* __restrict__ qt,
               const unsigned short* __restrict__ kt,
               const unsigned short* __restrict__ vt,
               unsigned short* __restrict__ opart, float* __restrict__ lpart) {
    const int h = blockIdx.y, b = blockIdx.z;
    const int s = blockIdx.x >> 5;
    const int t = threadIdx.x, lane = t & 63, w = t >> 6;
    const int lo32 = lane & 31, hi = lane >> 5;
    const int q0 = (blockIdx.x & 31) * 128 + w * 32;
    const int j0base = s * (NSP / NSPLIT);
    const unsigned short* qp = qt + ((size_t)(b * 8 + h) * NSP) * HD;
    const unsigned short* kp = kt + ((size_t)(b * 8 + h) * NSP) * HD;
    const unsigned short* vp = vt + ((size_t)(b * 8 + h) * HD) * NSP;
    __shared__ __align__(16) unsigned short K_lds[64 * 40];   // 80B rows, conflict-free
    __shared__ __align__(16) unsigned short V_lds[32 * 68];   // 136B rows, conflict-free

    short8 qf0 = *(const short8*)(qp + (size_t)(q0 + lo32) * HD + hi * 8);
    short8 qf1 = *(const short8*)(qp + (size_t)(q0 + lo32) * HD + 16 + hi * 8);
    f32x16 oacc;
    #pragma unroll
    for (int i = 0; i < 16; i++) oacc[i] = 0.f;
    float l = 0.f;

    // staging: K remapped so 8-lane phases hit rows 0-7 (bank-tiling); 1KB-coalesced/wave
    const int krow = (t & 7) + 8 * (t >> 5);
    const int kslot = (t >> 3) & 3;
    const int vd = t >> 3, vslot = t & 7;
    const unsigned short* kga = kp + (size_t)(j0base + krow) * HD + kslot * 8;
    const unsigned short* vga = vp + (size_t)vd * NSP + j0base + vslot * 8;
    const int kws = krow * 40 + kslot * 8;
    const int vws = vd * 68 + vslot * 8;

    const int NT = NSP / NSPLIT / 64;
    for (int it = 0; it < NT; ++it) {
        {   // stage current tile (transient regs; L2-hit latency hidden by TLP)
            uint4 kreg = *(const uint4*)(kga + (size_t)it * 64 * HD);
            uint4 vreg = *(const uint4*)(vga + it * 64);
            *(uint4*)&K_lds[kws] = kreg;
            *(uint4*)&V_lds[vws] = vreg;
        }
        __syncthreads();
        // ---- two independent 32-j half passes (sv dead between them) ----
        #pragma unroll
        for (int hf = 0; hf < 2; hf++) {
            const int jj = hf * 32 + lo32;
            short8 kf0 = *(const short8*)&K_lds[jj * 40 + hi * 8];
            short8 kf1 = *(const short8*)&K_lds[jj * 40 + (2 + hi) * 8];
            f32x16 sv;
            __builtin_amdgcn_s_setprio(1);
            sv = __builtin_amdgcn_mfma_f32_32x32x16_bf16(kf0, qf0, ZERO16, 0, 0, 0);
            sv = __builtin_amdgcn_mfma_f32_32x32x16_bf16(kf1, qf1, sv, 0, 0, 0);
            __builtin_amdgcn_s_setprio(0);
            // P' = exp2(S), unnormalized (no max tracking)
            #pragma unroll
            for (int i = 0; i < 16; i++) sv[i] = __builtin_amdgcn_exp2f(sv[i]);
            // row sum: v_pk_add_f32 tree + permlane32_swap exchange (symmetric)
            {
                #define SH2(V, I) __builtin_shufflevector(V, V, 2*(I), 2*(I)+1)
                f32x2 t0 = (SH2(sv,0) + SH2(sv,1)) + (SH2(sv,2) + SH2(sv,3));
                f32x2 t1 = (SH2(sv,4) + SH2(sv,5)) + (SH2(sv,6) + SH2(sv,7));
                f32x2 tt = t0 + t1;
                float sm = tt[0] + tt[1];
                #undef SH2
                unsigned sb = __builtin_bit_cast(unsigned, sm);
                auto sx = __builtin_amdgcn_permlane32_swap(sb, sb, false, false);
                l += __builtin_bit_cast(float, (unsigned)sx[0])
                   + __builtin_bit_cast(float, (unsigned)sx[1]);
            }
            // P->bf16 + permlane32_swap; O^T += V P
            #define PVSTEP(SV, BB, C) { \
                unsigned p0 = pkbf(SV[BB + 0], SV[BB + 1]); \
                unsigned p1 = pkbf(SV[BB + 2], SV[BB + 3]); \
                unsigned p2 = pkbf(SV[BB + 4], SV[BB + 5]); \
                unsigned p3 = pkbf(SV[BB + 6], SV[BB + 7]); \
                auto s02 = __builtin_amdgcn_permlane32_swap(p0, p2, false, false); \
                auto s13 = __builtin_amdgcn_permlane32_swap(p1, p3, false, false); \
                uint4 fu = make_uint4((unsigned)s02[0], (unsigned)s13[0], \
                                      (unsigned)s02[1], (unsigned)s13[1]); \
                short8 pa = *(short8*)&fu; \
                short8 vf = *(const short8*)&V_lds[lo32 * 68 + ((C) * 2 + hi) * 8]; \
                oacc = __builtin_amdgcn_mfma_f32_32x32x16_bf16(vf, pa, oacc, 0, 0, 0); \
            }
            __builtin_amdgcn_s_setprio(1);
            PVSTEP(sv, 0, hf * 2)
            PVSTEP(sv, 8, hf * 2 + 1)
            __builtin_amdgcn_s_setprio(0);
            #undef PVSTEP
        }
        __syncthreads();   // protect K_lds/V_lds before next stage
    }
    // bf16 unnormalized partials: lane q = q0+lo32, d = 8*rr + 4*hi + 0..3
    unsigned short* op = opart + ((((size_t)s * BATCH + b) * HEADS + h) * NSP + q0 + lo32) * HD;
    #pragma unroll
    for (int rr = 0; rr < 4; rr++) {
        ushort4 pk4;
        pk4.x = f2bf(oacc[rr * 4 + 0]);
        pk4.y = f2bf(oacc[rr * 4 + 1]);
        pk4.z = f2bf(oacc[rr * 4 + 2]);
        pk4.w = f2bf(oacc[rr * 4 + 3]);
        *(ushort4*)(op + rr * 8 + hi * 4) = pk4;
    }
    if (hi == 0)
        lpart[(((size_t)s * BATCH + b) * HEADS + h) * NSP + q0 + lo32] = l;
}

extern "C" void kernel_launch(void* const* d_in, const int* in_sizes, int n_in,
                              void* d_out, int out_size, void* d_ws, size_t ws_size,
                              hipStream_t stream) {
    const float* x       = (const float*)d_in[0];
    const float* gn_w    = (const float*)d_in[1];
    const float* gn_b    = (const float*)d_in[2];
    const float* qkv_w   = (const float*)d_in[3];
    const float* qkv_b   = (const float*)d_in[4];
    const float* proj_w  = (const float*)d_in[5];
    const float* proj_b  = (const float*)d_in[6];
    const float* gproj_w = (const float*)d_in[7];
    const float* gproj_b = (const float*)d_in[8];
    char* ws = (char*)d_ws;
    float*          stats  = (float*)(ws);                      // 512 B
    float*          gpart  = (float*)(ws + 1024);               // 128 KB
    float*          gfeat  = (float*)(ws + 132096);             // 2 KB
    unsigned short* wbf    = (unsigned short*)(ws + 134144);    // 512 KB bf16 weights
    unsigned short* xnt    = (unsigned short*)(ws + 658432);    // (b,p,c) bf16, 4 MB (dead after qkv GEMM)
    float*          lpart  = (float*)(ws + 658432);             // overlays xnt: 1 MB l per (s,q)
    unsigned short* qt     = (unsigned short*)(ws + 4852736);   // (b,h,n,hd) bf16, 4 MB
    unsigned short* kt     = (unsigned short*)(ws + 9047040);   // (b,h,n,hd) bf16, 4 MB
    unsigned short* vt     = (unsigned short*)(ws + 13241344);  // (b,h,hd,n) bf16, 4 MB
    unsigned short* opart  = (unsigned short*)(ws + 21629952);  // 4 splits bf16 O, 16.8 MB
    float* out = (float*)d_out;

    hipLaunchKernelGGL(k_gnstats, dim3(64), dim3(256), 0, stream, x, stats);
    hipLaunchKernelGGL(k_gnapply, dim3(64, 4, 2), dim3(256), 0, stream,
                       x, gn_w, gn_b, stats, xnt, gpart);
    hipLaunchKernelGGL(k_gproj, dim3(2), dim3(256), 0, stream,
                       gpart, gproj_w, gproj_b, gfeat);
    hipLaunchKernelGGL(k_convert, dim3(256), dim3(256), 0, stream, qkv_w, proj_w, wbf);
    hipLaunchKernelGGL(k_gemm_qkv, dim3(32, 12, 2), dim3(256), 0, stream,
                       wbf, xnt, qkv_b, gfeat, qt, kt, vt);
    hipLaunchKernelGGL(k_flash32, dim3(32 * NSPLIT, 8, 2), dim3(256), 0, stream,
                       qt, kt, vt, opart, lpart);
    hipLaunchKernelGGL(k_gemm_proj, dim3(32, 4, 2), dim3(256), 0, stream,
                       wbf + 196608, opart, lpart, proj_b, gfeat, x, out);
}

// Round 15
// 108.094 us; speedup vs baseline: 1.1968x; 1.0166x over previous
//
#include <hip/hip_runtime.h>
#include <hip/hip_bf16.h>
#include <stdint.h>

#define BATCH 2
#define CH 256
#define NSP 4096          // 64*64 spatial
#define HEADS 8
#define HD 32
#define GROUPS 32
#define EPS_GN 1e-5f
#define NSPLIT 4          // flash KV-sequence splits

// hd^-0.5 * log2(e): folds softmax scale AND exp->exp2 conversion into k
#define ATT_SCALE (0.17677669529663687f * 1.4426950408889634f)

typedef __attribute__((ext_vector_type(8))) short short8;    // 8 bf16 (MFMA A/B frag)
typedef __attribute__((ext_vector_type(4))) float f32x4;     // 16x16 C/D frag
typedef __attribute__((ext_vector_type(16))) float f32x16;   // 32x32 C/D frag
typedef __attribute__((ext_vector_type(2))) float f32x2;     // v_pk_add_f32 operand

#define ZERO16 ((f32x16){0.f,0.f,0.f,0.f,0.f,0.f,0.f,0.f,0.f,0.f,0.f,0.f,0.f,0.f,0.f,0.f})

static __device__ __forceinline__ unsigned short f2bf(float f) {
    union { float f; unsigned u; } v; v.f = f;
    unsigned r = v.u + 0x7fffu + ((v.u >> 16) & 1u);  // RNE
    return (unsigned short)(r >> 16);
}
static __device__ __forceinline__ float bf2f(unsigned short u) {
    unsigned v = (unsigned)u << 16;
    return *(float*)&v;
}
static __device__ __forceinline__ unsigned pkbf(float x, float y) {
    __hip_bfloat162 h = __float22bfloat162_rn(make_float2(x, y));  // -> v_cvt_pk_bf16_f32
    return *(unsigned*)&h;
}

// ---------------- K1: GroupNorm stats: one block per (b,group) ----------------
__global__ void k_gnstats(const float* __restrict__ x, float* __restrict__ stats) {
    int bg = blockIdx.x;
    int t = threadIdx.x;
    const float4* b4 = (const float4*)(x + (size_t)bg * (8 * NSP));
    float s = 0.f, sq = 0.f;
    #pragma unroll
    for (int i = 0; i < 32; i++) {
        float4 v = b4[t + i * 256];
        s  += v.x + v.y + v.z + v.w;
        sq += v.x * v.x + v.y * v.y + v.z * v.z + v.w * v.w;
    }
    #pragma unroll
    for (int off = 32; off > 0; off >>= 1) {
        s  += __shfl_down(s, off);
        sq += __shfl_down(sq, off);
    }
    __shared__ float rs[4], rq[4];
    int w = t >> 6;
    if ((t & 63) == 0) { rs[w] = s; rq[w] = sq; }
    __syncthreads();
    if (t == 0) {
        float S = rs[0] + rs[1] + rs[2] + rs[3];
        float Q = rq[0] + rq[1] + rq[2] + rq[3];
        float mu  = S * (1.0f / 32768.0f);
        float var = Q * (1.0f / 32768.0f) - mu * mu;
        stats[bg * 2]     = mu;
        stats[bg * 2 + 1] = rsqrtf(var + EPS_GN);
    }
}

// ------ K2: apply GN, write xn^T (b,p,c) bf16, per-channel partial sums ------
__global__ void k_gnapply(const float* __restrict__ x, const float* __restrict__ gn_w,
                          const float* __restrict__ gn_b, const float* __restrict__ stats,
                          unsigned short* __restrict__ xnt, float* __restrict__ gpart) {
    int p0 = blockIdx.x * 64, c0 = blockIdx.y * 64, b = blockIdx.z;
    int t = threadIdx.x;
    __shared__ float tile[64][65];
    int ci0 = t >> 4, pq = t & 15;
    #pragma unroll
    for (int k = 0; k < 4; k++) {
        int ci = ci0 + k * 16;
        int c = c0 + ci;
        float mu   = stats[(b * GROUPS + (c >> 3)) * 2];
        float rstd = stats[(b * GROUPS + (c >> 3)) * 2 + 1];
        float w  = gn_w[c] * rstd;
        float bb = gn_b[c] - mu * w;
        float4 v = *(const float4*)(x + ((size_t)(b * CH + c)) * NSP + p0 + pq * 4);
        tile[ci][pq * 4 + 0] = v.x * w + bb;
        tile[ci][pq * 4 + 1] = v.y * w + bb;
        tile[ci][pq * 4 + 2] = v.z * w + bb;
        tile[ci][pq * 4 + 3] = v.w * w + bb;
    }
    __syncthreads();
    int pi = t >> 2, cb = (t & 3) * 16;
    unsigned pack[8];
    #pragma unroll
    for (int e = 0; e < 8; e++) {
        float a  = tile[cb + 2 * e][pi];
        float bv = tile[cb + 2 * e + 1][pi];
        pack[e] = (unsigned)f2bf(a) | ((unsigned)f2bf(bv) << 16);
    }
    uint4* dst = (uint4*)(xnt + ((size_t)(b * NSP + p0 + pi)) * CH + c0 + cb);
    dst[0] = make_uint4(pack[0], pack[1], pack[2], pack[3]);
    dst[1] = make_uint4(pack[4], pack[5], pack[6], pack[7]);
    if (t < 64) {
        float s = 0.f;
        #pragma unroll
        for (int j = 0; j < 64; j++) s += tile[t][j];
        gpart[((size_t)(b * CH + c0 + t)) * 64 + blockIdx.x] = s;
    }
}

// -------- K3: gfeat = mean(xn) @ gproj_w^T + gproj_b --------
__global__ void k_gproj(const float* __restrict__ gpart, const float* __restrict__ gproj_w,
                        const float* __restrict__ gproj_b, float* __restrict__ gfeat) {
    int b = blockIdx.x, t = threadIdx.x;
    __shared__ float graw[256];
    const float* p = gpart + ((size_t)(b * CH + t)) * 64;
    float s = 0.f;
    #pragma unroll
    for (int i = 0; i < 64; i++) s += p[i];
    graw[t] = s * (1.0f / 4096.0f);
    __syncthreads();
    float acc = gproj_b[t];
    const float* wr = gproj_w + (size_t)t * CH;
    #pragma unroll 8
    for (int c = 0; c < 256; c++) acc += graw[c] * wr[c];
    gfeat[b * CH + t] = acc;
}

// ---------------- K4: convert qkv_w + proj_w to bf16 ----------------
__global__ void k_convert(const float* __restrict__ qkv_w, const float* __restrict__ proj_w,
                          unsigned short* __restrict__ wbf) {
    int i4 = blockIdx.x * 256 + threadIdx.x;
    const float* src = (i4 < 49152) ? (qkv_w + (size_t)i4 * 4)
                                    : (proj_w + (size_t)(i4 - 49152) * 4);
    float4 v = *(const float4*)src;
    ushort4 o;
    o.x = f2bf(v.x); o.y = f2bf(v.y); o.z = f2bf(v.z); o.w = f2bf(v.w);
    *(ushort4*)(wbf + (size_t)i4 * 4) = o;
}

// ---------------- K5a: QKV GEMM -> bf16 q/k/v in attention layouts ----------------
__global__ void k_gemm_qkv(const unsigned short* __restrict__ Ag,
                           const unsigned short* __restrict__ Btg,
                           const float* __restrict__ bias,
                           const float* __restrict__ gfeat,
                           unsigned short* __restrict__ qt,
                           unsigned short* __restrict__ kt,
                           unsigned short* __restrict__ vt) {
    int n0 = blockIdx.x * 128, m0 = blockIdx.y * 64, b = blockIdx.z;
    int t = threadIdx.x, lane = t & 63, w = t >> 6;
    int wm = w >> 1, wn = w & 1;
    __shared__ short A_lds[64][40];
    __shared__ short B_lds[128][40];
    const unsigned short* Bb = Btg + (size_t)b * NSP * CH;
    f32x4 acc[2][4];
    #pragma unroll
    for (int m = 0; m < 2; m++)
        #pragma unroll
        for (int n = 0; n < 4; n++) acc[m][n] = (f32x4){0.f, 0.f, 0.f, 0.f};
    int arow = t >> 2, akk = (t & 3) * 8;
    for (int k0 = 0; k0 < 256; k0 += 32) {
        __syncthreads();
        *(uint4*)&A_lds[arow][akk] = *(const uint4*)(Ag + (size_t)(m0 + arow) * CH + k0 + akk);
        #pragma unroll
        for (int hh = 0; hh < 2; hh++) {
            int f = t + hh * 256;
            int j = f >> 2, kk = (f & 3) * 8;
            *(uint4*)&B_lds[j][kk] = *(const uint4*)(Bb + (size_t)(n0 + j) * CH + k0 + kk);
        }
        __syncthreads();
        short8 a[2], bf[4];
        #pragma unroll
        for (int m = 0; m < 2; m++)
            a[m] = *(const short8*)&A_lds[wm * 32 + m * 16 + (lane & 15)][(lane >> 4) * 8];
        #pragma unroll
        for (int n = 0; n < 4; n++)
            bf[n] = *(const short8*)&B_lds[wn * 64 + n * 16 + (lane & 15)][(lane >> 4) * 8];
        #pragma unroll
        for (int m = 0; m < 2; m++)
            #pragma unroll
            for (int n = 0; n < 4; n++)
                acc[m][n] = __builtin_amdgcn_mfma_f32_16x16x32_bf16(a[m], bf[n], acc[m][n], 0, 0, 0);
    }
    int rbase = m0 + wm * 32 + ((lane >> 4) << 2);
    int cbase = n0 + wn * 64 + (lane & 15);
    #pragma unroll
    for (int m = 0; m < 2; m++) {
        int row0 = rbase + m * 16;
        int sec = row0 >> 8;
        int ch  = row0 & 255;
        int h = ch >> 5, d0 = ch & 31;
        #pragma unroll
        for (int n = 0; n < 4; n++) {
            int col = cbase + n * 16;
            if (sec == 0) {
                ushort4 pk;
                pk.x = f2bf(acc[m][n][0] + bias[row0 + 0]);
                pk.y = f2bf(acc[m][n][1] + bias[row0 + 1]);
                pk.z = f2bf(acc[m][n][2] + bias[row0 + 2]);
                pk.w = f2bf(acc[m][n][3] + bias[row0 + 3]);
                *(ushort4*)(qt + ((size_t)((b * 8 + h) * NSP + col)) * HD + d0) = pk;
            } else if (sec == 1) {
                ushort4 pk;
                #pragma unroll
                for (int i = 0; i < 4; i++) {
                    float v = (acc[m][n][i] + bias[row0 + i]
                               + 0.1f * gfeat[b * CH + ch + i]) * ATT_SCALE;
                    ((unsigned short*)&pk)[i] = f2bf(v);
                }
                *(ushort4*)(kt + ((size_t)((b * 8 + h) * NSP + col)) * HD + d0) = pk;
            } else {
                #pragma unroll
                for (int i = 0; i < 4; i++) {
                    float v = acc[m][n][i] + bias[row0 + i];
                    vt[((size_t)((b * 8 + h) * HD + d0 + i)) * NSP + col] = f2bf(v);
                }
            }
        }
    }
}

// -------- K5b: proj GEMM with FUSED split-combine in B-staging --------
__global__ void k_gemm_proj(const unsigned short* __restrict__ Ag,
                            const unsigned short* __restrict__ opart,
                            const float* __restrict__ lpart,
                            const float* __restrict__ bias,
                            const float* __restrict__ gfeat,
                            const float* __restrict__ xres,
                            float* __restrict__ out) {
    int n0 = blockIdx.x * 128, m0 = blockIdx.y * 64, b = blockIdx.z;
    int t = threadIdx.x, lane = t & 63, w = t >> 6;
    int wm = w >> 1, wn = w & 1;
    __shared__ short A_lds[64][40];
    __shared__ short B_lds[128][40];
    const size_t sO = (size_t)BATCH * HEADS * NSP;   // opart row-stride per split (x HD)
    f32x4 acc[2][4];
    #pragma unroll
    for (int m = 0; m < 2; m++)
        #pragma unroll
        for (int n = 0; n < 4; n++) acc[m][n] = (f32x4){0.f, 0.f, 0.f, 0.f};
    int arow = t >> 2, akk = (t & 3) * 8;
    for (int k0 = 0; k0 < 256; k0 += 32) {
        __syncthreads();
        *(uint4*)&A_lds[arow][akk] = *(const uint4*)(Ag + (size_t)(m0 + arow) * CH + k0 + akk);
        int hidx = k0 >> 5;
        #pragma unroll
        for (int hh = 0; hh < 2; hh++) {
            int f = t + hh * 256;
            int j = f >> 2, kk = (f & 3) * 8;
            size_t rowq = ((size_t)(b * HEADS + hidx)) * NSP + n0 + j;
            float den = 0.f;
            float a0 = 0.f, a1 = 0.f, a2 = 0.f, a3 = 0.f,
                  a4 = 0.f, a5 = 0.f, a6 = 0.f, a7 = 0.f;
            #pragma unroll
            for (int s2 = 0; s2 < NSPLIT; s2++) {
                size_t off = (size_t)s2 * sO + rowq;
                den += lpart[off];
                uint4 v = *(const uint4*)(opart + off * HD + kk);
                const unsigned short* pv = (const unsigned short*)&v;
                a0 += bf2f(pv[0]); a1 += bf2f(pv[1]);
                a2 += bf2f(pv[2]); a3 += bf2f(pv[3]);
                a4 += bf2f(pv[4]); a5 += bf2f(pv[5]);
                a6 += bf2f(pv[6]); a7 += bf2f(pv[7]);
            }
            float inv = 1.0f / den;
            uint4 pk;
            pk.x = (unsigned)f2bf(a0 * inv) | ((unsigned)f2bf(a1 * inv) << 16);
            pk.y = (unsigned)f2bf(a2 * inv) | ((unsigned)f2bf(a3 * inv) << 16);
            pk.z = (unsigned)f2bf(a4 * inv) | ((unsigned)f2bf(a5 * inv) << 16);
            pk.w = (unsigned)f2bf(a6 * inv) | ((unsigned)f2bf(a7 * inv) << 16);
            *(uint4*)&B_lds[j][kk] = pk;
        }
        __syncthreads();
        short8 a[2], bf[4];
        #pragma unroll
        for (int m = 0; m < 2; m++)
            a[m] = *(const short8*)&A_lds[wm * 32 + m * 16 + (lane & 15)][(lane >> 4) * 8];
        #pragma unroll
        for (int n = 0; n < 4; n++)
            bf[n] = *(const short8*)&B_lds[wn * 64 + n * 16 + (lane & 15)][(lane >> 4) * 8];
        #pragma unroll
        for (int m = 0; m < 2; m++)
            #pragma unroll
            for (int n = 0; n < 4; n++)
                acc[m][n] = __builtin_amdgcn_mfma_f32_16x16x32_bf16(a[m], bf[n], acc[m][n], 0, 0, 0);
    }
    int rbase = m0 + wm * 32 + ((lane >> 4) << 2);
    int cbase = n0 + wn * 64 + (lane & 15);
    #pragma unroll
    for (int m = 0; m < 2; m++) {
        #pragma unroll
        for (int n = 0; n < 4; n++) {
            int col = cbase + n * 16;
            #pragma unroll
            for (int i = 0; i < 4; i++) {
                int row = rbase + m * 16 + i;
                float add = bias[row] + 0.1f * gfeat[b * CH + row]
                          + xres[((size_t)(b * CH + row)) * NSP + col];
                out[((size_t)(b * CH + row)) * NSP + col] = acc[m][n][i] + add;
            }
        }
    }
}

// ------------- K6: 32x32 MFMA flash attention, NO-MAX, KVBLK=128 -------------
// S^T = mfma(K,Q): lane holds S[j][q=lane&31], j = hf*32 + (r&3) + 8*(r>>2) + 4*hi.
// P' = exp2(S) UNNORMALIZED (|S| <~ 20 << 127; max cancels in the split combine).
// KVBLK=128: halves barrier count vs 64 (2 barriers per 128 j). 4 j-half passes/iter.
// l partner-exchange DEFERRED to after the loop (sum is linear; one permlane total).
// K rows 80B (20 banks): conflict-free. V rows 132 shorts (264B == 2 mod-32 banks):
// only lo32<->lo32+16 alias = 2-way = free. PV B-frags via permlane32_swap builtin.
__global__ __launch_bounds__(256, 8)
void k_flash32(const unsigned short* __restrict__ qt,
               const unsigned short* __restrict__ kt,
               const unsigned short* __restrict__ vt,
               unsigned short* __restrict__ opart, float* __restrict__ lpart) {
    const int h = blockIdx.y, b = blockIdx.z;
    const int s = blockIdx.x >> 5;
    const int t = threadIdx.x, lane = t & 63, w = t >> 6;
    const int lo32 = lane & 31, hi = lane >> 5;
    const int q0 = (blockIdx.x & 31) * 128 + w * 32;
    const int j0base = s * (NSP / NSPLIT);
    const unsigned short* qp = qt + ((size_t)(b * 8 + h) * NSP) * HD;
    const unsigned short* kp = kt + ((size_t)(b * 8 + h) * NSP) * HD;
    const unsigned short* vp = vt + ((size_t)(b * 8 + h) * HD) * NSP;
    __shared__ __align__(16) unsigned short K_lds[128 * 40];   // 80B rows, conflict-free
    __shared__ __align__(16) unsigned short V_lds[32 * 132];   // 264B rows, 2-way max

    short8 qf0 = *(const short8*)(qp + (size_t)(q0 + lo32) * HD + hi * 8);
    short8 qf1 = *(const short8*)(qp + (size_t)(q0 + lo32) * HD + 16 + hi * 8);
    f32x16 oacc;
    #pragma unroll
    for (int i = 0; i < 16; i++) oacc[i] = 0.f;
    float l = 0.f;   // own-lane partial; partner merged after the loop

    // staging: K bank-tiled remap (rows 0..63 + 64..127); 1KB-coalesced/wave
    const int krow = (t & 7) + 8 * (t >> 5);
    const int kslot = (t >> 3) & 3;
    const int vd = t >> 3, vslot = t & 7;
    const unsigned short* kga = kp + (size_t)(j0base + krow) * HD + kslot * 8;
    const unsigned short* vga = vp + (size_t)vd * NSP + j0base + vslot * 8;
    const int kws = krow * 40 + kslot * 8;
    const int vws = vd * 132 + vslot * 8;

    const int NT = NSP / NSPLIT / 128;
    for (int it = 0; it < NT; ++it) {
        {   // stage current 128-j tile (2 rounds each for K and V; transient regs)
            const unsigned short* kb = kga + (size_t)it * 128 * HD;
            const unsigned short* vb = vga + it * 128;
            uint4 k0 = *(const uint4*)(kb);
            uint4 k1 = *(const uint4*)(kb + (size_t)64 * HD);
            uint4 v0 = *(const uint4*)(vb);
            uint4 v1 = *(const uint4*)(vb + 64);
            *(uint4*)&K_lds[kws] = k0;
            *(uint4*)&K_lds[kws + 64 * 40] = k1;
            *(uint4*)&V_lds[vws] = v0;
            *(uint4*)&V_lds[vws + 64] = v1;
        }
        __syncthreads();
        // ---- four independent 32-j half passes (sv dead between them) ----
        #pragma unroll
        for (int hf = 0; hf < 4; hf++) {
            const int jj = hf * 32 + lo32;
            short8 kf0 = *(const short8*)&K_lds[jj * 40 + hi * 8];
            short8 kf1 = *(const short8*)&K_lds[jj * 40 + (2 + hi) * 8];
            f32x16 sv;
            __builtin_amdgcn_s_setprio(1);
            sv = __builtin_amdgcn_mfma_f32_32x32x16_bf16(kf0, qf0, ZERO16, 0, 0, 0);
            sv = __builtin_amdgcn_mfma_f32_32x32x16_bf16(kf1, qf1, sv, 0, 0, 0);
            __builtin_amdgcn_s_setprio(0);
            // P' = exp2(S), unnormalized (no max tracking)
            #pragma unroll
            for (int i = 0; i < 16; i++) sv[i] = __builtin_amdgcn_exp2f(sv[i]);
            // row sum: v_pk_add_f32 tree; own-lane accumulate only (exchange deferred)
            {
                #define SH2(V, I) __builtin_shufflevector(V, V, 2*(I), 2*(I)+1)
                f32x2 t0 = (SH2(sv,0) + SH2(sv,1)) + (SH2(sv,2) + SH2(sv,3));
                f32x2 t1 = (SH2(sv,4) + SH2(sv,5)) + (SH2(sv,6) + SH2(sv,7));
                f32x2 tt = t0 + t1;
                l += tt[0] + tt[1];
                #undef SH2
            }
            // P->bf16 + permlane32_swap; O^T += V P
            #define PVSTEP(SV, BB, C) { \
                unsigned p0 = pkbf(SV[BB + 0], SV[BB + 1]); \
                unsigned p1 = pkbf(SV[BB + 2], SV[BB + 3]); \
                unsigned p2 = pkbf(SV[BB + 4], SV[BB + 5]); \
                unsigned p3 = pkbf(SV[BB + 6], SV[BB + 7]); \
                auto s02 = __builtin_amdgcn_permlane32_swap(p0, p2, false, false); \
                auto s13 = __builtin_amdgcn_permlane32_swap(p1, p3, false, false); \
                uint4 fu = make_uint4((unsigned)s02[0], (unsigned)s13[0], \
                                      (unsigned)s02[1], (unsigned)s13[1]); \
                short8 pa = *(short8*)&fu; \
                short8 vf = *(const short8*)&V_lds[lo32 * 132 + ((C) * 2 + hi) * 8]; \
                oacc = __builtin_amdgcn_mfma_f32_32x32x16_bf16(vf, pa, oacc, 0, 0, 0); \
            }
            __builtin_amdgcn_s_setprio(1);
            PVSTEP(sv, 0, hf * 2)
            PVSTEP(sv, 8, hf * 2 + 1)
            __builtin_amdgcn_s_setprio(0);
            #undef PVSTEP
        }
        __syncthreads();   // protect K_lds/V_lds before next stage
    }
    // merge partner's l once (own+partner, direction-symmetric)
    {
        unsigned sb = __builtin_bit_cast(unsigned, l);
        auto sx = __builtin_amdgcn_permlane32_swap(sb, sb, false, false);
        l = __builtin_bit_cast(float, (unsigned)sx[0])
          + __builtin_bit_cast(float, (unsigned)sx[1]);
    }
    // bf16 unnormalized partials: lane q = q0+lo32, d = 8*rr + 4*hi + 0..3
    unsigned short* op = opart + ((((size_t)s * BATCH + b) * HEADS + h) * NSP + q0 + lo32) * HD;
    #pragma unroll
    for (int rr = 0; rr < 4; rr++) {
        ushort4 pk4;
        pk4.x = f2bf(oacc[rr * 4 + 0]);
        pk4.y = f2bf(oacc[rr * 4 + 1]);
        pk4.z = f2bf(oacc[rr * 4 + 2]);
        pk4.w = f2bf(oacc[rr * 4 + 3]);
        *(ushort4*)(op + rr * 8 + hi * 4) = pk4;
    }
    if (hi == 0)
        lpart[(((size_t)s * BATCH + b) * HEADS + h) * NSP + q0 + lo32] = l;
}

extern "C" void kernel_launch(void* const* d_in, const int* in_sizes, int n_in,
                              void* d_out, int out_size, void* d_ws, size_t ws_size,
                              hipStream_t stream) {
    const float* x       = (const float*)d_in[0];
    const float* gn_w    = (const float*)d_in[1];
    const float* gn_b    = (const float*)d_in[2];
    const float* qkv_w   = (const float*)d_in[3];
    const float* qkv_b   = (const float*)d_in[4];
    const float* proj_w  = (const float*)d_in[5];
    const float* proj_b  = (const float*)d_in[6];
    const float* gproj_w = (const float*)d_in[7];
    const float* gproj_b = (const float*)d_in[8];
    char* ws = (char*)d_ws;
    float*          stats  = (float*)(ws);                      // 512 B
    float*          gpart  = (float*)(ws + 1024);               // 128 KB
    float*          gfeat  = (float*)(ws + 132096);             // 2 KB
    unsigned short* wbf    = (unsigned short*)(ws + 134144);    // 512 KB bf16 weights
    unsigned short* xnt    = (unsigned short*)(ws + 658432);    // (b,p,c) bf16, 4 MB (dead after qkv GEMM)
    float*          lpart  = (float*)(ws + 658432);             // overlays xnt: 1 MB l per (s,q)
    unsigned short* qt     = (unsigned short*)(ws + 4852736);   // (b,h,n,hd) bf16, 4 MB
    unsigned short* kt     = (unsigned short*)(ws + 9047040);   // (b,h,n,hd) bf16, 4 MB
    unsigned short* vt     = (unsigned short*)(ws + 13241344);  // (b,h,hd,n) bf16, 4 MB
    unsigned short* opart  = (unsigned short*)(ws + 21629952);  // 4 splits bf16 O, 16.8 MB
    float* out = (float*)d_out;

    hipLaunchKernelGGL(k_gnstats, dim3(64), dim3(256), 0, stream, x, stats);
    hipLaunchKernelGGL(k_gnapply, dim3(64, 4, 2), dim3(256), 0, stream,
                       x, gn_w, gn_b, stats, xnt, gpart);
    hipLaunchKernelGGL(k_gproj, dim3(2), dim3(256), 0, stream,
                       gpart, gproj_w, gproj_b, gfeat);
    hipLaunchKernelGGL(k_convert, dim3(256), dim3(256), 0, stream, qkv_w, proj_w, wbf);
    hipLaunchKernelGGL(k_gemm_qkv, dim3(32, 12, 2), dim3(256), 0, stream,
                       wbf, xnt, qkv_b, gfeat, qt, kt, vt);
    hipLaunchKernelGGL(k_flash32, dim3(32 * NSPLIT, 8, 2), dim3(256), 0, stream,
                       qt, kt, vt, opart, lpart);
    hipLaunchKernelGGL(k_gemm_proj, dim3(32, 4, 2), dim3(256), 0, stream,
                       wbf + 196608, opart, lpart, proj_b, gfeat, x, out);
}

// Round 16
// 106.774 us; speedup vs baseline: 1.2116x; 1.0124x over previous
//
#include <hip/hip_runtime.h>
#include <hip/hip_bf16.h>
#include <stdint.h>

#define BATCH 2
#define CH 256
#define NSP 4096          // 64*64 spatial
#define HEADS 8
#define HD 32
#define GROUPS 32
#define EPS_GN 1e-5f
#define NSPLIT 4          // flash KV-sequence splits

// hd^-0.5 * log2(e): folds softmax scale AND exp->exp2 conversion into k
#define ATT_SCALE (0.17677669529663687f * 1.4426950408889634f)

typedef __attribute__((ext_vector_type(8))) short short8;    // 8 bf16 (MFMA A/B frag)
typedef __attribute__((ext_vector_type(4))) float f32x4;     // 16x16 C/D frag
typedef __attribute__((ext_vector_type(16))) float f32x16;   // 32x32 C/D frag
typedef __attribute__((ext_vector_type(2))) float f32x2;     // v_pk_add_f32 operand

#define ZERO16 ((f32x16){0.f,0.f,0.f,0.f,0.f,0.f,0.f,0.f,0.f,0.f,0.f,0.f,0.f,0.f,0.f,0.f})

static __device__ __forceinline__ unsigned short f2bf(float f) {
    union { float f; unsigned u; } v; v.f = f;
    unsigned r = v.u + 0x7fffu + ((v.u >> 16) & 1u);  // RNE
    return (unsigned short)(r >> 16);
}
static __device__ __forceinline__ float bf2f(unsigned short u) {
    unsigned v = (unsigned)u << 16;
    return *(float*)&v;
}
static __device__ __forceinline__ unsigned pkbf(float x, float y) {
    __hip_bfloat162 h = __float22bfloat162_rn(make_float2(x, y));  // -> v_cvt_pk_bf16_f32
    return *(unsigned*)&h;
}

// ------ K1: GroupNorm partial stats: 4 blocks per (b,group), 256 total ------
__global__ void k_gnstats(const float* __restrict__ x, float* __restrict__ stats2) {
    int blk = blockIdx.x;             // (b*32+g)*4 + quarter
    int t = threadIdx.x;
    const float4* b4 = (const float4*)(x + (size_t)(blk >> 2) * 32768) + (blk & 3) * 2048;
    float s = 0.f, sq = 0.f;
    #pragma unroll
    for (int i = 0; i < 8; i++) {
        float4 v = b4[t + i * 256];
        s  += v.x + v.y + v.z + v.w;
        sq += v.x * v.x + v.y * v.y + v.z * v.z + v.w * v.w;
    }
    #pragma unroll
    for (int off = 32; off > 0; off >>= 1) {
        s  += __shfl_down(s, off);
        sq += __shfl_down(sq, off);
    }
    __shared__ float rs[4], rq[4];
    int w = t >> 6;
    if ((t & 63) == 0) { rs[w] = s; rq[w] = sq; }
    __syncthreads();
    if (t == 0) {
        stats2[blk * 2]     = rs[0] + rs[1] + rs[2] + rs[3];
        stats2[blk * 2 + 1] = rq[0] + rq[1] + rq[2] + rq[3];
    }
}

// ------ K2: apply GN (finalizing partial stats), write xn^T bf16 + gpart ------
__global__ void k_gnapply(const float* __restrict__ x, const float* __restrict__ gn_w,
                          const float* __restrict__ gn_b, const float* __restrict__ stats2,
                          unsigned short* __restrict__ xnt, float* __restrict__ gpart) {
    int p0 = blockIdx.x * 64, c0 = blockIdx.y * 64, b = blockIdx.z;
    int t = threadIdx.x;
    __shared__ float tile[64][65];
    int ci0 = t >> 4, pq = t & 15;
    #pragma unroll
    for (int k = 0; k < 4; k++) {
        int ci = ci0 + k * 16;
        int c = c0 + ci;
        int g4 = (b * GROUPS + (c >> 3)) * 4;
        float S = 0.f, Q = 0.f;
        #pragma unroll
        for (int qq = 0; qq < 4; qq++) {
            S += stats2[(g4 + qq) * 2];
            Q += stats2[(g4 + qq) * 2 + 1];
        }
        float mu   = S * (1.0f / 32768.0f);
        float var  = Q * (1.0f / 32768.0f) - mu * mu;
        float rstd = rsqrtf(var + EPS_GN);
        float w  = gn_w[c] * rstd;
        float bb = gn_b[c] - mu * w;
        float4 v = *(const float4*)(x + ((size_t)(b * CH + c)) * NSP + p0 + pq * 4);
        tile[ci][pq * 4 + 0] = v.x * w + bb;
        tile[ci][pq * 4 + 1] = v.y * w + bb;
        tile[ci][pq * 4 + 2] = v.z * w + bb;
        tile[ci][pq * 4 + 3] = v.w * w + bb;
    }
    __syncthreads();
    int pi = t >> 2, cb = (t & 3) * 16;
    unsigned pack[8];
    #pragma unroll
    for (int e = 0; e < 8; e++) {
        float a  = tile[cb + 2 * e][pi];
        float bv = tile[cb + 2 * e + 1][pi];
        pack[e] = (unsigned)f2bf(a) | ((unsigned)f2bf(bv) << 16);
    }
    uint4* dst = (uint4*)(xnt + ((size_t)(b * NSP + p0 + pi)) * CH + c0 + cb);
    dst[0] = make_uint4(pack[0], pack[1], pack[2], pack[3]);
    dst[1] = make_uint4(pack[4], pack[5], pack[6], pack[7]);
    if (t < 64) {
        float s = 0.f;
        #pragma unroll
        for (int j = 0; j < 64; j++) s += tile[t][j];
        gpart[((size_t)(b * CH + c0 + t)) * 64 + blockIdx.x] = s;
    }
}

// -------- K3: gfeat = mean(xn) @ gproj_w^T + gproj_b --------
__global__ void k_gproj(const float* __restrict__ gpart, const float* __restrict__ gproj_w,
                        const float* __restrict__ gproj_b, float* __restrict__ gfeat) {
    int b = blockIdx.x, t = threadIdx.x;
    __shared__ float graw[256];
    const float* p = gpart + ((size_t)(b * CH + t)) * 64;
    float s = 0.f;
    #pragma unroll
    for (int i = 0; i < 64; i++) s += p[i];
    graw[t] = s * (1.0f / 4096.0f);
    __syncthreads();
    float acc = gproj_b[t];
    const float* wr = gproj_w + (size_t)t * CH;
    #pragma unroll 8
    for (int c = 0; c < 256; c++) acc += graw[c] * wr[c];
    gfeat[b * CH + t] = acc;
}

// ---- K5a: QKV GEMM (A = fp32 qkv_w, converted during staging) -> q/k/v bf16 ----
__global__ void k_gemm_qkv(const float* __restrict__ Wf,
                           const unsigned short* __restrict__ Btg,
                           const float* __restrict__ bias,
                           const float* __restrict__ gfeat,
                           unsigned short* __restrict__ qt,
                           unsigned short* __restrict__ kt,
                           unsigned short* __restrict__ vt) {
    int n0 = blockIdx.x * 128, m0 = blockIdx.y * 64, b = blockIdx.z;
    int t = threadIdx.x, lane = t & 63, w = t >> 6;
    int wm = w >> 1, wn = w & 1;
    __shared__ short A_lds[64][40];
    __shared__ short B_lds[128][40];
    const unsigned short* Bb = Btg + (size_t)b * NSP * CH;
    f32x4 acc[2][4];
    #pragma unroll
    for (int m = 0; m < 2; m++)
        #pragma unroll
        for (int n = 0; n < 4; n++) acc[m][n] = (f32x4){0.f, 0.f, 0.f, 0.f};
    int arow = t >> 2, akk = (t & 3) * 8;
    for (int k0 = 0; k0 < 256; k0 += 32) {
        __syncthreads();
        {   // fp32 -> bf16 convert during A-stage (RNE, same as old k_convert)
            const float* wsrc = Wf + (size_t)(m0 + arow) * CH + k0 + akk;
            float4 w0 = *(const float4*)(wsrc);
            float4 w1 = *(const float4*)(wsrc + 4);
            *(uint4*)&A_lds[arow][akk] =
                make_uint4(pkbf(w0.x, w0.y), pkbf(w0.z, w0.w),
                           pkbf(w1.x, w1.y), pkbf(w1.z, w1.w));
        }
        #pragma unroll
        for (int hh = 0; hh < 2; hh++) {
            int f = t + hh * 256;
            int j = f >> 2, kk = (f & 3) * 8;
            *(uint4*)&B_lds[j][kk] = *(const uint4*)(Bb + (size_t)(n0 + j) * CH + k0 + kk);
        }
        __syncthreads();
        short8 a[2], bf[4];
        #pragma unroll
        for (int m = 0; m < 2; m++)
            a[m] = *(const short8*)&A_lds[wm * 32 + m * 16 + (lane & 15)][(lane >> 4) * 8];
        #pragma unroll
        for (int n = 0; n < 4; n++)
            bf[n] = *(const short8*)&B_lds[wn * 64 + n * 16 + (lane & 15)][(lane >> 4) * 8];
        #pragma unroll
        for (int m = 0; m < 2; m++)
            #pragma unroll
            for (int n = 0; n < 4; n++)
                acc[m][n] = __builtin_amdgcn_mfma_f32_16x16x32_bf16(a[m], bf[n], acc[m][n], 0, 0, 0);
    }
    int rbase = m0 + wm * 32 + ((lane >> 4) << 2);
    int cbase = n0 + wn * 64 + (lane & 15);
    #pragma unroll
    for (int m = 0; m < 2; m++) {
        int row0 = rbase + m * 16;
        int sec = row0 >> 8;
        int ch  = row0 & 255;
        int h = ch >> 5, d0 = ch & 31;
        #pragma unroll
        for (int n = 0; n < 4; n++) {
            int col = cbase + n * 16;
            if (sec == 0) {
                ushort4 pk;
                pk.x = f2bf(acc[m][n][0] + bias[row0 + 0]);
                pk.y = f2bf(acc[m][n][1] + bias[row0 + 1]);
                pk.z = f2bf(acc[m][n][2] + bias[row0 + 2]);
                pk.w = f2bf(acc[m][n][3] + bias[row0 + 3]);
                *(ushort4*)(qt + ((size_t)((b * 8 + h) * NSP + col)) * HD + d0) = pk;
            } else if (sec == 1) {
                ushort4 pk;
                #pragma unroll
                for (int i = 0; i < 4; i++) {
                    float v = (acc[m][n][i] + bias[row0 + i]
                               + 0.1f * gfeat[b * CH + ch + i]) * ATT_SCALE;
                    ((unsigned short*)&pk)[i] = f2bf(v);
                }
                *(ushort4*)(kt + ((size_t)((b * 8 + h) * NSP + col)) * HD + d0) = pk;
            } else {
                #pragma unroll
                for (int i = 0; i < 4; i++) {
                    float v = acc[m][n][i] + bias[row0 + i];
                    vt[((size_t)((b * 8 + h) * HD + d0 + i)) * NSP + col] = f2bf(v);
                }
            }
        }
    }
}

// -------- K5b: proj GEMM, A = fp32 proj_w converted in-stage, FUSED combine --------
__global__ void k_gemm_proj(const float* __restrict__ Wf,
                            const unsigned short* __restrict__ opart,
                            const float* __restrict__ lpart,
                            const float* __restrict__ bias,
                            const float* __restrict__ gfeat,
                            const float* __restrict__ xres,
                            float* __restrict__ out) {
    int n0 = blockIdx.x * 128, m0 = blockIdx.y * 64, b = blockIdx.z;
    int t = threadIdx.x, lane = t & 63, w = t >> 6;
    int wm = w >> 1, wn = w & 1;
    __shared__ short A_lds[64][40];
    __shared__ short B_lds[128][40];
    const size_t sO = (size_t)BATCH * HEADS * NSP;   // opart row-stride per split (x HD)
    f32x4 acc[2][4];
    #pragma unroll
    for (int m = 0; m < 2; m++)
        #pragma unroll
        for (int n = 0; n < 4; n++) acc[m][n] = (f32x4){0.f, 0.f, 0.f, 0.f};
    int arow = t >> 2, akk = (t & 3) * 8;
    for (int k0 = 0; k0 < 256; k0 += 32) {
        __syncthreads();
        {   // fp32 -> bf16 convert during A-stage
            const float* wsrc = Wf + (size_t)(m0 + arow) * CH + k0 + akk;
            float4 w0 = *(const float4*)(wsrc);
            float4 w1 = *(const float4*)(wsrc + 4);
            *(uint4*)&A_lds[arow][akk] =
                make_uint4(pkbf(w0.x, w0.y), pkbf(w0.z, w0.w),
                           pkbf(w1.x, w1.y), pkbf(w1.z, w1.w));
        }
        int hidx = k0 >> 5;
        #pragma unroll
        for (int hh = 0; hh < 2; hh++) {
            int f = t + hh * 256;
            int j = f >> 2, kk = (f & 3) * 8;
            size_t rowq = ((size_t)(b * HEADS + hidx)) * NSP + n0 + j;
            float den = 0.f;
            float a0 = 0.f, a1 = 0.f, a2 = 0.f, a3 = 0.f,
                  a4 = 0.f, a5 = 0.f, a6 = 0.f, a7 = 0.f;
            #pragma unroll
            for (int s2 = 0; s2 < NSPLIT; s2++) {
                size_t off = (size_t)s2 * sO + rowq;
                den += lpart[off];
                uint4 v = *(const uint4*)(opart + off * HD + kk);
                const unsigned short* pv = (const unsigned short*)&v;
                a0 += bf2f(pv[0]); a1 += bf2f(pv[1]);
                a2 += bf2f(pv[2]); a3 += bf2f(pv[3]);
                a4 += bf2f(pv[4]); a5 += bf2f(pv[5]);
                a6 += bf2f(pv[6]); a7 += bf2f(pv[7]);
            }
            float inv = 1.0f / den;
            uint4 pk;
            pk.x = (unsigned)f2bf(a0 * inv) | ((unsigned)f2bf(a1 * inv) << 16);
            pk.y = (unsigned)f2bf(a2 * inv) | ((unsigned)f2bf(a3 * inv) << 16);
            pk.z = (unsigned)f2bf(a4 * inv) | ((unsigned)f2bf(a5 * inv) << 16);
            pk.w = (unsigned)f2bf(a6 * inv) | ((unsigned)f2bf(a7 * inv) << 16);
            *(uint4*)&B_lds[j][kk] = pk;
        }
        __syncthreads();
        short8 a[2], bf[4];
        #pragma unroll
        for (int m = 0; m < 2; m++)
            a[m] = *(const short8*)&A_lds[wm * 32 + m * 16 + (lane & 15)][(lane >> 4) * 8];
        #pragma unroll
        for (int n = 0; n < 4; n++)
            bf[n] = *(const short8*)&B_lds[wn * 64 + n * 16 + (lane & 15)][(lane >> 4) * 8];
        #pragma unroll
        for (int m = 0; m < 2; m++)
            #pragma unroll
            for (int n = 0; n < 4; n++)
                acc[m][n] = __builtin_amdgcn_mfma_f32_16x16x32_bf16(a[m], bf[n], acc[m][n], 0, 0, 0);
    }
    int rbase = m0 + wm * 32 + ((lane >> 4) << 2);
    int cbase = n0 + wn * 64 + (lane & 15);
    #pragma unroll
    for (int m = 0; m < 2; m++) {
        #pragma unroll
        for (int n = 0; n < 4; n++) {
            int col = cbase + n * 16;
            #pragma unroll
            for (int i = 0; i < 4; i++) {
                int row = rbase + m * 16 + i;
                float add = bias[row] + 0.1f * gfeat[b * CH + row]
                          + xres[((size_t)(b * CH + row)) * NSP + col];
                out[((size_t)(b * CH + row)) * NSP + col] = acc[m][n][i] + add;
            }
        }
    }
}

// ------------- K6: 32x32 MFMA flash attention, NO-MAX, KVBLK=128 -------------
// (byte-identical to r15's passing kernel)
__global__ __launch_bounds__(256, 8)
void k_flash32(const unsigned short* __restrict__ qt,
               const unsigned short* __restrict__ kt,
               const unsigned short* __restrict__ vt,
               unsigned short* __restrict__ opart, float* __restrict__ lpart) {
    const int h = blockIdx.y, b = blockIdx.z;
    const int s = blockIdx.x >> 5;
    const int t = threadIdx.x, lane = t & 63, w = t >> 6;
    const int lo32 = lane & 31, hi = lane >> 5;
    const int q0 = (blockIdx.x & 31) * 128 + w * 32;
    const int j0base = s * (NSP / NSPLIT);
    const unsigned short* qp = qt + ((size_t)(b * 8 + h) * NSP) * HD;
    const unsigned short* kp = kt + ((size_t)(b * 8 + h) * NSP) * HD;
    const unsigned short* vp = vt + ((size_t)(b * 8 + h) * HD) * NSP;
    __shared__ __align__(16) unsigned short K_lds[128 * 40];   // 80B rows, conflict-free
    __shared__ __align__(16) unsigned short V_lds[32 * 132];   // 264B rows, 2-way max

    short8 qf0 = *(const short8*)(qp + (size_t)(q0 + lo32) * HD + hi * 8);
    short8 qf1 = *(const short8*)(qp + (size_t)(q0 + lo32) * HD + 16 + hi * 8);
    f32x16 oacc;
    #pragma unroll
    for (int i = 0; i < 16; i++) oacc[i] = 0.f;
    float l = 0.f;   // own-lane partial; partner merged after the loop

    const int krow = (t & 7) + 8 * (t >> 5);
    const int kslot = (t >> 3) & 3;
    const int vd = t >> 3, vslot = t & 7;
    const unsigned short* kga = kp + (size_t)(j0base + krow) * HD + kslot * 8;
    const unsigned short* vga = vp + (size_t)vd * NSP + j0base + vslot * 8;
    const int kws = krow * 40 + kslot * 8;
    const int vws = vd * 132 + vslot * 8;

    const int NT = NSP / NSPLIT / 128;
    for (int it = 0; it < NT; ++it) {
        {
            const unsigned short* kb = kga + (size_t)it * 128 * HD;
            const unsigned short* vb = vga + it * 128;
            uint4 k0 = *(const uint4*)(kb);
            uint4 k1 = *(const uint4*)(kb + (size_t)64 * HD);
            uint4 v0 = *(const uint4*)(vb);
            uint4 v1 = *(const uint4*)(vb + 64);
            *(uint4*)&K_lds[kws] = k0;
            *(uint4*)&K_lds[kws + 64 * 40] = k1;
            *(uint4*)&V_lds[vws] = v0;
            *(uint4*)&V_lds[vws + 64] = v1;
        }
        __syncthreads();
        #pragma unroll
        for (int hf = 0; hf < 4; hf++) {
            const int jj = hf * 32 + lo32;
            short8 kf0 = *(const short8*)&K_lds[jj * 40 + hi * 8];
            short8 kf1 = *(const short8*)&K_lds[jj * 40 + (2 + hi) * 8];
            f32x16 sv;
            __builtin_amdgcn_s_setprio(1);
            sv = __builtin_amdgcn_mfma_f32_32x32x16_bf16(kf0, qf0, ZERO16, 0, 0, 0);
            sv = __builtin_amdgcn_mfma_f32_32x32x16_bf16(kf1, qf1, sv, 0, 0, 0);
            __builtin_amdgcn_s_setprio(0);
            #pragma unroll
            for (int i = 0; i < 16; i++) sv[i] = __builtin_amdgcn_exp2f(sv[i]);
            {
                #define SH2(V, I) __builtin_shufflevector(V, V, 2*(I), 2*(I)+1)
                f32x2 t0 = (SH2(sv,0) + SH2(sv,1)) + (SH2(sv,2) + SH2(sv,3));
                f32x2 t1 = (SH2(sv,4) + SH2(sv,5)) + (SH2(sv,6) + SH2(sv,7));
                f32x2 tt = t0 + t1;
                l += tt[0] + tt[1];
                #undef SH2
            }
            #define PVSTEP(SV, BB, C) { \
                unsigned p0 = pkbf(SV[BB + 0], SV[BB + 1]); \
                unsigned p1 = pkbf(SV[BB + 2], SV[BB + 3]); \
                unsigned p2 = pkbf(SV[BB + 4], SV[BB + 5]); \
                unsigned p3 = pkbf(SV[BB + 6], SV[BB + 7]); \
                auto s02 = __builtin_amdgcn_permlane32_swap(p0, p2, false, false); \
                auto s13 = __builtin_amdgcn_permlane32_swap(p1, p3, false, false); \
                uint4 fu = make_uint4((unsigned)s02[0], (unsigned)s13[0], \
                                      (unsigned)s02[1], (unsigned)s13[1]); \
                short8 pa = *(short8*)&fu; \
                short8 vf = *(const short8*)&V_lds[lo32 * 132 + ((C) * 2 + hi) * 8]; \
                oacc = __builtin_amdgcn_mfma_f32_32x32x16_bf16(vf, pa, oacc, 0, 0, 0); \
            }
            __builtin_amdgcn_s_setprio(1);
            PVSTEP(sv, 0, hf * 2)
            PVSTEP(sv, 8, hf * 2 + 1)
            __builtin_amdgcn_s_setprio(0);
            #undef PVSTEP
        }
        __syncthreads();
    }
    {
        unsigned sb = __builtin_bit_cast(unsigned, l);
        auto sx = __builtin_amdgcn_permlane32_swap(sb, sb, false, false);
        l = __builtin_bit_cast(float, (unsigned)sx[0])
          + __builtin_bit_cast(float, (unsigned)sx[1]);
    }
    unsigned short* op = opart + ((((size_t)s * BATCH + b) * HEADS + h) * NSP + q0 + lo32) * HD;
    #pragma unroll
    for (int rr = 0; rr < 4; rr++) {
        ushort4 pk4;
        pk4.x = f2bf(oacc[rr * 4 + 0]);
        pk4.y = f2bf(oacc[rr * 4 + 1]);
        pk4.z = f2bf(oacc[rr * 4 + 2]);
        pk4.w = f2bf(oacc[rr * 4 + 3]);
        *(ushort4*)(op + rr * 8 + hi * 4) = pk4;
    }
    if (hi == 0)
        lpart[(((size_t)s * BATCH + b) * HEADS + h) * NSP + q0 + lo32] = l;
}

extern "C" void kernel_launch(void* const* d_in, const int* in_sizes, int n_in,
                              void* d_out, int out_size, void* d_ws, size_t ws_size,
                              hipStream_t stream) {
    const float* x       = (const float*)d_in[0];
    const float* gn_w    = (const float*)d_in[1];
    const float* gn_b    = (const float*)d_in[2];
    const float* qkv_w   = (const float*)d_in[3];
    const float* qkv_b   = (const float*)d_in[4];
    const float* proj_w  = (const float*)d_in[5];
    const float* proj_b  = (const float*)d_in[6];
    const float* gproj_w = (const float*)d_in[7];
    const float* gproj_b = (const float*)d_in[8];
    char* ws = (char*)d_ws;
    float*          gpart  = (float*)(ws + 1024);               // 128 KB
    float*          gfeat  = (float*)(ws + 132096);             // 2 KB
    float*          stats2 = (float*)(ws + 134144);             // 2 KB partial {S,Q} x 256
    unsigned short* xnt    = (unsigned short*)(ws + 658432);    // (b,p,c) bf16, 4 MB (dead after qkv GEMM)
    float*          lpart  = (float*)(ws + 658432);             // overlays xnt: 1 MB l per (s,q)
    unsigned short* qt     = (unsigned short*)(ws + 4852736);   // (b,h,n,hd) bf16, 4 MB
    unsigned short* kt     = (unsigned short*)(ws + 9047040);   // (b,h,n,hd) bf16, 4 MB
    unsigned short* vt     = (unsigned short*)(ws + 13241344);  // (b,h,hd,n) bf16, 4 MB
    unsigned short* opart  = (unsigned short*)(ws + 21629952);  // 4 splits bf16 O, 16.8 MB
    float* out = (float*)d_out;

    hipLaunchKernelGGL(k_gnstats, dim3(256), dim3(256), 0, stream, x, stats2);
    hipLaunchKernelGGL(k_gnapply, dim3(64, 4, 2), dim3(256), 0, stream,
                       x, gn_w, gn_b, stats2, xnt, gpart);
    hipLaunchKernelGGL(k_gproj, dim3(2), dim3(256), 0, stream,
                       gpart, gproj_w, gproj_b, gfeat);
    hipLaunchKernelGGL(k_gemm_qkv, dim3(32, 12, 2), dim3(256), 0, stream,
                       qkv_w, xnt, qkv_b, gfeat, qt, kt, vt);
    hipLaunchKernelGGL(k_flash32, dim3(32 * NSPLIT, 8, 2), dim3(256), 0, stream,
                       qt, kt, vt, opart, lpart);
    hipLaunchKernelGGL(k_gemm_proj, dim3(32, 4, 2), dim3(256), 0, stream,
                       proj_w, opart, lpart, proj_b, gfeat, x, out);
}